// Round 14
// baseline (862.152 us; speedup 1.0000x reference)
//
#include <hip/hip_runtime.h>
#include <hip/hip_bf16.h>

typedef __attribute__((ext_vector_type(8))) short bf16x8;
typedef __attribute__((ext_vector_type(4))) short s16x4;
typedef __attribute__((ext_vector_type(4))) float f32x4;

#define NW_   3072
#define WACT_ 1536
#define NTOK_ 98304
#define NBLK_ 9830
#define DIM_  384
#define QKVD_ 1152
#define MLPD_ 1536

__device__ __forceinline__ float bf2f(short s) {
  union { unsigned u; float f; } c;
  c.u = ((unsigned)(unsigned short)s) << 16;
  return c.f;
}
__device__ __forceinline__ short f2bf(float f) {
  union { float f; unsigned u; } c; c.f = f;
  unsigned lsb = (c.u >> 16) & 1u;
  c.u += 0x7fffu + lsb;
  return (short)(c.u >> 16);
}

// f32 -> OCP e4m3fn (RNE). Finite inputs only; clamps to +-448.
__device__ __forceinline__ unsigned char f2e4m3(float f) {
  float a = fabsf(f);
  unsigned s = (__builtin_bit_cast(unsigned, f) >> 31) << 7;
  if (a >= 448.f) return (unsigned char)(s | 0x7E);
  if (a < 0.015625f) {               // denormal: multiples of 2^-9 (q=8 -> 0x08 ok)
    int q = (int)rintf(a * 512.f);
    return (unsigned char)(s | q);
  }
  int ex; float man = frexpf(a, &ex);  // a = man*2^ex, man in [0.5,1)
  int q = (int)rintf(man * 16.f);      // [8,16]
  if (q == 16) { q = 8; ex++; }
  int E = ex + 6;
  if (E > 15) return (unsigned char)(s | 0x7E);
  return (unsigned char)(s | (E << 3) | (q - 8));
}

__device__ __forceinline__ f32x4 mfma16(bf16x8 a, bf16x8 b, f32x4 c) {
  return __builtin_amdgcn_mfma_f32_16x16x32_bf16(a, b, c, 0, 0, 0);
}

__device__ __forceinline__ void gload16(const void* g, void* l) {
  __builtin_amdgcn_global_load_lds(
      (const __attribute__((address_space(1))) unsigned*)g,
      (__attribute__((address_space(3))) unsigned*)l, 16, 0, 0);
}

// ---------------- map kernels ----------------
__global__ __launch_bounds__(256) void mapA_k(int* win_rank, unsigned* bitmap) {
  int t = blockIdx.x * 256 + threadIdx.x;
  if (t < NW_) { win_rank[t] = -1; bitmap[t] = 0u; }
}

__global__ __launch_bounds__(256) void mapB_k(const int* __restrict__ iw,
                                              const int* __restrict__ blk,
                                              int* win_rank, unsigned* bitmap) {
  int t = blockIdx.x * 256 + threadIdx.x;
  if (t < WACT_) win_rank[iw[t]] = t;
  if (t < NBLK_) { int j = blk[t]; atomicOr(&bitmap[j >> 5], 1u << (j & 31)); }
}

__global__ __launch_bounds__(256) void mapC_k(const int* __restrict__ ip,
                                              const int* __restrict__ iw,
                                              const unsigned* __restrict__ bitmap,
                                              int* inv_ip, int* rowmap) {
  int i = blockIdx.x * 256 + threadIdx.x;
  if (i < NTOK_) {
    int j = ip[i];
    inv_ip[j] = i;
    int blocked = (bitmap[j >> 5] >> (j & 31)) & 1;
    rowmap[i] = blocked ? -1 : (iw[j >> 6] * 64 + (j & 63));
  }
}

// ---------------- weight conversion ----------------
__global__ __launch_bounds__(256) void wconv_k(const float* __restrict__ qkvw,
                                               const float* __restrict__ projw,
                                               const float* __restrict__ fc1w,
                                               const float* __restrict__ fc2w,
                                               short* __restrict__ dst) {
  int i = (blockIdx.x * 256 + threadIdx.x) * 4;  // total 1,769,472 elems
  f32x4 v;
  if (i < 442368) v = *(const f32x4*)&qkvw[i];
  else if (i < 589824) v = *(const f32x4*)&projw[i - 442368];
  else if (i < 1179648) v = *(const f32x4*)&fc1w[i - 589824];
  else v = *(const f32x4*)&fc2w[i - 1179648];
  s16x4 o;
#pragma unroll
  for (int e = 0; e < 4; ++e) o[e] = f2bf(v[e]);
  *(s16x4*)&dst[i] = o;
}

// fc2w -> fp8 e4m3 (589,824 elems)
__global__ __launch_bounds__(256) void wconv8_k(const float* __restrict__ fc2w,
                                                unsigned char* __restrict__ dst) {
  int i = (blockIdx.x * 256 + threadIdx.x) * 4;
  f32x4 v = *(const f32x4*)&fc2w[i];
  uchar4 o;
  o.x = f2e4m3(v[0]); o.y = f2e4m3(v[1]); o.z = f2e4m3(v[2]); o.w = f2e4m3(v[3]);
  *(uchar4*)&dst[i] = o;
}

// ---------------- LN1 + gather/permute (vectorized: 32 lanes/token) --------
__global__ __launch_bounds__(256) void ln1_k(const float* __restrict__ x,
                                             const float* __restrict__ w,
                                             const float* __restrict__ b,
                                             const int* __restrict__ win_rank,
                                             const int* __restrict__ inv_ip,
                                             const unsigned* __restrict__ bitmap,
                                             float* __restrict__ out,
                                             short* __restrict__ xp) {
  const int l = threadIdx.x & 31;
  const int tok = blockIdx.x * 8 + (threadIdx.x >> 5);
  const f32x4* xr = (const f32x4*)(x + (size_t)tok * DIM_);
  f32x4 v[3]; float s = 0.f;
#pragma unroll
  for (int j = 0; j < 3; ++j) {
    v[j] = xr[l + 32 * j];
    s += v[j][0] + v[j][1] + v[j][2] + v[j][3];
  }
#pragma unroll
  for (int m = 1; m <= 16; m <<= 1) s += __shfl_xor(s, m, 64);
  float mu = s * (1.0f / DIM_);
  float q = 0.f;
#pragma unroll
  for (int j = 0; j < 3; ++j)
#pragma unroll
    for (int e = 0; e < 4; ++e) { float d = v[j][e] - mu; q += d * d; }
#pragma unroll
  for (int m = 1; m <= 16; m <<= 1) q += __shfl_xor(q, m, 64);
  float rs = rsqrtf(q * (1.0f / DIM_) + 1e-5f);
  f32x4 y[3];
#pragma unroll
  for (int j = 0; j < 3; ++j) {
    f32x4 wv = *(const f32x4*)&w[4 * l + 128 * j];
    f32x4 bv = *(const f32x4*)&b[4 * l + 128 * j];
#pragma unroll
    for (int e = 0; e < 4; ++e) y[j][e] = (v[j][e] - mu) * rs * wv[e] + bv[e];
  }
  int wdw = tok >> 6, t = tok & 63;
  int rank = win_rank[wdw];
  if (rank < 0) {
    f32x4* po = (f32x4*)(out + (size_t)tok * DIM_);
#pragma unroll
    for (int j = 0; j < 3; ++j) po[l + 32 * j] = y[j];
  } else {
    int jdx = (rank << 6) + t;
    int i = inv_ip[jdx];
#pragma unroll
    for (int j = 0; j < 3; ++j) {
      s16x4 o;
#pragma unroll
      for (int e = 0; e < 4; ++e) o[e] = f2bf(y[j][e]);
      *(s16x4*)&xp[(size_t)i * DIM_ + 4 * l + 128 * j] = o;
    }
    if ((bitmap[jdx >> 5] >> (jdx & 31)) & 1) {
      f32x4* po = (f32x4*)(out + (size_t)tok * DIM_);
#pragma unroll
      for (int j = 0; j < 3; ++j) po[l + 32 * j] = y[j];
    }
  }
}

// ---------------- LN2 (vectorized: 32 lanes/token, short4) ----------------
__global__ __launch_bounds__(256) void ln2_k(const short* __restrict__ h,
                                             const float* __restrict__ w,
                                             const float* __restrict__ b,
                                             short* __restrict__ outln) {
  const int l = threadIdx.x & 31;
  const int tok = blockIdx.x * 8 + (threadIdx.x >> 5);
  const s16x4* xr = (const s16x4*)(h + (size_t)tok * DIM_);
  float v[12]; float s = 0.f;
#pragma unroll
  for (int j = 0; j < 3; ++j) {
    s16x4 rv = xr[l + 32 * j];
#pragma unroll
    for (int e = 0; e < 4; ++e) { v[j * 4 + e] = bf2f(rv[e]); s += v[j * 4 + e]; }
  }
#pragma unroll
  for (int m = 1; m <= 16; m <<= 1) s += __shfl_xor(s, m, 64);
  float mu = s * (1.0f / DIM_);
  float q = 0.f;
#pragma unroll
  for (int e = 0; e < 12; ++e) { float d = v[e] - mu; q += d * d; }
#pragma unroll
  for (int m = 1; m <= 16; m <<= 1) q += __shfl_xor(q, m, 64);
  float rs = rsqrtf(q * (1.0f / DIM_) + 1e-5f);
  s16x4* po = (s16x4*)(outln + (size_t)tok * DIM_);
#pragma unroll
  for (int j = 0; j < 3; ++j) {
    f32x4 wv = *(const f32x4*)&w[4 * l + 128 * j];
    f32x4 bv = *(const f32x4*)&b[4 * l + 128 * j];
    s16x4 o;
#pragma unroll
    for (int e = 0; e < 4; ++e)
      o[e] = f2bf((v[j * 4 + e] - mu) * rs * wv[e] + bv[e]);
    po[l + 32 * j] = o;
  }
}

// ---------------- GEMM: C = A * B^T (256x128 tile, 8 waves) ----------------
// Proven R10 structure: single-buffer LDS (48 KB), __syncthreads pipeline,
// XCD-chunk swizzle, bias in regs.
// EPI 0: +bias -> bf16 (ld N)         (QKV)
// EPI 2: +bias, fast gelu -> FP8 e4m3 (fc1 -> t8, ld MLPD_)
template <int EPI>
__global__ __launch_bounds__(512) void gemm_k(const short* __restrict__ A,
                                              const short* __restrict__ B,
                                              const float* __restrict__ bias,
                                              int K, int N, int nx,
                                              short* __restrict__ Cb,
                                              unsigned char* __restrict__ C8) {
  const int nwg = gridDim.x;
  const int q8 = nwg >> 3;
  const int wg = (blockIdx.x & 7) * q8 + (blockIdx.x >> 3);
  const int ntile = wg % nx, mtile = wg / nx;
  const int tid = threadIdx.x, wid = tid >> 6, lane = tid & 63;
  const int fq = lane >> 4, fr = lane & 15;
  const int wr = wid >> 1, wc = wid & 1;  // 4(M) x 2(N) waves, 64x64 each
  __shared__ __align__(16) short lA[256 * 64];
  __shared__ __align__(16) short lB[128 * 64];
  const int row0 = mtile * 256, col0 = ntile * 128;
  float bs[4];
#pragma unroll
  for (int nt = 0; nt < 4; ++nt) bs[nt] = bias[col0 + wc * 64 + nt * 16 + fr];
  f32x4 acc[4][4];
#pragma unroll
  for (int a = 0; a < 4; ++a)
#pragma unroll
    for (int c = 0; c < 4; ++c) acc[a][c] = (f32x4){0.f, 0.f, 0.f, 0.f};
  const int nkt = K >> 6;
  for (int kt = 0; kt < nkt; ++kt) {
    const int k0 = kt << 6;
#pragma unroll
    for (int i = 0; i < 4; ++i) {
      int g = i * 512 + tid;
      int r = g >> 3, c8 = g & 7;
      int s8 = c8 ^ (r & 7);
      gload16(A + (size_t)(row0 + r) * K + k0 + s8 * 8, (char*)lA + (size_t)g * 16);
    }
#pragma unroll
    for (int i = 0; i < 2; ++i) {
      int g = i * 512 + tid;
      int r = g >> 3, c8 = g & 7;
      int s8 = c8 ^ (r & 7);
      gload16(B + (size_t)(col0 + r) * K + k0 + s8 * 8, (char*)lB + (size_t)g * 16);
    }
    __syncthreads();
#pragma unroll
    for (int ks = 0; ks < 2; ++ks) {
      bf16x8 af[4], bfr[4];
#pragma unroll
      for (int mt = 0; mt < 4; ++mt) {
        int r = wr * 64 + mt * 16 + fr;
        af[mt] = *(const bf16x8*)&lA[r * 64 + ((ks * 4 + fq) ^ (r & 7)) * 8];
      }
#pragma unroll
      for (int nt = 0; nt < 4; ++nt) {
        int r = wc * 64 + nt * 16 + fr;
        bfr[nt] = *(const bf16x8*)&lB[r * 64 + ((ks * 4 + fq) ^ (r & 7)) * 8];
      }
#pragma unroll
      for (int mt = 0; mt < 4; ++mt)
#pragma unroll
        for (int nt = 0; nt < 4; ++nt)
          acc[mt][nt] = mfma16(af[mt], bfr[nt], acc[mt][nt]);
    }
    __syncthreads();
  }
#pragma unroll
  for (int mt = 0; mt < 4; ++mt) {
#pragma unroll
    for (int jj = 0; jj < 4; ++jj) {
      int r = row0 + wr * 64 + mt * 16 + fq * 4 + jj;
#pragma unroll
      for (int nt = 0; nt < 4; ++nt) {
        int gcol = col0 + wc * 64 + nt * 16 + fr;
        float v = acc[mt][nt][jj] + bs[nt];
        if (EPI == 0) {
          Cb[(size_t)r * N + gcol] = f2bf(v);
        } else {
          // gelu(x) ~= x * sigmoid(2u), u = 0.79788456*(x + 0.044715 x^3)
          float u = v * (0.79788456f + 0.03567741f * v * v);
          float g = v * __builtin_amdgcn_rcpf(1.0f + __expf(-2.0f * u));
          C8[(size_t)r * MLPD_ + gcol] = f2e4m3(g);
        }
      }
    }
  }
}

// ---------------- GEMM 128x128 bf16 (proj) ----------------
// Proven R7 structure. EPI 1: +bias +add_bf -> bf16 (proj + residual -> h)
__global__ __launch_bounds__(256) void gemm128_k(const short* __restrict__ A,
                                                 const short* __restrict__ B,
                                                 const float* __restrict__ bias,
                                                 int K, int nx,
                                                 short* __restrict__ Cb,
                                                 const short* __restrict__ add_bf) {
  const int nwg = gridDim.x;
  const int q8 = nwg >> 3;
  const int wg = (blockIdx.x & 7) * q8 + (blockIdx.x >> 3);
  const int ntile = wg % nx, mtile = wg / nx;
  const int tid = threadIdx.x, wid = tid >> 6, lane = tid & 63;
  const int fq = lane >> 4, fr = lane & 15;
  const int wr = wid >> 1, wc = wid & 1;
  __shared__ __align__(16) short lA[128 * 64];
  __shared__ __align__(16) short lB[128 * 64];
  const int row0 = mtile * 128, col0 = ntile * 128;
  float bs[4];
#pragma unroll
  for (int nt = 0; nt < 4; ++nt) bs[nt] = bias[col0 + wc * 64 + nt * 16 + fr];
  f32x4 acc[4][4];
#pragma unroll
  for (int a = 0; a < 4; ++a)
#pragma unroll
    for (int c = 0; c < 4; ++c) acc[a][c] = (f32x4){0.f, 0.f, 0.f, 0.f};
  const int nkt = K >> 6;
  for (int kt = 0; kt < nkt; ++kt) {
    const int k0 = kt << 6;
#pragma unroll
    for (int i = 0; i < 4; ++i) {
      int cb = ((i * 4 + wid) << 6) + lane;
      int r = cb >> 3, c8 = cb & 7;
      int s8 = c8 ^ (r & 7);
      gload16(A + (size_t)(row0 + r) * K + k0 + s8 * 8,
              (char*)lA + (size_t)(i * 4 + wid) * 1024);
      gload16(B + (size_t)(col0 + r) * K + k0 + s8 * 8,
              (char*)lB + (size_t)(i * 4 + wid) * 1024);
    }
    __syncthreads();
#pragma unroll
    for (int ks = 0; ks < 2; ++ks) {
      bf16x8 af[4], bfr[4];
#pragma unroll
      for (int mt = 0; mt < 4; ++mt) {
        int r = wr * 64 + mt * 16 + fr;
        af[mt] = *(const bf16x8*)&lA[r * 64 + ((ks * 4 + fq) ^ (r & 7)) * 8];
      }
#pragma unroll
      for (int nt = 0; nt < 4; ++nt) {
        int r = wc * 64 + nt * 16 + fr;
        bfr[nt] = *(const bf16x8*)&lB[r * 64 + ((ks * 4 + fq) ^ (r & 7)) * 8];
      }
#pragma unroll
      for (int mt = 0; mt < 4; ++mt)
#pragma unroll
        for (int nt = 0; nt < 4; ++nt)
          acc[mt][nt] = mfma16(af[mt], bfr[nt], acc[mt][nt]);
    }
    __syncthreads();
  }
#pragma unroll
  for (int mt = 0; mt < 4; ++mt) {
#pragma unroll
    for (int jj = 0; jj < 4; ++jj) {
      int r = row0 + wr * 64 + mt * 16 + fq * 4 + jj;
#pragma unroll
      for (int nt = 0; nt < 4; ++nt) {
        int gcol = col0 + wc * 64 + nt * 16 + fr;
        float v = acc[mt][nt][jj] + bs[nt] + bf2f(add_bf[(size_t)r * DIM_ + gcol]);
        Cb[(size_t)r * DIM_ + gcol] = f2bf(v);
      }
    }
  }
}

// ---------------- FC2 GEMM fp8: out = scatter(t8 @ W8^T + b2 + hres) -------
// 128x128 tile, BK=64 fp8 elems (64 B/row), LDS 16 KB total. 16B-slot
// swizzle d = c ^ ((r>>1)&3): staging 16B-contiguous, ds_read_b64 2-way
// (lanes r,r+8 broadcast). mfma_f32_16x16x32_fp8_fp8 (K=32, 8 elems/lane,
// same fragment geometry & C/D layout as bf16 16x16x32).
__global__ __launch_bounds__(256) void gemmf8_k(const unsigned char* __restrict__ A8,
                                                const unsigned char* __restrict__ B8,
                                                const float* __restrict__ bias,
                                                int nx,
                                                const short* __restrict__ add_bf,
                                                const int* __restrict__ rowmap,
                                                float* __restrict__ outf) {
  const int K = MLPD_;
  const int nwg = gridDim.x;
  const int q8 = nwg >> 3;
  const int wg = (blockIdx.x & 7) * q8 + (blockIdx.x >> 3);
  const int ntile = wg % nx, mtile = wg / nx;
  const int tid = threadIdx.x, wid = tid >> 6, lane = tid & 63;
  const int fq = lane >> 4, fr = lane & 15;
  const int wr = wid >> 1, wc = wid & 1;
  __shared__ __align__(16) unsigned char lA[128 * 64];
  __shared__ __align__(16) unsigned char lB[128 * 64];
  const int row0 = mtile * 128, col0 = ntile * 128;
  float bs[4];
#pragma unroll
  for (int nt = 0; nt < 4; ++nt) bs[nt] = bias[col0 + wc * 64 + nt * 16 + fr];
  f32x4 acc[4][4];
#pragma unroll
  for (int a = 0; a < 4; ++a)
#pragma unroll
    for (int c = 0; c < 4; ++c) acc[a][c] = (f32x4){0.f, 0.f, 0.f, 0.f};
  const int nkt = K >> 6;  // 24
  for (int kt = 0; kt < nkt; ++kt) {
    const int k0 = kt << 6;
    // 512 16B-groups per matrix; 2 per thread each
#pragma unroll
    for (int i = 0; i < 2; ++i) {
      int g = i * 256 + tid;
      int r = g >> 2, d = g & 3;
      int c = d ^ ((r >> 1) & 3);  // logical 16B-block held at slot d
      gload16(A8 + (size_t)(row0 + r) * K + k0 + c * 16, (char*)lA + (size_t)g * 16);
      gload16(B8 + (size_t)(col0 + r) * K + k0 + c * 16, (char*)lB + (size_t)g * 16);
    }
    __syncthreads();
#pragma unroll
    for (int ks = 0; ks < 2; ++ks) {
      long af[4], bfr[4];
      const int clog = ks * 2 + (fq >> 1);
      const int off = (fq & 1) * 8;
#pragma unroll
      for (int mt = 0; mt < 4; ++mt) {
        int r = wr * 64 + mt * 16 + fr;
        int d = clog ^ ((r >> 1) & 3);
        af[mt] = *(const long*)&lA[r * 64 + d * 16 + off];
      }
#pragma unroll
      for (int nt = 0; nt < 4; ++nt) {
        int r = wc * 64 + nt * 16 + fr;
        int d = clog ^ ((r >> 1) & 3);
        bfr[nt] = *(const long*)&lB[r * 64 + d * 16 + off];
      }
#pragma unroll
      for (int mt = 0; mt < 4; ++mt)
#pragma unroll
        for (int nt = 0; nt < 4; ++nt)
          acc[mt][nt] = __builtin_amdgcn_mfma_f32_16x16x32_fp8_fp8(
              af[mt], bfr[nt], acc[mt][nt], 0, 0, 0);
    }
    __syncthreads();
  }
#pragma unroll
  for (int mt = 0; mt < 4; ++mt) {
#pragma unroll
    for (int jj = 0; jj < 4; ++jj) {
      int r = row0 + wr * 64 + mt * 16 + fq * 4 + jj;
      int dmap = rowmap[r];
#pragma unroll
      for (int nt = 0; nt < 4; ++nt) {
        int gcol = col0 + wc * 64 + nt * 16 + fr;
        float v = acc[mt][nt][jj] + bs[nt] + bf2f(add_bf[(size_t)r * DIM_ + gcol]);
        if (dmap >= 0) outf[(size_t)dmap * DIM_ + gcol] = v;
      }
    }
  }
}

// ---------------- attention: one head per wave, XCD-grouped m ----------------
__global__ __launch_bounds__(256) void attn_k(const short* __restrict__ qkv,
                                              const unsigned* __restrict__ bitmap,
                                              const int* __restrict__ ip,
                                              short* __restrict__ o) {
  // bijective XCD swizzle: 4608 = 8 * 576; same-m triplets land on one XCD
  const int flat = (blockIdx.x & 7) * 576 + (blockIdx.x >> 3);
  const int m = flat / 3;
  const int h = (flat % 3) * 4 + (threadIdx.x >> 6);
  const int wid = threadIdx.x >> 6, lane = threadIdx.x & 63;
  const int fq = lane >> 4, fr = lane & 15;
  __shared__ __align__(16) short P[4][64 * 72];
  __shared__ __align__(16) short Vt[4][32 * 72];
  __shared__ unsigned char flags[64];
  if (threadIdx.x < 64) {
    int j = ip[m * 64 + threadIdx.x];
    flags[threadIdx.x] = (unsigned char)((bitmap[j >> 5] >> (j & 31)) & 1);
  }
  __syncthreads();
  const float scale = 0.17677669529663687f;
  int msk[4];
#pragma unroll
  for (int nt = 0; nt < 4; ++nt) msk[nt] = flags[nt * 16 + fr];

  const short* base = qkv + (size_t)m * 64 * QKVD_ + h * 96;
  f32x4 sacc[4][4];
#pragma unroll
  for (int a = 0; a < 4; ++a)
#pragma unroll
    for (int c = 0; c < 4; ++c) sacc[a][c] = (f32x4){0.f, 0.f, 0.f, 0.f};
  bf16x8 qa[4], kb[4];
#pragma unroll
  for (int mt = 0; mt < 4; ++mt)
    qa[mt] = *(const bf16x8*)(base + (size_t)(mt * 16 + fr) * QKVD_ + fq * 8);
#pragma unroll
  for (int nt = 0; nt < 4; ++nt)
    kb[nt] = *(const bf16x8*)(base + (size_t)(nt * 16 + fr) * QKVD_ + 32 + fq * 8);
#pragma unroll
  for (int mt = 0; mt < 4; ++mt)
#pragma unroll
    for (int nt = 0; nt < 4; ++nt)
      sacc[mt][nt] = mfma16(qa[mt], kb[nt], sacc[mt][nt]);
#pragma unroll
  for (int c = 0; c < 4; ++c) {
    bf16x8 vv = *(const bf16x8*)(base + (size_t)lane * QKVD_ + 64 + c * 8);
#pragma unroll
    for (int e = 0; e < 8; ++e) Vt[wid][(c * 8 + e) * 72 + lane] = vv[e];
  }
#pragma unroll
  for (int mt = 0; mt < 4; ++mt)
#pragma unroll
    for (int nt = 0; nt < 4; ++nt) {
      f32x4 sv = sacc[mt][nt];
#pragma unroll
      for (int jj = 0; jj < 4; ++jj)
        sv[jj] = msk[nt] ? -10000.0f : sv[jj] * scale;
      sacc[mt][nt] = sv;
    }
#pragma unroll
  for (int mt = 0; mt < 4; ++mt) {
#pragma unroll
    for (int jj = 0; jj < 4; ++jj) {
      float mx = sacc[mt][0][jj];
#pragma unroll
      for (int nt = 1; nt < 4; ++nt) mx = fmaxf(mx, sacc[mt][nt][jj]);
#pragma unroll
      for (int mm = 1; mm < 16; mm <<= 1) mx = fmaxf(mx, __shfl_xor(mx, mm, 64));
      float sm = 0.f;
      float p[4];
#pragma unroll
      for (int nt = 0; nt < 4; ++nt) {
        p[nt] = __expf(sacc[mt][nt][jj] - mx);
        sm += p[nt];
      }
#pragma unroll
      for (int mm = 1; mm < 16; mm <<= 1) sm += __shfl_xor(sm, mm, 64);
      float inv = 1.0f / sm;
      int rowb = (mt * 16 + fq * 4 + jj) * 72;
#pragma unroll
      for (int nt = 0; nt < 4; ++nt)
        P[wid][rowb + nt * 16 + fr] = f2bf(p[nt] * inv);
    }
  }
  f32x4 oacc[4][2];
#pragma unroll
  for (int a = 0; a < 4; ++a)
#pragma unroll
    for (int c = 0; c < 2; ++c) oacc[a][c] = (f32x4){0.f, 0.f, 0.f, 0.f};
#pragma unroll
  for (int ks = 0; ks < 2; ++ks) {
    bf16x8 pa[4], vb[2];
#pragma unroll
    for (int mt = 0; mt < 4; ++mt)
      pa[mt] = *(const bf16x8*)&P[wid][(mt * 16 + fr) * 72 + ks * 32 + fq * 8];
#pragma unroll
    for (int nd = 0; nd < 2; ++nd)
      vb[nd] = *(const bf16x8*)&Vt[wid][(nd * 16 + fr) * 72 + ks * 32 + fq * 8];
#pragma unroll
    for (int mt = 0; mt < 4; ++mt)
#pragma unroll
      for (int nd = 0; nd < 2; ++nd)
        oacc[mt][nd] = mfma16(pa[mt], vb[nd], oacc[mt][nd]);
  }
#pragma unroll
  for (int mt = 0; mt < 4; ++mt)
#pragma unroll
    for (int nd = 0; nd < 2; ++nd)
#pragma unroll
      for (int jj = 0; jj < 4; ++jj)
        o[(size_t)(m * 64 + mt * 16 + fq * 4 + jj) * DIM_ + h * 32 + nd * 16 + fr] =
            f2bf(oacc[mt][nd][jj]);
}

// ---------------- launch ----------------
extern "C" void kernel_launch(void* const* d_in, const int* in_sizes, int n_in,
                              void* d_out, int out_size, void* d_ws, size_t ws_size,
                              hipStream_t stream) {
  const float* x = (const float*)d_in[0];
  const int* iw = (const int*)d_in[1];
  const int* ip = (const int*)d_in[2];
  const int* blk = (const int*)d_in[3];
  const float* ln1w = (const float*)d_in[6];
  const float* ln1b = (const float*)d_in[7];
  const float* qkvw = (const float*)d_in[8];
  const float* qkvb = (const float*)d_in[9];
  const float* projw = (const float*)d_in[10];
  const float* projb = (const float*)d_in[11];
  const float* ln2w = (const float*)d_in[12];
  const float* ln2b = (const float*)d_in[13];
  const float* fc1w = (const float*)d_in[14];
  const float* fc1b = (const float*)d_in[15];
  const float* fc2w = (const float*)d_in[16];
  const float* fc2b = (const float*)d_in[17];
  float* out = (float*)d_out;

  char* ws = (char*)d_ws;
  short* w_all = (short*)ws;                 // 1,769,472 bf16
  short* w_qkv = w_all;
  short* w_proj = w_all + 442368;
  short* w_fc1 = w_all + 589824;
  int* inv_ip = (int*)(ws + 3538944);
  int* rowmap = inv_ip + NTOK_;
  int* win_rank = rowmap + NTOK_;
  unsigned* bitmap = (unsigned*)(win_rank + NW_);
  short* xp = (short*)(ws + 4349952);                        // 75.5 MB (also ln2 out)
  short* qkv_g = (short*)(ws + 4349952 + 75497472);          // qkv 226.5 MB / t8 151 MB
  unsigned char* t8 = (unsigned char*)qkv_g;                 // fp8 gelu (FC1 out)
  unsigned char* w2f8 = (unsigned char*)(ws + 306339840);    // 576 KB fp8 fc2w
  short* obuf = (short*)(ws + 381837312);                    // 75.5 MB
  short* hbuf = (short*)(ws + 457334784);                    // 75.5 MB
  short* ln2buf = xp;
  (void)in_sizes; (void)n_in; (void)out_size; (void)ws_size;

  mapA_k<<<12, 256, 0, stream>>>(win_rank, bitmap);
  mapB_k<<<39, 256, 0, stream>>>(iw, blk, win_rank, bitmap);
  mapC_k<<<NTOK_ / 256, 256, 0, stream>>>(ip, iw, bitmap, inv_ip, rowmap);
  wconv_k<<<1728, 256, 0, stream>>>(qkvw, projw, fc1w, fc2w, w_all);
  wconv8_k<<<576, 256, 0, stream>>>(fc2w, w2f8);
  ln1_k<<<(NW_ * 64) / 8, 256, 0, stream>>>(x, ln1w, ln1b, win_rank, inv_ip, bitmap,
                                            out, xp);
  // 256-row mtiles = 384; 128-row mtiles = 768
  gemm_k<0><<<384 * 9, 512, 0, stream>>>(xp, w_qkv, qkvb, 384, QKVD_, 9, qkv_g,
                                         nullptr);
  attn_k<<<WACT_ * 3, 256, 0, stream>>>(qkv_g, bitmap, ip, obuf);
  gemm128_k<<<768 * 3, 256, 0, stream>>>(obuf, w_proj, projb, 384, 3, hbuf, xp);
  ln2_k<<<NTOK_ / 8, 256, 0, stream>>>(hbuf, ln2w, ln2b, ln2buf);
  gemm_k<2><<<384 * 12, 512, 0, stream>>>(ln2buf, w_fc1, fc1b, 384, MLPD_, 12,
                                          nullptr, t8);
  gemmf8_k<<<768 * 3, 256, 0, stream>>>(t8, w2f8, fc2b, 3, hbuf, rowmap, out);
}

// Round 15
// 804.216 us; speedup vs baseline: 1.0720x; 1.0720x over previous
//
#include <hip/hip_runtime.h>
#include <hip/hip_bf16.h>

typedef __attribute__((ext_vector_type(8))) short bf16x8;
typedef __attribute__((ext_vector_type(4))) short s16x4;
typedef __attribute__((ext_vector_type(4))) float f32x4;

#define NW_   3072
#define WACT_ 1536
#define NTOK_ 98304
#define NBLK_ 9830
#define DIM_  384
#define QKVD_ 1152
#define MLPD_ 1536

__device__ __forceinline__ float bf2f(short s) {
  union { unsigned u; float f; } c;
  c.u = ((unsigned)(unsigned short)s) << 16;
  return c.f;
}
__device__ __forceinline__ short f2bf(float f) {
  union { float f; unsigned u; } c; c.f = f;
  unsigned lsb = (c.u >> 16) & 1u;
  c.u += 0x7fffu + lsb;
  return (short)(c.u >> 16);
}

__device__ __forceinline__ f32x4 mfma16(bf16x8 a, bf16x8 b, f32x4 c) {
  return __builtin_amdgcn_mfma_f32_16x16x32_bf16(a, b, c, 0, 0, 0);
}

__device__ __forceinline__ void gload16(const void* g, void* l) {
  __builtin_amdgcn_global_load_lds(
      (const __attribute__((address_space(1))) unsigned*)g,
      (__attribute__((address_space(3))) unsigned*)l, 16, 0, 0);
}

// ---------------- map kernels ----------------
__global__ __launch_bounds__(256) void mapA_k(int* win_rank, unsigned* bitmap) {
  int t = blockIdx.x * 256 + threadIdx.x;
  if (t < NW_) { win_rank[t] = -1; bitmap[t] = 0u; }
}

__global__ __launch_bounds__(256) void mapB_k(const int* __restrict__ iw,
                                              const int* __restrict__ blk,
                                              int* win_rank, unsigned* bitmap) {
  int t = blockIdx.x * 256 + threadIdx.x;
  if (t < WACT_) win_rank[iw[t]] = t;
  if (t < NBLK_) { int j = blk[t]; atomicOr(&bitmap[j >> 5], 1u << (j & 31)); }
}

__global__ __launch_bounds__(256) void mapC_k(const int* __restrict__ ip,
                                              const int* __restrict__ iw,
                                              const unsigned* __restrict__ bitmap,
                                              int* inv_ip, int* rowmap) {
  int i = blockIdx.x * 256 + threadIdx.x;
  if (i < NTOK_) {
    int j = ip[i];
    inv_ip[j] = i;
    int blocked = (bitmap[j >> 5] >> (j & 31)) & 1;
    rowmap[i] = blocked ? -1 : (iw[j >> 6] * 64 + (j & 63));
  }
}

// ---------------- weight conversion ----------------
__global__ __launch_bounds__(256) void wconv_k(const float* __restrict__ qkvw,
                                               const float* __restrict__ projw,
                                               const float* __restrict__ fc1w,
                                               const float* __restrict__ fc2w,
                                               short* __restrict__ dst) {
  int i = (blockIdx.x * 256 + threadIdx.x) * 4;  // total 1,769,472 elems
  f32x4 v;
  if (i < 442368) v = *(const f32x4*)&qkvw[i];
  else if (i < 589824) v = *(const f32x4*)&projw[i - 442368];
  else if (i < 1179648) v = *(const f32x4*)&fc1w[i - 589824];
  else v = *(const f32x4*)&fc2w[i - 1179648];
  s16x4 o;
#pragma unroll
  for (int e = 0; e < 4; ++e) o[e] = f2bf(v[e]);
  *(s16x4*)&dst[i] = o;
}

// fc2w -> fp8 e4m3 via HW cvt (589,824 elems)
__global__ __launch_bounds__(256) void wconv8_k(const float* __restrict__ fc2w,
                                                unsigned char* __restrict__ dst) {
  int i = (blockIdx.x * 256 + threadIdx.x) * 4;
  f32x4 v = *(const f32x4*)&fc2w[i];
  int w = __builtin_amdgcn_cvt_pk_fp8_f32(v[0], v[1], 0, false);
  w = __builtin_amdgcn_cvt_pk_fp8_f32(v[2], v[3], w, true);
  *(int*)&dst[i] = w;
}

// ---------------- LN1 + gather/permute (vectorized: 32 lanes/token) --------
__global__ __launch_bounds__(256) void ln1_k(const float* __restrict__ x,
                                             const float* __restrict__ w,
                                             const float* __restrict__ b,
                                             const int* __restrict__ win_rank,
                                             const int* __restrict__ inv_ip,
                                             const unsigned* __restrict__ bitmap,
                                             float* __restrict__ out,
                                             short* __restrict__ xp) {
  const int l = threadIdx.x & 31;
  const int tok = blockIdx.x * 8 + (threadIdx.x >> 5);
  const f32x4* xr = (const f32x4*)(x + (size_t)tok * DIM_);
  f32x4 v[3]; float s = 0.f;
#pragma unroll
  for (int j = 0; j < 3; ++j) {
    v[j] = xr[l + 32 * j];
    s += v[j][0] + v[j][1] + v[j][2] + v[j][3];
  }
#pragma unroll
  for (int m = 1; m <= 16; m <<= 1) s += __shfl_xor(s, m, 64);
  float mu = s * (1.0f / DIM_);
  float q = 0.f;
#pragma unroll
  for (int j = 0; j < 3; ++j)
#pragma unroll
    for (int e = 0; e < 4; ++e) { float d = v[j][e] - mu; q += d * d; }
#pragma unroll
  for (int m = 1; m <= 16; m <<= 1) q += __shfl_xor(q, m, 64);
  float rs = rsqrtf(q * (1.0f / DIM_) + 1e-5f);
  f32x4 y[3];
#pragma unroll
  for (int j = 0; j < 3; ++j) {
    f32x4 wv = *(const f32x4*)&w[4 * l + 128 * j];
    f32x4 bv = *(const f32x4*)&b[4 * l + 128 * j];
#pragma unroll
    for (int e = 0; e < 4; ++e) y[j][e] = (v[j][e] - mu) * rs * wv[e] + bv[e];
  }
  int wdw = tok >> 6, t = tok & 63;
  int rank = win_rank[wdw];
  if (rank < 0) {
    f32x4* po = (f32x4*)(out + (size_t)tok * DIM_);
#pragma unroll
    for (int j = 0; j < 3; ++j) po[l + 32 * j] = y[j];
  } else {
    int jdx = (rank << 6) + t;
    int i = inv_ip[jdx];
#pragma unroll
    for (int j = 0; j < 3; ++j) {
      s16x4 o;
#pragma unroll
      for (int e = 0; e < 4; ++e) o[e] = f2bf(y[j][e]);
      *(s16x4*)&xp[(size_t)i * DIM_ + 4 * l + 128 * j] = o;
    }
    if ((bitmap[jdx >> 5] >> (jdx & 31)) & 1) {
      f32x4* po = (f32x4*)(out + (size_t)tok * DIM_);
#pragma unroll
      for (int j = 0; j < 3; ++j) po[l + 32 * j] = y[j];
    }
  }
}

// ---------------- LN2 (vectorized: 32 lanes/token, short4) ----------------
__global__ __launch_bounds__(256) void ln2_k(const short* __restrict__ h,
                                             const float* __restrict__ w,
                                             const float* __restrict__ b,
                                             short* __restrict__ outln) {
  const int l = threadIdx.x & 31;
  const int tok = blockIdx.x * 8 + (threadIdx.x >> 5);
  const s16x4* xr = (const s16x4*)(h + (size_t)tok * DIM_);
  float v[12]; float s = 0.f;
#pragma unroll
  for (int j = 0; j < 3; ++j) {
    s16x4 rv = xr[l + 32 * j];
#pragma unroll
    for (int e = 0; e < 4; ++e) { v[j * 4 + e] = bf2f(rv[e]); s += v[j * 4 + e]; }
  }
#pragma unroll
  for (int m = 1; m <= 16; m <<= 1) s += __shfl_xor(s, m, 64);
  float mu = s * (1.0f / DIM_);
  float q = 0.f;
#pragma unroll
  for (int e = 0; e < 12; ++e) { float d = v[e] - mu; q += d * d; }
#pragma unroll
  for (int m = 1; m <= 16; m <<= 1) q += __shfl_xor(q, m, 64);
  float rs = rsqrtf(q * (1.0f / DIM_) + 1e-5f);
  s16x4* po = (s16x4*)(outln + (size_t)tok * DIM_);
#pragma unroll
  for (int j = 0; j < 3; ++j) {
    f32x4 wv = *(const f32x4*)&w[4 * l + 128 * j];
    f32x4 bv = *(const f32x4*)&b[4 * l + 128 * j];
    s16x4 o;
#pragma unroll
    for (int e = 0; e < 4; ++e)
      o[e] = f2bf((v[j * 4 + e] - mu) * rs * wv[e] + bv[e]);
    po[l + 32 * j] = o;
  }
}

// ---------------- GEMM: C = A * B^T (256x128 tile, 8 waves) ----------------
// Proven R10 structure: single-buffer LDS (48 KB), __syncthreads pipeline,
// XCD-chunk swizzle, bias in regs.
// EPI 0: +bias -> bf16 (ld N)              (QKV)
// EPI 2: +bias, fast gelu -> FP8 (HW cvt)  (fc1 -> t8, ld MLPD_)
template <int EPI>
__global__ __launch_bounds__(512) void gemm_k(const short* __restrict__ A,
                                              const short* __restrict__ B,
                                              const float* __restrict__ bias,
                                              int K, int N, int nx,
                                              short* __restrict__ Cb,
                                              unsigned char* __restrict__ C8) {
  const int nwg = gridDim.x;
  const int q8 = nwg >> 3;
  const int wg = (blockIdx.x & 7) * q8 + (blockIdx.x >> 3);
  const int ntile = wg % nx, mtile = wg / nx;
  const int tid = threadIdx.x, wid = tid >> 6, lane = tid & 63;
  const int fq = lane >> 4, fr = lane & 15;
  const int wr = wid >> 1, wc = wid & 1;  // 4(M) x 2(N) waves, 64x64 each
  __shared__ __align__(16) short lA[256 * 64];
  __shared__ __align__(16) short lB[128 * 64];
  const int row0 = mtile * 256, col0 = ntile * 128;
  float bs[4];
#pragma unroll
  for (int nt = 0; nt < 4; ++nt) bs[nt] = bias[col0 + wc * 64 + nt * 16 + fr];
  f32x4 acc[4][4];
#pragma unroll
  for (int a = 0; a < 4; ++a)
#pragma unroll
    for (int c = 0; c < 4; ++c) acc[a][c] = (f32x4){0.f, 0.f, 0.f, 0.f};
  const int nkt = K >> 6;
  for (int kt = 0; kt < nkt; ++kt) {
    const int k0 = kt << 6;
#pragma unroll
    for (int i = 0; i < 4; ++i) {
      int g = i * 512 + tid;
      int r = g >> 3, c8 = g & 7;
      int s8 = c8 ^ (r & 7);
      gload16(A + (size_t)(row0 + r) * K + k0 + s8 * 8, (char*)lA + (size_t)g * 16);
    }
#pragma unroll
    for (int i = 0; i < 2; ++i) {
      int g = i * 512 + tid;
      int r = g >> 3, c8 = g & 7;
      int s8 = c8 ^ (r & 7);
      gload16(B + (size_t)(col0 + r) * K + k0 + s8 * 8, (char*)lB + (size_t)g * 16);
    }
    __syncthreads();
#pragma unroll
    for (int ks = 0; ks < 2; ++ks) {
      bf16x8 af[4], bfr[4];
#pragma unroll
      for (int mt = 0; mt < 4; ++mt) {
        int r = wr * 64 + mt * 16 + fr;
        af[mt] = *(const bf16x8*)&lA[r * 64 + ((ks * 4 + fq) ^ (r & 7)) * 8];
      }
#pragma unroll
      for (int nt = 0; nt < 4; ++nt) {
        int r = wc * 64 + nt * 16 + fr;
        bfr[nt] = *(const bf16x8*)&lB[r * 64 + ((ks * 4 + fq) ^ (r & 7)) * 8];
      }
#pragma unroll
      for (int mt = 0; mt < 4; ++mt)
#pragma unroll
        for (int nt = 0; nt < 4; ++nt)
          acc[mt][nt] = mfma16(af[mt], bfr[nt], acc[mt][nt]);
    }
    __syncthreads();
  }
#pragma unroll
  for (int mt = 0; mt < 4; ++mt) {
#pragma unroll
    for (int jj = 0; jj < 4; ++jj) {
      int r = row0 + wr * 64 + mt * 16 + fq * 4 + jj;
      if (EPI == 0) {
#pragma unroll
        for (int nt = 0; nt < 4; ++nt) {
          int gcol = col0 + wc * 64 + nt * 16 + fr;
          Cb[(size_t)r * N + gcol] = f2bf(acc[mt][nt][jj] + bs[nt]);
        }
      } else {
        float g[4];
#pragma unroll
        for (int nt = 0; nt < 4; ++nt) {
          float v = acc[mt][nt][jj] + bs[nt];
          // gelu(x) ~= x * sigmoid(2u), u = 0.79788456*(x + 0.044715 x^3)
          float u = v * (0.79788456f + 0.03567741f * v * v);
          g[nt] = v * __builtin_amdgcn_rcpf(1.0f + __expf(-2.0f * u));
        }
        int p01 = __builtin_amdgcn_cvt_pk_fp8_f32(g[0], g[1], 0, false);
        int p23 = __builtin_amdgcn_cvt_pk_fp8_f32(g[2], g[3], 0, false);
        int base = col0 + wc * 64 + fr;
        C8[(size_t)r * MLPD_ + base]      = (unsigned char)(p01 & 0xff);
        C8[(size_t)r * MLPD_ + base + 16] = (unsigned char)((p01 >> 8) & 0xff);
        C8[(size_t)r * MLPD_ + base + 32] = (unsigned char)(p23 & 0xff);
        C8[(size_t)r * MLPD_ + base + 48] = (unsigned char)((p23 >> 8) & 0xff);
      }
    }
  }
}

// ---------------- GEMM 128x128 bf16 (proj) ----------------
// Proven R7 structure. +bias +add_bf -> bf16 (proj + residual -> h)
__global__ __launch_bounds__(256) void gemm128_k(const short* __restrict__ A,
                                                 const short* __restrict__ B,
                                                 const float* __restrict__ bias,
                                                 int K, int nx,
                                                 short* __restrict__ Cb,
                                                 const short* __restrict__ add_bf) {
  const int nwg = gridDim.x;
  const int q8 = nwg >> 3;
  const int wg = (blockIdx.x & 7) * q8 + (blockIdx.x >> 3);
  const int ntile = wg % nx, mtile = wg / nx;
  const int tid = threadIdx.x, wid = tid >> 6, lane = tid & 63;
  const int fq = lane >> 4, fr = lane & 15;
  const int wr = wid >> 1, wc = wid & 1;
  __shared__ __align__(16) short lA[128 * 64];
  __shared__ __align__(16) short lB[128 * 64];
  const int row0 = mtile * 128, col0 = ntile * 128;
  float bs[4];
#pragma unroll
  for (int nt = 0; nt < 4; ++nt) bs[nt] = bias[col0 + wc * 64 + nt * 16 + fr];
  f32x4 acc[4][4];
#pragma unroll
  for (int a = 0; a < 4; ++a)
#pragma unroll
    for (int c = 0; c < 4; ++c) acc[a][c] = (f32x4){0.f, 0.f, 0.f, 0.f};
  const int nkt = K >> 6;
  for (int kt = 0; kt < nkt; ++kt) {
    const int k0 = kt << 6;
#pragma unroll
    for (int i = 0; i < 4; ++i) {
      int cb = ((i * 4 + wid) << 6) + lane;
      int r = cb >> 3, c8 = cb & 7;
      int s8 = c8 ^ (r & 7);
      gload16(A + (size_t)(row0 + r) * K + k0 + s8 * 8,
              (char*)lA + (size_t)(i * 4 + wid) * 1024);
      gload16(B + (size_t)(col0 + r) * K + k0 + s8 * 8,
              (char*)lB + (size_t)(i * 4 + wid) * 1024);
    }
    __syncthreads();
#pragma unroll
    for (int ks = 0; ks < 2; ++ks) {
      bf16x8 af[4], bfr[4];
#pragma unroll
      for (int mt = 0; mt < 4; ++mt) {
        int r = wr * 64 + mt * 16 + fr;
        af[mt] = *(const bf16x8*)&lA[r * 64 + ((ks * 4 + fq) ^ (r & 7)) * 8];
      }
#pragma unroll
      for (int nt = 0; nt < 4; ++nt) {
        int r = wc * 64 + nt * 16 + fr;
        bfr[nt] = *(const bf16x8*)&lB[r * 64 + ((ks * 4 + fq) ^ (r & 7)) * 8];
      }
#pragma unroll
      for (int mt = 0; mt < 4; ++mt)
#pragma unroll
        for (int nt = 0; nt < 4; ++nt)
          acc[mt][nt] = mfma16(af[mt], bfr[nt], acc[mt][nt]);
    }
    __syncthreads();
  }
#pragma unroll
  for (int mt = 0; mt < 4; ++mt) {
#pragma unroll
    for (int jj = 0; jj < 4; ++jj) {
      int r = row0 + wr * 64 + mt * 16 + fq * 4 + jj;
#pragma unroll
      for (int nt = 0; nt < 4; ++nt) {
        int gcol = col0 + wc * 64 + nt * 16 + fr;
        float v = acc[mt][nt][jj] + bs[nt] + bf2f(add_bf[(size_t)r * DIM_ + gcol]);
        Cb[(size_t)r * DIM_ + gcol] = f2bf(v);
      }
    }
  }
}

// ---------------- FC2 GEMM fp8: out = scatter(t8 @ W8^T + b2 + hres) -------
// 128x128 tile, BK=64 fp8 elems (64 B/row), LDS 16 KB total. 16B-slot
// swizzle d = c ^ ((r>>1)&3). mfma_f32_16x16x32_fp8_fp8.
__global__ __launch_bounds__(256) void gemmf8_k(const unsigned char* __restrict__ A8,
                                                const unsigned char* __restrict__ B8,
                                                const float* __restrict__ bias,
                                                int nx,
                                                const short* __restrict__ add_bf,
                                                const int* __restrict__ rowmap,
                                                float* __restrict__ outf) {
  const int K = MLPD_;
  const int nwg = gridDim.x;
  const int q8 = nwg >> 3;
  const int wg = (blockIdx.x & 7) * q8 + (blockIdx.x >> 3);
  const int ntile = wg % nx, mtile = wg / nx;
  const int tid = threadIdx.x, wid = tid >> 6, lane = tid & 63;
  const int fq = lane >> 4, fr = lane & 15;
  const int wr = wid >> 1, wc = wid & 1;
  __shared__ __align__(16) unsigned char lA[128 * 64];
  __shared__ __align__(16) unsigned char lB[128 * 64];
  const int row0 = mtile * 128, col0 = ntile * 128;
  float bs[4];
#pragma unroll
  for (int nt = 0; nt < 4; ++nt) bs[nt] = bias[col0 + wc * 64 + nt * 16 + fr];
  f32x4 acc[4][4];
#pragma unroll
  for (int a = 0; a < 4; ++a)
#pragma unroll
    for (int c = 0; c < 4; ++c) acc[a][c] = (f32x4){0.f, 0.f, 0.f, 0.f};
  const int nkt = K >> 6;  // 24
  for (int kt = 0; kt < nkt; ++kt) {
    const int k0 = kt << 6;
    // 512 16B-groups per matrix; 2 per thread each
#pragma unroll
    for (int i = 0; i < 2; ++i) {
      int g = i * 256 + tid;
      int r = g >> 2, d = g & 3;
      int c = d ^ ((r >> 1) & 3);  // logical 16B-block held at slot d
      gload16(A8 + (size_t)(row0 + r) * K + k0 + c * 16, (char*)lA + (size_t)g * 16);
      gload16(B8 + (size_t)(col0 + r) * K + k0 + c * 16, (char*)lB + (size_t)g * 16);
    }
    __syncthreads();
#pragma unroll
    for (int ks = 0; ks < 2; ++ks) {
      long af[4], bfr[4];
      const int clog = ks * 2 + (fq >> 1);
      const int off = (fq & 1) * 8;
#pragma unroll
      for (int mt = 0; mt < 4; ++mt) {
        int r = wr * 64 + mt * 16 + fr;
        int d = clog ^ ((r >> 1) & 3);
        af[mt] = *(const long*)&lA[r * 64 + d * 16 + off];
      }
#pragma unroll
      for (int nt = 0; nt < 4; ++nt) {
        int r = wc * 64 + nt * 16 + fr;
        int d = clog ^ ((r >> 1) & 3);
        bfr[nt] = *(const long*)&lB[r * 64 + d * 16 + off];
      }
#pragma unroll
      for (int mt = 0; mt < 4; ++mt)
#pragma unroll
        for (int nt = 0; nt < 4; ++nt)
          acc[mt][nt] = __builtin_amdgcn_mfma_f32_16x16x32_fp8_fp8(
              af[mt], bfr[nt], acc[mt][nt], 0, 0, 0);
    }
    __syncthreads();
  }
#pragma unroll
  for (int mt = 0; mt < 4; ++mt) {
#pragma unroll
    for (int jj = 0; jj < 4; ++jj) {
      int r = row0 + wr * 64 + mt * 16 + fq * 4 + jj;
      int dmap = rowmap[r];
#pragma unroll
      for (int nt = 0; nt < 4; ++nt) {
        int gcol = col0 + wc * 64 + nt * 16 + fr;
        float v = acc[mt][nt][jj] + bs[nt] + bf2f(add_bf[(size_t)r * DIM_ + gcol]);
        if (dmap >= 0) outf[(size_t)dmap * DIM_ + gcol] = v;
      }
    }
  }
}

// ---------------- attention: one head per wave, XCD-grouped m ----------------
__global__ __launch_bounds__(256) void attn_k(const short* __restrict__ qkv,
                                              const unsigned* __restrict__ bitmap,
                                              const int* __restrict__ ip,
                                              short* __restrict__ o) {
  // bijective XCD swizzle: 4608 = 8 * 576; same-m triplets land on one XCD
  const int flat = (blockIdx.x & 7) * 576 + (blockIdx.x >> 3);
  const int m = flat / 3;
  const int h = (flat % 3) * 4 + (threadIdx.x >> 6);
  const int wid = threadIdx.x >> 6, lane = threadIdx.x & 63;
  const int fq = lane >> 4, fr = lane & 15;
  __shared__ __align__(16) short P[4][64 * 72];
  __shared__ __align__(16) short Vt[4][32 * 72];
  __shared__ unsigned char flags[64];
  if (threadIdx.x < 64) {
    int j = ip[m * 64 + threadIdx.x];
    flags[threadIdx.x] = (unsigned char)((bitmap[j >> 5] >> (j & 31)) & 1);
  }
  __syncthreads();
  const float scale = 0.17677669529663687f;
  int msk[4];
#pragma unroll
  for (int nt = 0; nt < 4; ++nt) msk[nt] = flags[nt * 16 + fr];

  const short* base = qkv + (size_t)m * 64 * QKVD_ + h * 96;
  f32x4 sacc[4][4];
#pragma unroll
  for (int a = 0; a < 4; ++a)
#pragma unroll
    for (int c = 0; c < 4; ++c) sacc[a][c] = (f32x4){0.f, 0.f, 0.f, 0.f};
  bf16x8 qa[4], kb[4];
#pragma unroll
  for (int mt = 0; mt < 4; ++mt)
    qa[mt] = *(const bf16x8*)(base + (size_t)(mt * 16 + fr) * QKVD_ + fq * 8);
#pragma unroll
  for (int nt = 0; nt < 4; ++nt)
    kb[nt] = *(const bf16x8*)(base + (size_t)(nt * 16 + fr) * QKVD_ + 32 + fq * 8);
#pragma unroll
  for (int mt = 0; mt < 4; ++mt)
#pragma unroll
    for (int nt = 0; nt < 4; ++nt)
      sacc[mt][nt] = mfma16(qa[mt], kb[nt], sacc[mt][nt]);
#pragma unroll
  for (int c = 0; c < 4; ++c) {
    bf16x8 vv = *(const bf16x8*)(base + (size_t)lane * QKVD_ + 64 + c * 8);
#pragma unroll
    for (int e = 0; e < 8; ++e) Vt[wid][(c * 8 + e) * 72 + lane] = vv[e];
  }
#pragma unroll
  for (int mt = 0; mt < 4; ++mt)
#pragma unroll
    for (int nt = 0; nt < 4; ++nt) {
      f32x4 sv = sacc[mt][nt];
#pragma unroll
      for (int jj = 0; jj < 4; ++jj)
        sv[jj] = msk[nt] ? -10000.0f : sv[jj] * scale;
      sacc[mt][nt] = sv;
    }
#pragma unroll
  for (int mt = 0; mt < 4; ++mt) {
#pragma unroll
    for (int jj = 0; jj < 4; ++jj) {
      float mx = sacc[mt][0][jj];
#pragma unroll
      for (int nt = 1; nt < 4; ++nt) mx = fmaxf(mx, sacc[mt][nt][jj]);
#pragma unroll
      for (int mm = 1; mm < 16; mm <<= 1) mx = fmaxf(mx, __shfl_xor(mx, mm, 64));
      float sm = 0.f;
      float p[4];
#pragma unroll
      for (int nt = 0; nt < 4; ++nt) {
        p[nt] = __expf(sacc[mt][nt][jj] - mx);
        sm += p[nt];
      }
#pragma unroll
      for (int mm = 1; mm < 16; mm <<= 1) sm += __shfl_xor(sm, mm, 64);
      float inv = 1.0f / sm;
      int rowb = (mt * 16 + fq * 4 + jj) * 72;
#pragma unroll
      for (int nt = 0; nt < 4; ++nt)
        P[wid][rowb + nt * 16 + fr] = f2bf(p[nt] * inv);
    }
  }
  f32x4 oacc[4][2];
#pragma unroll
  for (int a = 0; a < 4; ++a)
#pragma unroll
    for (int c = 0; c < 2; ++c) oacc[a][c] = (f32x4){0.f, 0.f, 0.f, 0.f};
#pragma unroll
  for (int ks = 0; ks < 2; ++ks) {
    bf16x8 pa[4], vb[2];
#pragma unroll
    for (int mt = 0; mt < 4; ++mt)
      pa[mt] = *(const bf16x8*)&P[wid][(mt * 16 + fr) * 72 + ks * 32 + fq * 8];
#pragma unroll
    for (int nd = 0; nd < 2; ++nd)
      vb[nd] = *(const bf16x8*)&Vt[wid][(nd * 16 + fr) * 72 + ks * 32 + fq * 8];
#pragma unroll
    for (int mt = 0; mt < 4; ++mt)
#pragma unroll
      for (int nd = 0; nd < 2; ++nd)
        oacc[mt][nd] = mfma16(pa[mt], vb[nd], oacc[mt][nd]);
  }
#pragma unroll
  for (int mt = 0; mt < 4; ++mt)
#pragma unroll
    for (int nd = 0; nd < 2; ++nd)
#pragma unroll
      for (int jj = 0; jj < 4; ++jj)
        o[(size_t)(m * 64 + mt * 16 + fq * 4 + jj) * DIM_ + h * 32 + nd * 16 + fr] =
            f2bf(oacc[mt][nd][jj]);
}

// ---------------- launch ----------------
extern "C" void kernel_launch(void* const* d_in, const int* in_sizes, int n_in,
                              void* d_out, int out_size, void* d_ws, size_t ws_size,
                              hipStream_t stream) {
  const float* x = (const float*)d_in[0];
  const int* iw = (const int*)d_in[1];
  const int* ip = (const int*)d_in[2];
  const int* blk = (const int*)d_in[3];
  const float* ln1w = (const float*)d_in[6];
  const float* ln1b = (const float*)d_in[7];
  const float* qkvw = (const float*)d_in[8];
  const float* qkvb = (const float*)d_in[9];
  const float* projw = (const float*)d_in[10];
  const float* projb = (const float*)d_in[11];
  const float* ln2w = (const float*)d_in[12];
  const float* ln2b = (const float*)d_in[13];
  const float* fc1w = (const float*)d_in[14];
  const float* fc1b = (const float*)d_in[15];
  const float* fc2w = (const float*)d_in[16];
  const float* fc2b = (const float*)d_in[17];
  float* out = (float*)d_out;

  char* ws = (char*)d_ws;
  short* w_all = (short*)ws;                 // 1,769,472 bf16
  short* w_qkv = w_all;
  short* w_proj = w_all + 442368;
  short* w_fc1 = w_all + 589824;
  int* inv_ip = (int*)(ws + 3538944);
  int* rowmap = inv_ip + NTOK_;
  int* win_rank = rowmap + NTOK_;
  unsigned* bitmap = (unsigned*)(win_rank + NW_);
  short* xp = (short*)(ws + 4349952);                        // 75.5 MB (also ln2 out)
  short* qkv_g = (short*)(ws + 4349952 + 75497472);          // qkv 226.5 MB / t8 151 MB
  unsigned char* t8 = (unsigned char*)qkv_g;                 // fp8 gelu (FC1 out)
  unsigned char* w2f8 = (unsigned char*)(ws + 306339840);    // 576 KB fp8 fc2w
  short* obuf = (short*)(ws + 381837312);                    // 75.5 MB
  short* hbuf = (short*)(ws + 457334784);                    // 75.5 MB
  short* ln2buf = xp;
  (void)in_sizes; (void)n_in; (void)out_size; (void)ws_size;

  mapA_k<<<12, 256, 0, stream>>>(win_rank, bitmap);
  mapB_k<<<39, 256, 0, stream>>>(iw, blk, win_rank, bitmap);
  mapC_k<<<NTOK_ / 256, 256, 0, stream>>>(ip, iw, bitmap, inv_ip, rowmap);
  wconv_k<<<1728, 256, 0, stream>>>(qkvw, projw, fc1w, fc2w, w_all);
  wconv8_k<<<576, 256, 0, stream>>>(fc2w, w2f8);
  ln1_k<<<(NW_ * 64) / 8, 256, 0, stream>>>(x, ln1w, ln1b, win_rank, inv_ip, bitmap,
                                            out, xp);
  // 256-row mtiles = 384; 128-row mtiles = 768
  gemm_k<0><<<384 * 9, 512, 0, stream>>>(xp, w_qkv, qkvb, 384, QKVD_, 9, qkv_g,
                                         nullptr);
  attn_k<<<WACT_ * 3, 256, 0, stream>>>(qkv_g, bitmap, ip, obuf);
  gemm128_k<<<768 * 3, 256, 0, stream>>>(obuf, w_proj, projb, 384, 3, hbuf, xp);
  ln2_k<<<NTOK_ / 8, 256, 0, stream>>>(hbuf, ln2w, ln2b, ln2buf);
  gemm_k<2><<<384 * 12, 512, 0, stream>>>(ln2buf, w_fc1, fc1b, 384, MLPD_, 12,
                                          nullptr, t8);
  gemmf8_k<<<768 * 3, 256, 0, stream>>>(t8, w2f8, fc2b, 3, hbuf, rowmap, out);
}

// Round 16
// 797.037 us; speedup vs baseline: 1.0817x; 1.0090x over previous
//
#include <hip/hip_runtime.h>
#include <hip/hip_bf16.h>

typedef __attribute__((ext_vector_type(8))) short bf16x8;
typedef __attribute__((ext_vector_type(4))) short s16x4;
typedef __attribute__((ext_vector_type(4))) float f32x4;

#define NW_   3072
#define WACT_ 1536
#define NTOK_ 98304
#define NBLK_ 9830
#define DIM_  384
#define QKVD_ 1152
#define MLPD_ 1536

__device__ __forceinline__ float bf2f(short s) {
  union { unsigned u; float f; } c;
  c.u = ((unsigned)(unsigned short)s) << 16;
  return c.f;
}
__device__ __forceinline__ short f2bf(float f) {
  union { float f; unsigned u; } c; c.f = f;
  unsigned lsb = (c.u >> 16) & 1u;
  c.u += 0x7fffu + lsb;
  return (short)(c.u >> 16);
}

__device__ __forceinline__ f32x4 mfma16(bf16x8 a, bf16x8 b, f32x4 c) {
  return __builtin_amdgcn_mfma_f32_16x16x32_bf16(a, b, c, 0, 0, 0);
}

__device__ __forceinline__ void gload16(const void* g, void* l) {
  __builtin_amdgcn_global_load_lds(
      (const __attribute__((address_space(1))) unsigned*)g,
      (__attribute__((address_space(3))) unsigned*)l, 16, 0, 0);
}

// ---------------- map kernels ----------------
__global__ __launch_bounds__(256) void mapA_k(int* win_rank, unsigned* bitmap) {
  int t = blockIdx.x * 256 + threadIdx.x;
  if (t < NW_) { win_rank[t] = -1; bitmap[t] = 0u; }
}

__global__ __launch_bounds__(256) void mapB_k(const int* __restrict__ iw,
                                              const int* __restrict__ blk,
                                              int* win_rank, unsigned* bitmap) {
  int t = blockIdx.x * 256 + threadIdx.x;
  if (t < WACT_) win_rank[iw[t]] = t;
  if (t < NBLK_) { int j = blk[t]; atomicOr(&bitmap[j >> 5], 1u << (j & 31)); }
}

__global__ __launch_bounds__(256) void mapC_k(const int* __restrict__ ip,
                                              const int* __restrict__ iw,
                                              const unsigned* __restrict__ bitmap,
                                              int* inv_ip, int* rowmap) {
  int i = blockIdx.x * 256 + threadIdx.x;
  if (i < NTOK_) {
    int j = ip[i];
    inv_ip[j] = i;
    int blocked = (bitmap[j >> 5] >> (j & 31)) & 1;
    rowmap[i] = blocked ? -1 : (iw[j >> 6] * 64 + (j & 63));
  }
}

// ---------------- weight conversion ----------------
__global__ __launch_bounds__(256) void wconv_k(const float* __restrict__ qkvw,
                                               const float* __restrict__ projw,
                                               const float* __restrict__ fc1w,
                                               const float* __restrict__ fc2w,
                                               short* __restrict__ dst) {
  int i = (blockIdx.x * 256 + threadIdx.x) * 4;  // total 1,769,472 elems
  f32x4 v;
  if (i < 442368) v = *(const f32x4*)&qkvw[i];
  else if (i < 589824) v = *(const f32x4*)&projw[i - 442368];
  else if (i < 1179648) v = *(const f32x4*)&fc1w[i - 589824];
  else v = *(const f32x4*)&fc2w[i - 1179648];
  s16x4 o;
#pragma unroll
  for (int e = 0; e < 4; ++e) o[e] = f2bf(v[e]);
  *(s16x4*)&dst[i] = o;
}

// fc2w -> fp8 e4m3 via HW cvt (589,824 elems)
__global__ __launch_bounds__(256) void wconv8_k(const float* __restrict__ fc2w,
                                                unsigned char* __restrict__ dst) {
  int i = (blockIdx.x * 256 + threadIdx.x) * 4;
  f32x4 v = *(const f32x4*)&fc2w[i];
  int w = __builtin_amdgcn_cvt_pk_fp8_f32(v[0], v[1], 0, false);
  w = __builtin_amdgcn_cvt_pk_fp8_f32(v[2], v[3], w, true);
  *(int*)&dst[i] = w;
}

// ---------------- LN1 + gather/permute (vectorized: 32 lanes/token) --------
__global__ __launch_bounds__(256) void ln1_k(const float* __restrict__ x,
                                             const float* __restrict__ w,
                                             const float* __restrict__ b,
                                             const int* __restrict__ win_rank,
                                             const int* __restrict__ inv_ip,
                                             const unsigned* __restrict__ bitmap,
                                             float* __restrict__ out,
                                             short* __restrict__ xp) {
  const int l = threadIdx.x & 31;
  const int tok = blockIdx.x * 8 + (threadIdx.x >> 5);
  const f32x4* xr = (const f32x4*)(x + (size_t)tok * DIM_);
  f32x4 v[3]; float s = 0.f;
#pragma unroll
  for (int j = 0; j < 3; ++j) {
    v[j] = xr[l + 32 * j];
    s += v[j][0] + v[j][1] + v[j][2] + v[j][3];
  }
#pragma unroll
  for (int m = 1; m <= 16; m <<= 1) s += __shfl_xor(s, m, 64);
  float mu = s * (1.0f / DIM_);
  float q = 0.f;
#pragma unroll
  for (int j = 0; j < 3; ++j)
#pragma unroll
    for (int e = 0; e < 4; ++e) { float d = v[j][e] - mu; q += d * d; }
#pragma unroll
  for (int m = 1; m <= 16; m <<= 1) q += __shfl_xor(q, m, 64);
  float rs = rsqrtf(q * (1.0f / DIM_) + 1e-5f);
  f32x4 y[3];
#pragma unroll
  for (int j = 0; j < 3; ++j) {
    f32x4 wv = *(const f32x4*)&w[4 * l + 128 * j];
    f32x4 bv = *(const f32x4*)&b[4 * l + 128 * j];
#pragma unroll
    for (int e = 0; e < 4; ++e) y[j][e] = (v[j][e] - mu) * rs * wv[e] + bv[e];
  }
  int wdw = tok >> 6, t = tok & 63;
  int rank = win_rank[wdw];
  if (rank < 0) {
    f32x4* po = (f32x4*)(out + (size_t)tok * DIM_);
#pragma unroll
    for (int j = 0; j < 3; ++j) po[l + 32 * j] = y[j];
  } else {
    int jdx = (rank << 6) + t;
    int i = inv_ip[jdx];
#pragma unroll
    for (int j = 0; j < 3; ++j) {
      s16x4 o;
#pragma unroll
      for (int e = 0; e < 4; ++e) o[e] = f2bf(y[j][e]);
      *(s16x4*)&xp[(size_t)i * DIM_ + 4 * l + 128 * j] = o;
    }
    if ((bitmap[jdx >> 5] >> (jdx & 31)) & 1) {
      f32x4* po = (f32x4*)(out + (size_t)tok * DIM_);
#pragma unroll
      for (int j = 0; j < 3; ++j) po[l + 32 * j] = y[j];
    }
  }
}

// ---------------- LN2 (vectorized: 32 lanes/token, short4) ----------------
__global__ __launch_bounds__(256) void ln2_k(const short* __restrict__ h,
                                             const float* __restrict__ w,
                                             const float* __restrict__ b,
                                             short* __restrict__ outln) {
  const int l = threadIdx.x & 31;
  const int tok = blockIdx.x * 8 + (threadIdx.x >> 5);
  const s16x4* xr = (const s16x4*)(h + (size_t)tok * DIM_);
  float v[12]; float s = 0.f;
#pragma unroll
  for (int j = 0; j < 3; ++j) {
    s16x4 rv = xr[l + 32 * j];
#pragma unroll
    for (int e = 0; e < 4; ++e) { v[j * 4 + e] = bf2f(rv[e]); s += v[j * 4 + e]; }
  }
#pragma unroll
  for (int m = 1; m <= 16; m <<= 1) s += __shfl_xor(s, m, 64);
  float mu = s * (1.0f / DIM_);
  float q = 0.f;
#pragma unroll
  for (int e = 0; e < 12; ++e) { float d = v[e] - mu; q += d * d; }
#pragma unroll
  for (int m = 1; m <= 16; m <<= 1) q += __shfl_xor(q, m, 64);
  float rs = rsqrtf(q * (1.0f / DIM_) + 1e-5f);
  s16x4* po = (s16x4*)(outln + (size_t)tok * DIM_);
#pragma unroll
  for (int j = 0; j < 3; ++j) {
    f32x4 wv = *(const f32x4*)&w[4 * l + 128 * j];
    f32x4 bv = *(const f32x4*)&b[4 * l + 128 * j];
    s16x4 o;
#pragma unroll
    for (int e = 0; e < 4; ++e)
      o[e] = f2bf((v[j * 4 + e] - mu) * rs * wv[e] + bv[e]);
    po[l + 32 * j] = o;
  }
}

// ---------------- GEMM: C = A * B^T (256x128 tile, 8 waves) ----------------
// Proven R10 structure: single-buffer LDS (48 KB), __syncthreads pipeline,
// XCD-chunk swizzle, bias in regs.
// EPI 0: +bias -> bf16 (ld N)              (QKV)
// EPI 2: +bias, fast gelu -> FP8 (HW cvt)  (fc1 -> t8, ld MLPD_)
template <int EPI>
__global__ __launch_bounds__(512) void gemm_k(const short* __restrict__ A,
                                              const short* __restrict__ B,
                                              const float* __restrict__ bias,
                                              int K, int N, int nx,
                                              short* __restrict__ Cb,
                                              unsigned char* __restrict__ C8) {
  const int nwg = gridDim.x;
  const int q8 = nwg >> 3;
  const int wg = (blockIdx.x & 7) * q8 + (blockIdx.x >> 3);
  const int ntile = wg % nx, mtile = wg / nx;
  const int tid = threadIdx.x, wid = tid >> 6, lane = tid & 63;
  const int fq = lane >> 4, fr = lane & 15;
  const int wr = wid >> 1, wc = wid & 1;  // 4(M) x 2(N) waves, 64x64 each
  __shared__ __align__(16) short lA[256 * 64];
  __shared__ __align__(16) short lB[128 * 64];
  const int row0 = mtile * 256, col0 = ntile * 128;
  float bs[4];
#pragma unroll
  for (int nt = 0; nt < 4; ++nt) bs[nt] = bias[col0 + wc * 64 + nt * 16 + fr];
  f32x4 acc[4][4];
#pragma unroll
  for (int a = 0; a < 4; ++a)
#pragma unroll
    for (int c = 0; c < 4; ++c) acc[a][c] = (f32x4){0.f, 0.f, 0.f, 0.f};
  const int nkt = K >> 6;
  for (int kt = 0; kt < nkt; ++kt) {
    const int k0 = kt << 6;
#pragma unroll
    for (int i = 0; i < 4; ++i) {
      int g = i * 512 + tid;
      int r = g >> 3, c8 = g & 7;
      int s8 = c8 ^ (r & 7);
      gload16(A + (size_t)(row0 + r) * K + k0 + s8 * 8, (char*)lA + (size_t)g * 16);
    }
#pragma unroll
    for (int i = 0; i < 2; ++i) {
      int g = i * 512 + tid;
      int r = g >> 3, c8 = g & 7;
      int s8 = c8 ^ (r & 7);
      gload16(B + (size_t)(col0 + r) * K + k0 + s8 * 8, (char*)lB + (size_t)g * 16);
    }
    __syncthreads();
#pragma unroll
    for (int ks = 0; ks < 2; ++ks) {
      bf16x8 af[4], bfr[4];
#pragma unroll
      for (int mt = 0; mt < 4; ++mt) {
        int r = wr * 64 + mt * 16 + fr;
        af[mt] = *(const bf16x8*)&lA[r * 64 + ((ks * 4 + fq) ^ (r & 7)) * 8];
      }
#pragma unroll
      for (int nt = 0; nt < 4; ++nt) {
        int r = wc * 64 + nt * 16 + fr;
        bfr[nt] = *(const bf16x8*)&lB[r * 64 + ((ks * 4 + fq) ^ (r & 7)) * 8];
      }
#pragma unroll
      for (int mt = 0; mt < 4; ++mt)
#pragma unroll
        for (int nt = 0; nt < 4; ++nt)
          acc[mt][nt] = mfma16(af[mt], bfr[nt], acc[mt][nt]);
    }
    __syncthreads();
  }
#pragma unroll
  for (int mt = 0; mt < 4; ++mt) {
#pragma unroll
    for (int jj = 0; jj < 4; ++jj) {
      int r = row0 + wr * 64 + mt * 16 + fq * 4 + jj;
      if (EPI == 0) {
#pragma unroll
        for (int nt = 0; nt < 4; ++nt) {
          int gcol = col0 + wc * 64 + nt * 16 + fr;
          Cb[(size_t)r * N + gcol] = f2bf(acc[mt][nt][jj] + bs[nt]);
        }
      } else {
        float g[4];
#pragma unroll
        for (int nt = 0; nt < 4; ++nt) {
          float v = acc[mt][nt][jj] + bs[nt];
          // gelu(x) ~= x * sigmoid(2u), u = 0.79788456*(x + 0.044715 x^3)
          float u = v * (0.79788456f + 0.03567741f * v * v);
          g[nt] = v * __builtin_amdgcn_rcpf(1.0f + __expf(-2.0f * u));
        }
        int p01 = __builtin_amdgcn_cvt_pk_fp8_f32(g[0], g[1], 0, false);
        int p23 = __builtin_amdgcn_cvt_pk_fp8_f32(g[2], g[3], 0, false);
        int base = col0 + wc * 64 + fr;
        C8[(size_t)r * MLPD_ + base]      = (unsigned char)(p01 & 0xff);
        C8[(size_t)r * MLPD_ + base + 16] = (unsigned char)((p01 >> 8) & 0xff);
        C8[(size_t)r * MLPD_ + base + 32] = (unsigned char)(p23 & 0xff);
        C8[(size_t)r * MLPD_ + base + 48] = (unsigned char)((p23 >> 8) & 0xff);
      }
    }
  }
}

// ---------------- GEMM 128x128 bf16 (proj) ----------------
// Proven R7 structure. +bias +add_bf -> bf16 (proj + residual -> h)
__global__ __launch_bounds__(256) void gemm128_k(const short* __restrict__ A,
                                                 const short* __restrict__ B,
                                                 const float* __restrict__ bias,
                                                 int K, int nx,
                                                 short* __restrict__ Cb,
                                                 const short* __restrict__ add_bf) {
  const int nwg = gridDim.x;
  const int q8 = nwg >> 3;
  const int wg = (blockIdx.x & 7) * q8 + (blockIdx.x >> 3);
  const int ntile = wg % nx, mtile = wg / nx;
  const int tid = threadIdx.x, wid = tid >> 6, lane = tid & 63;
  const int fq = lane >> 4, fr = lane & 15;
  const int wr = wid >> 1, wc = wid & 1;
  __shared__ __align__(16) short lA[128 * 64];
  __shared__ __align__(16) short lB[128 * 64];
  const int row0 = mtile * 128, col0 = ntile * 128;
  float bs[4];
#pragma unroll
  for (int nt = 0; nt < 4; ++nt) bs[nt] = bias[col0 + wc * 64 + nt * 16 + fr];
  f32x4 acc[4][4];
#pragma unroll
  for (int a = 0; a < 4; ++a)
#pragma unroll
    for (int c = 0; c < 4; ++c) acc[a][c] = (f32x4){0.f, 0.f, 0.f, 0.f};
  const int nkt = K >> 6;
  for (int kt = 0; kt < nkt; ++kt) {
    const int k0 = kt << 6;
#pragma unroll
    for (int i = 0; i < 4; ++i) {
      int cb = ((i * 4 + wid) << 6) + lane;
      int r = cb >> 3, c8 = cb & 7;
      int s8 = c8 ^ (r & 7);
      gload16(A + (size_t)(row0 + r) * K + k0 + s8 * 8,
              (char*)lA + (size_t)(i * 4 + wid) * 1024);
      gload16(B + (size_t)(col0 + r) * K + k0 + s8 * 8,
              (char*)lB + (size_t)(i * 4 + wid) * 1024);
    }
    __syncthreads();
#pragma unroll
    for (int ks = 0; ks < 2; ++ks) {
      bf16x8 af[4], bfr[4];
#pragma unroll
      for (int mt = 0; mt < 4; ++mt) {
        int r = wr * 64 + mt * 16 + fr;
        af[mt] = *(const bf16x8*)&lA[r * 64 + ((ks * 4 + fq) ^ (r & 7)) * 8];
      }
#pragma unroll
      for (int nt = 0; nt < 4; ++nt) {
        int r = wc * 64 + nt * 16 + fr;
        bfr[nt] = *(const bf16x8*)&lB[r * 64 + ((ks * 4 + fq) ^ (r & 7)) * 8];
      }
#pragma unroll
      for (int mt = 0; mt < 4; ++mt)
#pragma unroll
        for (int nt = 0; nt < 4; ++nt)
          acc[mt][nt] = mfma16(af[mt], bfr[nt], acc[mt][nt]);
    }
    __syncthreads();
  }
#pragma unroll
  for (int mt = 0; mt < 4; ++mt) {
#pragma unroll
    for (int jj = 0; jj < 4; ++jj) {
      int r = row0 + wr * 64 + mt * 16 + fq * 4 + jj;
#pragma unroll
      for (int nt = 0; nt < 4; ++nt) {
        int gcol = col0 + wc * 64 + nt * 16 + fr;
        float v = acc[mt][nt][jj] + bs[nt] + bf2f(add_bf[(size_t)r * DIM_ + gcol]);
        Cb[(size_t)r * DIM_ + gcol] = f2bf(v);
      }
    }
  }
}

// ---------------- FC2 GEMM fp8: out = scatter(t8 @ W8^T + b2 + hres) -------
// 128x128 tile, BK=128 fp8 elems (128 B/row -> byte-identical geometry to
// the proven bf16 tile; swizzle c8^(r&7) measured 0 bank conflicts). LDS
// 32 KB total, 12 K-tiles. mfma_f32_16x16x32_fp8_fp8, 4 K-steps/tile.
__global__ __launch_bounds__(256) void gemmf8_k(const unsigned char* __restrict__ A8,
                                                const unsigned char* __restrict__ B8,
                                                const float* __restrict__ bias,
                                                int nx,
                                                const short* __restrict__ add_bf,
                                                const int* __restrict__ rowmap,
                                                float* __restrict__ outf) {
  const int K = MLPD_;
  const int nwg = gridDim.x;
  const int q8 = nwg >> 3;
  const int wg = (blockIdx.x & 7) * q8 + (blockIdx.x >> 3);
  const int ntile = wg % nx, mtile = wg / nx;
  const int tid = threadIdx.x, wid = tid >> 6, lane = tid & 63;
  const int fq = lane >> 4, fr = lane & 15;
  const int wr = wid >> 1, wc = wid & 1;
  __shared__ __align__(16) unsigned char lA[128 * 128];
  __shared__ __align__(16) unsigned char lB[128 * 128];
  const int row0 = mtile * 128, col0 = ntile * 128;
  float bs[4];
#pragma unroll
  for (int nt = 0; nt < 4; ++nt) bs[nt] = bias[col0 + wc * 64 + nt * 16 + fr];
  f32x4 acc[4][4];
#pragma unroll
  for (int a = 0; a < 4; ++a)
#pragma unroll
    for (int c = 0; c < 4; ++c) acc[a][c] = (f32x4){0.f, 0.f, 0.f, 0.f};
  const int nkt = K >> 7;  // 12
  for (int kt = 0; kt < nkt; ++kt) {
    const int k0 = kt << 7;
    // 1024 16B-groups per matrix; 4 per thread each
#pragma unroll
    for (int i = 0; i < 4; ++i) {
      int g = i * 256 + tid;
      int r = g >> 3, c8 = g & 7;
      int s8 = c8 ^ (r & 7);
      gload16(A8 + (size_t)(row0 + r) * K + k0 + s8 * 16, (char*)lA + (size_t)g * 16);
      gload16(B8 + (size_t)(col0 + r) * K + k0 + s8 * 16, (char*)lB + (size_t)g * 16);
    }
    __syncthreads();
#pragma unroll
    for (int ksi = 0; ksi < 4; ++ksi) {
      long af[4], bfr[4];
      const int clog = ksi * 2 + (fq >> 1);
      const int off = (fq & 1) * 8;
#pragma unroll
      for (int mt = 0; mt < 4; ++mt) {
        int r = wr * 64 + mt * 16 + fr;
        int d = clog ^ (r & 7);
        af[mt] = *(const long*)&lA[r * 128 + d * 16 + off];
      }
#pragma unroll
      for (int nt = 0; nt < 4; ++nt) {
        int r = wc * 64 + nt * 16 + fr;
        int d = clog ^ (r & 7);
        bfr[nt] = *(const long*)&lB[r * 128 + d * 16 + off];
      }
#pragma unroll
      for (int mt = 0; mt < 4; ++mt)
#pragma unroll
        for (int nt = 0; nt < 4; ++nt)
          acc[mt][nt] = __builtin_amdgcn_mfma_f32_16x16x32_fp8_fp8(
              af[mt], bfr[nt], acc[mt][nt], 0, 0, 0);
    }
    __syncthreads();
  }
#pragma unroll
  for (int mt = 0; mt < 4; ++mt) {
#pragma unroll
    for (int jj = 0; jj < 4; ++jj) {
      int r = row0 + wr * 64 + mt * 16 + fq * 4 + jj;
      int dmap = rowmap[r];
#pragma unroll
      for (int nt = 0; nt < 4; ++nt) {
        int gcol = col0 + wc * 64 + nt * 16 + fr;
        float v = acc[mt][nt][jj] + bs[nt] + bf2f(add_bf[(size_t)r * DIM_ + gcol]);
        if (dmap >= 0) outf[(size_t)dmap * DIM_ + gcol] = v;
      }
    }
  }
}

// ---------------- attention: one head per wave, XCD-grouped m ----------------
__global__ __launch_bounds__(256) void attn_k(const short* __restrict__ qkv,
                                              const unsigned* __restrict__ bitmap,
                                              const int* __restrict__ ip,
                                              short* __restrict__ o) {
  // bijective XCD swizzle: 4608 = 8 * 576; same-m triplets land on one XCD
  const int flat = (blockIdx.x & 7) * 576 + (blockIdx.x >> 3);
  const int m = flat / 3;
  const int h = (flat % 3) * 4 + (threadIdx.x >> 6);
  const int wid = threadIdx.x >> 6, lane = threadIdx.x & 63;
  const int fq = lane >> 4, fr = lane & 15;
  __shared__ __align__(16) short P[4][64 * 72];
  __shared__ __align__(16) short Vt[4][32 * 72];
  __shared__ unsigned char flags[64];
  if (threadIdx.x < 64) {
    int j = ip[m * 64 + threadIdx.x];
    flags[threadIdx.x] = (unsigned char)((bitmap[j >> 5] >> (j & 31)) & 1);
  }
  __syncthreads();
  const float scale = 0.17677669529663687f;
  int msk[4];
#pragma unroll
  for (int nt = 0; nt < 4; ++nt) msk[nt] = flags[nt * 16 + fr];

  const short* base = qkv + (size_t)m * 64 * QKVD_ + h * 96;
  f32x4 sacc[4][4];
#pragma unroll
  for (int a = 0; a < 4; ++a)
#pragma unroll
    for (int c = 0; c < 4; ++c) sacc[a][c] = (f32x4){0.f, 0.f, 0.f, 0.f};
  bf16x8 qa[4], kb[4];
#pragma unroll
  for (int mt = 0; mt < 4; ++mt)
    qa[mt] = *(const bf16x8*)(base + (size_t)(mt * 16 + fr) * QKVD_ + fq * 8);
#pragma unroll
  for (int nt = 0; nt < 4; ++nt)
    kb[nt] = *(const bf16x8*)(base + (size_t)(nt * 16 + fr) * QKVD_ + 32 + fq * 8);
#pragma unroll
  for (int mt = 0; mt < 4; ++mt)
#pragma unroll
    for (int nt = 0; nt < 4; ++nt)
      sacc[mt][nt] = mfma16(qa[mt], kb[nt], sacc[mt][nt]);
#pragma unroll
  for (int c = 0; c < 4; ++c) {
    bf16x8 vv = *(const bf16x8*)(base + (size_t)lane * QKVD_ + 64 + c * 8);
#pragma unroll
    for (int e = 0; e < 8; ++e) Vt[wid][(c * 8 + e) * 72 + lane] = vv[e];
  }
#pragma unroll
  for (int mt = 0; mt < 4; ++mt)
#pragma unroll
    for (int nt = 0; nt < 4; ++nt) {
      f32x4 sv = sacc[mt][nt];
#pragma unroll
      for (int jj = 0; jj < 4; ++jj)
        sv[jj] = msk[nt] ? -10000.0f : sv[jj] * scale;
      sacc[mt][nt] = sv;
    }
#pragma unroll
  for (int mt = 0; mt < 4; ++mt) {
#pragma unroll
    for (int jj = 0; jj < 4; ++jj) {
      float mx = sacc[mt][0][jj];
#pragma unroll
      for (int nt = 1; nt < 4; ++nt) mx = fmaxf(mx, sacc[mt][nt][jj]);
#pragma unroll
      for (int mm = 1; mm < 16; mm <<= 1) mx = fmaxf(mx, __shfl_xor(mx, mm, 64));
      float sm = 0.f;
      float p[4];
#pragma unroll
      for (int nt = 0; nt < 4; ++nt) {
        p[nt] = __expf(sacc[mt][nt][jj] - mx);
        sm += p[nt];
      }
#pragma unroll
      for (int mm = 1; mm < 16; mm <<= 1) sm += __shfl_xor(sm, mm, 64);
      float inv = 1.0f / sm;
      int rowb = (mt * 16 + fq * 4 + jj) * 72;
#pragma unroll
      for (int nt = 0; nt < 4; ++nt)
        P[wid][rowb + nt * 16 + fr] = f2bf(p[nt] * inv);
    }
  }
  f32x4 oacc[4][2];
#pragma unroll
  for (int a = 0; a < 4; ++a)
#pragma unroll
    for (int c = 0; c < 2; ++c) oacc[a][c] = (f32x4){0.f, 0.f, 0.f, 0.f};
#pragma unroll
  for (int ks = 0; ks < 2; ++ks) {
    bf16x8 pa[4], vb[2];
#pragma unroll
    for (int mt = 0; mt < 4; ++mt)
      pa[mt] = *(const bf16x8*)&P[wid][(mt * 16 + fr) * 72 + ks * 32 + fq * 8];
#pragma unroll
    for (int nd = 0; nd < 2; ++nd)
      vb[nd] = *(const bf16x8*)&Vt[wid][(nd * 16 + fr) * 72 + ks * 32 + fq * 8];
#pragma unroll
    for (int mt = 0; mt < 4; ++mt)
#pragma unroll
      for (int nd = 0; nd < 2; ++nd)
        oacc[mt][nd] = mfma16(pa[mt], vb[nd], oacc[mt][nd]);
  }
#pragma unroll
  for (int mt = 0; mt < 4; ++mt)
#pragma unroll
    for (int nd = 0; nd < 2; ++nd)
#pragma unroll
      for (int jj = 0; jj < 4; ++jj)
        o[(size_t)(m * 64 + mt * 16 + fq * 4 + jj) * DIM_ + h * 32 + nd * 16 + fr] =
            f2bf(oacc[mt][nd][jj]);
}

// ---------------- launch ----------------
extern "C" void kernel_launch(void* const* d_in, const int* in_sizes, int n_in,
                              void* d_out, int out_size, void* d_ws, size_t ws_size,
                              hipStream_t stream) {
  const float* x = (const float*)d_in[0];
  const int* iw = (const int*)d_in[1];
  const int* ip = (const int*)d_in[2];
  const int* blk = (const int*)d_in[3];
  const float* ln1w = (const float*)d_in[6];
  const float* ln1b = (const float*)d_in[7];
  const float* qkvw = (const float*)d_in[8];
  const float* qkvb = (const float*)d_in[9];
  const float* projw = (const float*)d_in[10];
  const float* projb = (const float*)d_in[11];
  const float* ln2w = (const float*)d_in[12];
  const float* ln2b = (const float*)d_in[13];
  const float* fc1w = (const float*)d_in[14];
  const float* fc1b = (const float*)d_in[15];
  const float* fc2w = (const float*)d_in[16];
  const float* fc2b = (const float*)d_in[17];
  float* out = (float*)d_out;

  char* ws = (char*)d_ws;
  short* w_all = (short*)ws;                 // 1,769,472 bf16
  short* w_qkv = w_all;
  short* w_proj = w_all + 442368;
  short* w_fc1 = w_all + 589824;
  int* inv_ip = (int*)(ws + 3538944);
  int* rowmap = inv_ip + NTOK_;
  int* win_rank = rowmap + NTOK_;
  unsigned* bitmap = (unsigned*)(win_rank + NW_);
  short* xp = (short*)(ws + 4349952);                        // 75.5 MB (also ln2 out)
  short* qkv_g = (short*)(ws + 4349952 + 75497472);          // qkv 226.5 MB / t8 151 MB
  unsigned char* t8 = (unsigned char*)qkv_g;                 // fp8 gelu (FC1 out)
  unsigned char* w2f8 = (unsigned char*)(ws + 306339840);    // 576 KB fp8 fc2w
  short* obuf = (short*)(ws + 381837312);                    // 75.5 MB
  short* hbuf = (short*)(ws + 457334784);                    // 75.5 MB
  short* ln2buf = xp;
  (void)in_sizes; (void)n_in; (void)out_size; (void)ws_size;

  mapA_k<<<12, 256, 0, stream>>>(win_rank, bitmap);
  mapB_k<<<39, 256, 0, stream>>>(iw, blk, win_rank, bitmap);
  mapC_k<<<NTOK_ / 256, 256, 0, stream>>>(ip, iw, bitmap, inv_ip, rowmap);
  wconv_k<<<1728, 256, 0, stream>>>(qkvw, projw, fc1w, fc2w, w_all);
  wconv8_k<<<576, 256, 0, stream>>>(fc2w, w2f8);
  ln1_k<<<(NW_ * 64) / 8, 256, 0, stream>>>(x, ln1w, ln1b, win_rank, inv_ip, bitmap,
                                            out, xp);
  // 256-row mtiles = 384; 128-row mtiles = 768
  gemm_k<0><<<384 * 9, 512, 0, stream>>>(xp, w_qkv, qkvb, 384, QKVD_, 9, qkv_g,
                                         nullptr);
  attn_k<<<WACT_ * 3, 256, 0, stream>>>(qkv_g, bitmap, ip, obuf);
  gemm128_k<<<768 * 3, 256, 0, stream>>>(obuf, w_proj, projb, 384, 3, hbuf, xp);
  ln2_k<<<NTOK_ / 8, 256, 0, stream>>>(hbuf, ln2w, ln2b, ln2buf);
  gemm_k<2><<<384 * 12, 512, 0, stream>>>(ln2buf, w_fc1, fc1b, 384, MLPD_, 12,
                                          nullptr, t8);
  gemmf8_k<<<768 * 3, 256, 0, stream>>>(t8, w2f8, fc2b, 3, hbuf, rowmap, out);
}

// Round 17
// 786.435 us; speedup vs baseline: 1.0963x; 1.0135x over previous
//
#include <hip/hip_runtime.h>
#include <hip/hip_bf16.h>

typedef __attribute__((ext_vector_type(8))) short bf16x8;
typedef __attribute__((ext_vector_type(4))) short s16x4;
typedef __attribute__((ext_vector_type(4))) float f32x4;
typedef __attribute__((ext_vector_type(2))) long longx2;

#define NW_   3072
#define WACT_ 1536
#define NTOK_ 98304
#define NBLK_ 9830
#define DIM_  384
#define QKVD_ 1152
#define MLPD_ 1536

__device__ __forceinline__ float bf2f(short s) {
  union { unsigned u; float f; } c;
  c.u = ((unsigned)(unsigned short)s) << 16;
  return c.f;
}
__device__ __forceinline__ short f2bf(float f) {
  union { float f; unsigned u; } c; c.f = f;
  unsigned lsb = (c.u >> 16) & 1u;
  c.u += 0x7fffu + lsb;
  return (short)(c.u >> 16);
}

__device__ __forceinline__ f32x4 mfma16(bf16x8 a, bf16x8 b, f32x4 c) {
  return __builtin_amdgcn_mfma_f32_16x16x32_bf16(a, b, c, 0, 0, 0);
}

__device__ __forceinline__ void gload16(const void* g, void* l) {
  __builtin_amdgcn_global_load_lds(
      (const __attribute__((address_space(1))) unsigned*)g,
      (__attribute__((address_space(3))) unsigned*)l, 16, 0, 0);
}

// ---------------- map kernels ----------------
__global__ __launch_bounds__(256) void mapA_k(int* win_rank, unsigned* bitmap) {
  int t = blockIdx.x * 256 + threadIdx.x;
  if (t < NW_) { win_rank[t] = -1; bitmap[t] = 0u; }
}

__global__ __launch_bounds__(256) void mapB_k(const int* __restrict__ iw,
                                              const int* __restrict__ blk,
                                              int* win_rank, unsigned* bitmap) {
  int t = blockIdx.x * 256 + threadIdx.x;
  if (t < WACT_) win_rank[iw[t]] = t;
  if (t < NBLK_) { int j = blk[t]; atomicOr(&bitmap[j >> 5], 1u << (j & 31)); }
}

__global__ __launch_bounds__(256) void mapC_k(const int* __restrict__ ip,
                                              const int* __restrict__ iw,
                                              const unsigned* __restrict__ bitmap,
                                              int* inv_ip, int* rowmap) {
  int i = blockIdx.x * 256 + threadIdx.x;
  if (i < NTOK_) {
    int j = ip[i];
    inv_ip[j] = i;
    int blocked = (bitmap[j >> 5] >> (j & 31)) & 1;
    rowmap[i] = blocked ? -1 : (iw[j >> 6] * 64 + (j & 63));
  }
}

// ---------------- weight conversion ----------------
__global__ __launch_bounds__(256) void wconv_k(const float* __restrict__ qkvw,
                                               const float* __restrict__ projw,
                                               const float* __restrict__ fc1w,
                                               const float* __restrict__ fc2w,
                                               short* __restrict__ dst) {
  int i = (blockIdx.x * 256 + threadIdx.x) * 4;  // total 1,769,472 elems
  f32x4 v;
  if (i < 442368) v = *(const f32x4*)&qkvw[i];
  else if (i < 589824) v = *(const f32x4*)&projw[i - 442368];
  else if (i < 1179648) v = *(const f32x4*)&fc1w[i - 589824];
  else v = *(const f32x4*)&fc2w[i - 1179648];
  s16x4 o;
#pragma unroll
  for (int e = 0; e < 4; ++e) o[e] = f2bf(v[e]);
  *(s16x4*)&dst[i] = o;
}

// fc2w -> fp8 e4m3 (HW cvt), K-PERMUTED: within each 64B group, 8B-chunk
// l -> slot ((l&3)<<1)|(l>>2). Thread handles one 8B chunk.
__global__ __launch_bounds__(256) void wconv8_k(const float* __restrict__ fc2w,
                                                unsigned char* __restrict__ dst) {
  int i = (blockIdx.x * 256 + threadIdx.x) * 8;  // 589824 / 8 -> 288 blocks
  f32x4 v0 = *(const f32x4*)&fc2w[i];
  f32x4 v1 = *(const f32x4*)&fc2w[i + 4];
  int w0 = __builtin_amdgcn_cvt_pk_fp8_f32(v0[0], v0[1], 0, false);
  w0 = __builtin_amdgcn_cvt_pk_fp8_f32(v0[2], v0[3], w0, true);
  int w1 = __builtin_amdgcn_cvt_pk_fp8_f32(v1[0], v1[1], 0, false);
  w1 = __builtin_amdgcn_cvt_pk_fp8_f32(v1[2], v1[3], w1, true);
  int kro = i % MLPD_, row = i / MLPD_;
  int g = kro >> 6, l = (kro >> 3) & 7;
  int s = ((l & 3) << 1) | (l >> 2);
  union { int u[2]; long ll; } p; p.u[0] = w0; p.u[1] = w1;
  *(long*)&dst[(size_t)row * MLPD_ + g * 64 + s * 8] = p.ll;
}

// ---------------- LN1 + gather/permute (vectorized: 32 lanes/token) --------
__global__ __launch_bounds__(256) void ln1_k(const float* __restrict__ x,
                                             const float* __restrict__ w,
                                             const float* __restrict__ b,
                                             const int* __restrict__ win_rank,
                                             const int* __restrict__ inv_ip,
                                             const unsigned* __restrict__ bitmap,
                                             float* __restrict__ out,
                                             short* __restrict__ xp) {
  const int l = threadIdx.x & 31;
  const int tok = blockIdx.x * 8 + (threadIdx.x >> 5);
  const f32x4* xr = (const f32x4*)(x + (size_t)tok * DIM_);
  f32x4 v[3]; float s = 0.f;
#pragma unroll
  for (int j = 0; j < 3; ++j) {
    v[j] = xr[l + 32 * j];
    s += v[j][0] + v[j][1] + v[j][2] + v[j][3];
  }
#pragma unroll
  for (int m = 1; m <= 16; m <<= 1) s += __shfl_xor(s, m, 64);
  float mu = s * (1.0f / DIM_);
  float q = 0.f;
#pragma unroll
  for (int j = 0; j < 3; ++j)
#pragma unroll
    for (int e = 0; e < 4; ++e) { float d = v[j][e] - mu; q += d * d; }
#pragma unroll
  for (int m = 1; m <= 16; m <<= 1) q += __shfl_xor(q, m, 64);
  float rs = rsqrtf(q * (1.0f / DIM_) + 1e-5f);
  f32x4 y[3];
#pragma unroll
  for (int j = 0; j < 3; ++j) {
    f32x4 wv = *(const f32x4*)&w[4 * l + 128 * j];
    f32x4 bv = *(const f32x4*)&b[4 * l + 128 * j];
#pragma unroll
    for (int e = 0; e < 4; ++e) y[j][e] = (v[j][e] - mu) * rs * wv[e] + bv[e];
  }
  int wdw = tok >> 6, t = tok & 63;
  int rank = win_rank[wdw];
  if (rank < 0) {
    f32x4* po = (f32x4*)(out + (size_t)tok * DIM_);
#pragma unroll
    for (int j = 0; j < 3; ++j) po[l + 32 * j] = y[j];
  } else {
    int jdx = (rank << 6) + t;
    int i = inv_ip[jdx];
#pragma unroll
    for (int j = 0; j < 3; ++j) {
      s16x4 o;
#pragma unroll
      for (int e = 0; e < 4; ++e) o[e] = f2bf(y[j][e]);
      *(s16x4*)&xp[(size_t)i * DIM_ + 4 * l + 128 * j] = o;
    }
    if ((bitmap[jdx >> 5] >> (jdx & 31)) & 1) {
      f32x4* po = (f32x4*)(out + (size_t)tok * DIM_);
#pragma unroll
      for (int j = 0; j < 3; ++j) po[l + 32 * j] = y[j];
    }
  }
}

// ---------------- LN2 (vectorized: 32 lanes/token, short4) ----------------
__global__ __launch_bounds__(256) void ln2_k(const short* __restrict__ h,
                                             const float* __restrict__ w,
                                             const float* __restrict__ b,
                                             short* __restrict__ outln) {
  const int l = threadIdx.x & 31;
  const int tok = blockIdx.x * 8 + (threadIdx.x >> 5);
  const s16x4* xr = (const s16x4*)(h + (size_t)tok * DIM_);
  float v[12]; float s = 0.f;
#pragma unroll
  for (int j = 0; j < 3; ++j) {
    s16x4 rv = xr[l + 32 * j];
#pragma unroll
    for (int e = 0; e < 4; ++e) { v[j * 4 + e] = bf2f(rv[e]); s += v[j * 4 + e]; }
  }
#pragma unroll
  for (int m = 1; m <= 16; m <<= 1) s += __shfl_xor(s, m, 64);
  float mu = s * (1.0f / DIM_);
  float q = 0.f;
#pragma unroll
  for (int e = 0; e < 12; ++e) { float d = v[e] - mu; q += d * d; }
#pragma unroll
  for (int m = 1; m <= 16; m <<= 1) q += __shfl_xor(q, m, 64);
  float rs = rsqrtf(q * (1.0f / DIM_) + 1e-5f);
  s16x4* po = (s16x4*)(outln + (size_t)tok * DIM_);
#pragma unroll
  for (int j = 0; j < 3; ++j) {
    f32x4 wv = *(const f32x4*)&w[4 * l + 128 * j];
    f32x4 bv = *(const f32x4*)&b[4 * l + 128 * j];
    s16x4 o;
#pragma unroll
    for (int e = 0; e < 4; ++e)
      o[e] = f2bf((v[j * 4 + e] - mu) * rs * wv[e] + bv[e]);
    po[l + 32 * j] = o;
  }
}

// ---------------- GEMM: C = A * B^T (256x128 tile, 8 waves) ----------------
// Proven R10 structure: single-buffer LDS (48 KB), __syncthreads pipeline,
// XCD-chunk swizzle, bias in regs.
// EPI 0: +bias -> bf16 (ld N)                       (QKV)
// EPI 2: +bias, fast gelu -> FP8 (HW cvt, K-perm)   (fc1 -> t8, ld MLPD_)
template <int EPI>
__global__ __launch_bounds__(512) void gemm_k(const short* __restrict__ A,
                                              const short* __restrict__ B,
                                              const float* __restrict__ bias,
                                              int K, int N, int nx,
                                              short* __restrict__ Cb,
                                              unsigned char* __restrict__ C8) {
  const int nwg = gridDim.x;
  const int q8 = nwg >> 3;
  const int wg = (blockIdx.x & 7) * q8 + (blockIdx.x >> 3);
  const int ntile = wg % nx, mtile = wg / nx;
  const int tid = threadIdx.x, wid = tid >> 6, lane = tid & 63;
  const int fq = lane >> 4, fr = lane & 15;
  const int wr = wid >> 1, wc = wid & 1;  // 4(M) x 2(N) waves, 64x64 each
  __shared__ __align__(16) short lA[256 * 64];
  __shared__ __align__(16) short lB[128 * 64];
  const int row0 = mtile * 256, col0 = ntile * 128;
  float bs[4];
#pragma unroll
  for (int nt = 0; nt < 4; ++nt) bs[nt] = bias[col0 + wc * 64 + nt * 16 + fr];
  f32x4 acc[4][4];
#pragma unroll
  for (int a = 0; a < 4; ++a)
#pragma unroll
    for (int c = 0; c < 4; ++c) acc[a][c] = (f32x4){0.f, 0.f, 0.f, 0.f};
  const int nkt = K >> 6;
  for (int kt = 0; kt < nkt; ++kt) {
    const int k0 = kt << 6;
#pragma unroll
    for (int i = 0; i < 4; ++i) {
      int g = i * 512 + tid;
      int r = g >> 3, c8 = g & 7;
      int s8 = c8 ^ (r & 7);
      gload16(A + (size_t)(row0 + r) * K + k0 + s8 * 8, (char*)lA + (size_t)g * 16);
    }
#pragma unroll
    for (int i = 0; i < 2; ++i) {
      int g = i * 512 + tid;
      int r = g >> 3, c8 = g & 7;
      int s8 = c8 ^ (r & 7);
      gload16(B + (size_t)(col0 + r) * K + k0 + s8 * 8, (char*)lB + (size_t)g * 16);
    }
    __syncthreads();
#pragma unroll
    for (int ks = 0; ks < 2; ++ks) {
      bf16x8 af[4], bfr[4];
#pragma unroll
      for (int mt = 0; mt < 4; ++mt) {
        int r = wr * 64 + mt * 16 + fr;
        af[mt] = *(const bf16x8*)&lA[r * 64 + ((ks * 4 + fq) ^ (r & 7)) * 8];
      }
#pragma unroll
      for (int nt = 0; nt < 4; ++nt) {
        int r = wc * 64 + nt * 16 + fr;
        bfr[nt] = *(const bf16x8*)&lB[r * 64 + ((ks * 4 + fq) ^ (r & 7)) * 8];
      }
#pragma unroll
      for (int mt = 0; mt < 4; ++mt)
#pragma unroll
        for (int nt = 0; nt < 4; ++nt)
          acc[mt][nt] = mfma16(af[mt], bfr[nt], acc[mt][nt]);
    }
    __syncthreads();
  }
#pragma unroll
  for (int mt = 0; mt < 4; ++mt) {
#pragma unroll
    for (int jj = 0; jj < 4; ++jj) {
      int r = row0 + wr * 64 + mt * 16 + fq * 4 + jj;
      if (EPI == 0) {
#pragma unroll
        for (int nt = 0; nt < 4; ++nt) {
          int gcol = col0 + wc * 64 + nt * 16 + fr;
          Cb[(size_t)r * N + gcol] = f2bf(acc[mt][nt][jj] + bs[nt]);
        }
      } else {
        float g4[4];
#pragma unroll
        for (int nt = 0; nt < 4; ++nt) {
          float v = acc[mt][nt][jj] + bs[nt];
          // gelu(x) ~= x * sigmoid(2u), u = 0.79788456*(x + 0.044715 x^3)
          float u = v * (0.79788456f + 0.03567741f * v * v);
          g4[nt] = v * __builtin_amdgcn_rcpf(1.0f + __expf(-2.0f * u));
        }
        int p01 = __builtin_amdgcn_cvt_pk_fp8_f32(g4[0], g4[1], 0, false);
        int p23 = __builtin_amdgcn_cvt_pk_fp8_f32(g4[2], g4[3], 0, false);
        // K-permuted positions: col = C0 + nt*16 + fr -> chunk l = 2nt+(fr>>3),
        // slot s = ((l&3)<<1)|(l>>2); byte = C0 + s*8 + (fr&7).
        const int C0 = col0 + wc * 64;
        const size_t rb = (size_t)r * MLPD_ + C0 + (fr & 7) + ((fr >> 3) << 4);
        C8[rb]      = (unsigned char)(p01 & 0xff);          // nt=0: s*8 = 16fh
        C8[rb + 32] = (unsigned char)((p01 >> 8) & 0xff);   // nt=1: 32+16fh
        C8[rb + 8]  = (unsigned char)(p23 & 0xff);          // nt=2: 16fh+8
        C8[rb + 40] = (unsigned char)((p23 >> 8) & 0xff);   // nt=3: 40+16fh
      }
    }
  }
}

// ---------------- GEMM 128x128 bf16 (proj) ----------------
// Proven R7 structure. +bias +add_bf -> bf16 (proj + residual -> h)
__global__ __launch_bounds__(256) void gemm128_k(const short* __restrict__ A,
                                                 const short* __restrict__ B,
                                                 const float* __restrict__ bias,
                                                 int K, int nx,
                                                 short* __restrict__ Cb,
                                                 const short* __restrict__ add_bf) {
  const int nwg = gridDim.x;
  const int q8 = nwg >> 3;
  const int wg = (blockIdx.x & 7) * q8 + (blockIdx.x >> 3);
  const int ntile = wg % nx, mtile = wg / nx;
  const int tid = threadIdx.x, wid = tid >> 6, lane = tid & 63;
  const int fq = lane >> 4, fr = lane & 15;
  const int wr = wid >> 1, wc = wid & 1;
  __shared__ __align__(16) short lA[128 * 64];
  __shared__ __align__(16) short lB[128 * 64];
  const int row0 = mtile * 128, col0 = ntile * 128;
  float bs[4];
#pragma unroll
  for (int nt = 0; nt < 4; ++nt) bs[nt] = bias[col0 + wc * 64 + nt * 16 + fr];
  f32x4 acc[4][4];
#pragma unroll
  for (int a = 0; a < 4; ++a)
#pragma unroll
    for (int c = 0; c < 4; ++c) acc[a][c] = (f32x4){0.f, 0.f, 0.f, 0.f};
  const int nkt = K >> 6;
  for (int kt = 0; kt < nkt; ++kt) {
    const int k0 = kt << 6;
#pragma unroll
    for (int i = 0; i < 4; ++i) {
      int cb = ((i * 4 + wid) << 6) + lane;
      int r = cb >> 3, c8 = cb & 7;
      int s8 = c8 ^ (r & 7);
      gload16(A + (size_t)(row0 + r) * K + k0 + s8 * 8,
              (char*)lA + (size_t)(i * 4 + wid) * 1024);
      gload16(B + (size_t)(col0 + r) * K + k0 + s8 * 8,
              (char*)lB + (size_t)(i * 4 + wid) * 1024);
    }
    __syncthreads();
#pragma unroll
    for (int ks = 0; ks < 2; ++ks) {
      bf16x8 af[4], bfr[4];
#pragma unroll
      for (int mt = 0; mt < 4; ++mt) {
        int r = wr * 64 + mt * 16 + fr;
        af[mt] = *(const bf16x8*)&lA[r * 64 + ((ks * 4 + fq) ^ (r & 7)) * 8];
      }
#pragma unroll
      for (int nt = 0; nt < 4; ++nt) {
        int r = wc * 64 + nt * 16 + fr;
        bfr[nt] = *(const bf16x8*)&lB[r * 64 + ((ks * 4 + fq) ^ (r & 7)) * 8];
      }
#pragma unroll
      for (int mt = 0; mt < 4; ++mt)
#pragma unroll
        for (int nt = 0; nt < 4; ++nt)
          acc[mt][nt] = mfma16(af[mt], bfr[nt], acc[mt][nt]);
    }
    __syncthreads();
  }
#pragma unroll
  for (int mt = 0; mt < 4; ++mt) {
#pragma unroll
    for (int jj = 0; jj < 4; ++jj) {
      int r = row0 + wr * 64 + mt * 16 + fq * 4 + jj;
#pragma unroll
      for (int nt = 0; nt < 4; ++nt) {
        int gcol = col0 + wc * 64 + nt * 16 + fr;
        float v = acc[mt][nt][jj] + bs[nt] + bf2f(add_bf[(size_t)r * DIM_ + gcol]);
        Cb[(size_t)r * DIM_ + gcol] = f2bf(v);
      }
    }
  }
}

// ---------------- FC2 GEMM fp8 (K-permuted operands) ----------------
// 128x128 tile, BK=128 fp8. Reads are ds_read_b128 at r*128 + d*16 with
// d = (ss*4+fq) ^ (r&7) -- byte-identical address pattern to the bf16
// kernels (measured 0 bank conflicts). Low/high 8B of each b128 feed
// K-steps 2ss / 2ss+1 (K-permutation baked into t8/w2f8 producers).
__global__ __launch_bounds__(256) void gemmf8_k(const unsigned char* __restrict__ A8,
                                                const unsigned char* __restrict__ B8,
                                                const float* __restrict__ bias,
                                                int nx,
                                                const short* __restrict__ add_bf,
                                                const int* __restrict__ rowmap,
                                                float* __restrict__ outf) {
  const int K = MLPD_;
  const int nwg = gridDim.x;
  const int q8 = nwg >> 3;
  const int wg = (blockIdx.x & 7) * q8 + (blockIdx.x >> 3);
  const int ntile = wg % nx, mtile = wg / nx;
  const int tid = threadIdx.x, wid = tid >> 6, lane = tid & 63;
  const int fq = lane >> 4, fr = lane & 15;
  const int wr = wid >> 1, wc = wid & 1;
  __shared__ __align__(16) unsigned char lA[128 * 128];
  __shared__ __align__(16) unsigned char lB[128 * 128];
  const int row0 = mtile * 128, col0 = ntile * 128;
  float bs[4];
#pragma unroll
  for (int nt = 0; nt < 4; ++nt) bs[nt] = bias[col0 + wc * 64 + nt * 16 + fr];
  f32x4 acc[4][4];
#pragma unroll
  for (int a = 0; a < 4; ++a)
#pragma unroll
    for (int c = 0; c < 4; ++c) acc[a][c] = (f32x4){0.f, 0.f, 0.f, 0.f};
  const int nkt = K >> 7;  // 12
  for (int kt = 0; kt < nkt; ++kt) {
    const int k0 = kt << 7;
    // 1024 16B-blocks per matrix; 4 per thread each
#pragma unroll
    for (int i = 0; i < 4; ++i) {
      int g = i * 256 + tid;
      int r = g >> 3, c8 = g & 7;
      int s8 = c8 ^ (r & 7);
      gload16(A8 + (size_t)(row0 + r) * K + k0 + s8 * 16, (char*)lA + (size_t)g * 16);
      gload16(B8 + (size_t)(col0 + r) * K + k0 + s8 * 16, (char*)lB + (size_t)g * 16);
    }
    __syncthreads();
#pragma unroll
    for (int ss = 0; ss < 2; ++ss) {
      longx2 af[4], bfr[4];
      const int pb = ss * 4 + fq;  // logical 16B block (permuted layout)
#pragma unroll
      for (int mt = 0; mt < 4; ++mt) {
        int r = wr * 64 + mt * 16 + fr;
        int d = pb ^ (r & 7);
        af[mt] = *(const longx2*)&lA[r * 128 + d * 16];
      }
#pragma unroll
      for (int nt = 0; nt < 4; ++nt) {
        int r = wc * 64 + nt * 16 + fr;
        int d = pb ^ (r & 7);
        bfr[nt] = *(const longx2*)&lB[r * 128 + d * 16];
      }
#pragma unroll
      for (int mt = 0; mt < 4; ++mt)
#pragma unroll
        for (int nt = 0; nt < 4; ++nt) {
          acc[mt][nt] = __builtin_amdgcn_mfma_f32_16x16x32_fp8_fp8(
              af[mt][0], bfr[nt][0], acc[mt][nt], 0, 0, 0);
          acc[mt][nt] = __builtin_amdgcn_mfma_f32_16x16x32_fp8_fp8(
              af[mt][1], bfr[nt][1], acc[mt][nt], 0, 0, 0);
        }
    }
    __syncthreads();
  }
#pragma unroll
  for (int mt = 0; mt < 4; ++mt) {
#pragma unroll
    for (int jj = 0; jj < 4; ++jj) {
      int r = row0 + wr * 64 + mt * 16 + fq * 4 + jj;
      int dmap = rowmap[r];
#pragma unroll
      for (int nt = 0; nt < 4; ++nt) {
        int gcol = col0 + wc * 64 + nt * 16 + fr;
        float v = acc[mt][nt][jj] + bs[nt] + bf2f(add_bf[(size_t)r * DIM_ + gcol]);
        if (dmap >= 0) outf[(size_t)dmap * DIM_ + gcol] = v;
      }
    }
  }
}

// ---------------- attention: one head per wave, XCD-grouped m ----------------
__global__ __launch_bounds__(256) void attn_k(const short* __restrict__ qkv,
                                              const unsigned* __restrict__ bitmap,
                                              const int* __restrict__ ip,
                                              short* __restrict__ o) {
  // bijective XCD swizzle: 4608 = 8 * 576; same-m triplets land on one XCD
  const int flat = (blockIdx.x & 7) * 576 + (blockIdx.x >> 3);
  const int m = flat / 3;
  const int h = (flat % 3) * 4 + (threadIdx.x >> 6);
  const int wid = threadIdx.x >> 6, lane = threadIdx.x & 63;
  const int fq = lane >> 4, fr = lane & 15;
  __shared__ __align__(16) short P[4][64 * 72];
  __shared__ __align__(16) short Vt[4][32 * 72];
  __shared__ unsigned char flags[64];
  if (threadIdx.x < 64) {
    int j = ip[m * 64 + threadIdx.x];
    flags[threadIdx.x] = (unsigned char)((bitmap[j >> 5] >> (j & 31)) & 1);
  }
  __syncthreads();
  const float scale = 0.17677669529663687f;
  int msk[4];
#pragma unroll
  for (int nt = 0; nt < 4; ++nt) msk[nt] = flags[nt * 16 + fr];

  const short* base = qkv + (size_t)m * 64 * QKVD_ + h * 96;
  f32x4 sacc[4][4];
#pragma unroll
  for (int a = 0; a < 4; ++a)
#pragma unroll
    for (int c = 0; c < 4; ++c) sacc[a][c] = (f32x4){0.f, 0.f, 0.f, 0.f};
  bf16x8 qa[4], kb[4];
#pragma unroll
  for (int mt = 0; mt < 4; ++mt)
    qa[mt] = *(const bf16x8*)(base + (size_t)(mt * 16 + fr) * QKVD_ + fq * 8);
#pragma unroll
  for (int nt = 0; nt < 4; ++nt)
    kb[nt] = *(const bf16x8*)(base + (size_t)(nt * 16 + fr) * QKVD_ + 32 + fq * 8);
#pragma unroll
  for (int mt = 0; mt < 4; ++mt)
#pragma unroll
    for (int nt = 0; nt < 4; ++nt)
      sacc[mt][nt] = mfma16(qa[mt], kb[nt], sacc[mt][nt]);
#pragma unroll
  for (int c = 0; c < 4; ++c) {
    bf16x8 vv = *(const bf16x8*)(base + (size_t)lane * QKVD_ + 64 + c * 8);
#pragma unroll
    for (int e = 0; e < 8; ++e) Vt[wid][(c * 8 + e) * 72 + lane] = vv[e];
  }
#pragma unroll
  for (int mt = 0; mt < 4; ++mt)
#pragma unroll
    for (int nt = 0; nt < 4; ++nt) {
      f32x4 sv = sacc[mt][nt];
#pragma unroll
      for (int jj = 0; jj < 4; ++jj)
        sv[jj] = msk[nt] ? -10000.0f : sv[jj] * scale;
      sacc[mt][nt] = sv;
    }
#pragma unroll
  for (int mt = 0; mt < 4; ++mt) {
#pragma unroll
    for (int jj = 0; jj < 4; ++jj) {
      float mx = sacc[mt][0][jj];
#pragma unroll
      for (int nt = 1; nt < 4; ++nt) mx = fmaxf(mx, sacc[mt][nt][jj]);
#pragma unroll
      for (int mm = 1; mm < 16; mm <<= 1) mx = fmaxf(mx, __shfl_xor(mx, mm, 64));
      float sm = 0.f;
      float p[4];
#pragma unroll
      for (int nt = 0; nt < 4; ++nt) {
        p[nt] = __expf(sacc[mt][nt][jj] - mx);
        sm += p[nt];
      }
#pragma unroll
      for (int mm = 1; mm < 16; mm <<= 1) sm += __shfl_xor(sm, mm, 64);
      float inv = 1.0f / sm;
      int rowb = (mt * 16 + fq * 4 + jj) * 72;
#pragma unroll
      for (int nt = 0; nt < 4; ++nt)
        P[wid][rowb + nt * 16 + fr] = f2bf(p[nt] * inv);
    }
  }
  f32x4 oacc[4][2];
#pragma unroll
  for (int a = 0; a < 4; ++a)
#pragma unroll
    for (int c = 0; c < 2; ++c) oacc[a][c] = (f32x4){0.f, 0.f, 0.f, 0.f};
#pragma unroll
  for (int ks = 0; ks < 2; ++ks) {
    bf16x8 pa[4], vb[2];
#pragma unroll
    for (int mt = 0; mt < 4; ++mt)
      pa[mt] = *(const bf16x8*)&P[wid][(mt * 16 + fr) * 72 + ks * 32 + fq * 8];
#pragma unroll
    for (int nd = 0; nd < 2; ++nd)
      vb[nd] = *(const bf16x8*)&Vt[wid][(nd * 16 + fr) * 72 + ks * 32 + fq * 8];
#pragma unroll
    for (int mt = 0; mt < 4; ++mt)
#pragma unroll
      for (int nd = 0; nd < 2; ++nd)
        oacc[mt][nd] = mfma16(pa[mt], vb[nd], oacc[mt][nd]);
  }
#pragma unroll
  for (int mt = 0; mt < 4; ++mt)
#pragma unroll
    for (int nd = 0; nd < 2; ++nd)
#pragma unroll
      for (int jj = 0; jj < 4; ++jj)
        o[(size_t)(m * 64 + mt * 16 + fq * 4 + jj) * DIM_ + h * 32 + nd * 16 + fr] =
            f2bf(oacc[mt][nd][jj]);
}

// ---------------- launch ----------------
extern "C" void kernel_launch(void* const* d_in, const int* in_sizes, int n_in,
                              void* d_out, int out_size, void* d_ws, size_t ws_size,
                              hipStream_t stream) {
  const float* x = (const float*)d_in[0];
  const int* iw = (const int*)d_in[1];
  const int* ip = (const int*)d_in[2];
  const int* blk = (const int*)d_in[3];
  const float* ln1w = (const float*)d_in[6];
  const float* ln1b = (const float*)d_in[7];
  const float* qkvw = (const float*)d_in[8];
  const float* qkvb = (const float*)d_in[9];
  const float* projw = (const float*)d_in[10];
  const float* projb = (const float*)d_in[11];
  const float* ln2w = (const float*)d_in[12];
  const float* ln2b = (const float*)d_in[13];
  const float* fc1w = (const float*)d_in[14];
  const float* fc1b = (const float*)d_in[15];
  const float* fc2w = (const float*)d_in[16];
  const float* fc2b = (const float*)d_in[17];
  float* out = (float*)d_out;

  char* ws = (char*)d_ws;
  short* w_all = (short*)ws;                 // 1,769,472 bf16
  short* w_qkv = w_all;
  short* w_proj = w_all + 442368;
  short* w_fc1 = w_all + 589824;
  int* inv_ip = (int*)(ws + 3538944);
  int* rowmap = inv_ip + NTOK_;
  int* win_rank = rowmap + NTOK_;
  unsigned* bitmap = (unsigned*)(win_rank + NW_);
  short* xp = (short*)(ws + 4349952);                        // 75.5 MB (also ln2 out)
  short* qkv_g = (short*)(ws + 4349952 + 75497472);          // qkv 226.5 MB / t8 151 MB
  unsigned char* t8 = (unsigned char*)qkv_g;                 // fp8 gelu (FC1 out)
  unsigned char* w2f8 = (unsigned char*)(ws + 306339840);    // 576 KB fp8 fc2w
  short* obuf = (short*)(ws + 381837312);                    // 75.5 MB
  short* hbuf = (short*)(ws + 457334784);                    // 75.5 MB
  short* ln2buf = xp;
  (void)in_sizes; (void)n_in; (void)out_size; (void)ws_size;

  mapA_k<<<12, 256, 0, stream>>>(win_rank, bitmap);
  mapB_k<<<39, 256, 0, stream>>>(iw, blk, win_rank, bitmap);
  mapC_k<<<NTOK_ / 256, 256, 0, stream>>>(ip, iw, bitmap, inv_ip, rowmap);
  wconv_k<<<1728, 256, 0, stream>>>(qkvw, projw, fc1w, fc2w, w_all);
  wconv8_k<<<288, 256, 0, stream>>>(fc2w, w2f8);
  ln1_k<<<(NW_ * 64) / 8, 256, 0, stream>>>(x, ln1w, ln1b, win_rank, inv_ip, bitmap,
                                            out, xp);
  // 256-row mtiles = 384; 128-row mtiles = 768
  gemm_k<0><<<384 * 9, 512, 0, stream>>>(xp, w_qkv, qkvb, 384, QKVD_, 9, qkv_g,
                                         nullptr);
  attn_k<<<WACT_ * 3, 256, 0, stream>>>(qkv_g, bitmap, ip, obuf);
  gemm128_k<<<768 * 3, 256, 0, stream>>>(obuf, w_proj, projb, 384, 3, hbuf, xp);
  ln2_k<<<NTOK_ / 8, 256, 0, stream>>>(hbuf, ln2w, ln2b, ln2buf);
  gemm_k<2><<<384 * 12, 512, 0, stream>>>(ln2buf, w_fc1, fc1b, 384, MLPD_, 12,
                                          nullptr, t8);
  gemmf8_k<<<768 * 3, 256, 0, stream>>>(t8, w2f8, fc2b, 3, hbuf, rowmap, out);
}

// Round 18
// 744.452 us; speedup vs baseline: 1.1581x; 1.0564x over previous
//
#include <hip/hip_runtime.h>
#include <hip/hip_bf16.h>

typedef __attribute__((ext_vector_type(8))) short bf16x8;
typedef __attribute__((ext_vector_type(4))) short s16x4;
typedef __attribute__((ext_vector_type(4))) float f32x4;
typedef __attribute__((ext_vector_type(2))) long longx2;
typedef __attribute__((ext_vector_type(16))) unsigned char u8x16;

#define NW_   3072
#define WACT_ 1536
#define NTOK_ 98304
#define NBLK_ 9830
#define DIM_  384
#define QKVD_ 1152
#define MLPD_ 1536

__device__ __forceinline__ float bf2f(short s) {
  union { unsigned u; float f; } c;
  c.u = ((unsigned)(unsigned short)s) << 16;
  return c.f;
}
__device__ __forceinline__ short f2bf(float f) {
  union { float f; unsigned u; } c; c.f = f;
  unsigned lsb = (c.u >> 16) & 1u;
  c.u += 0x7fffu + lsb;
  return (short)(c.u >> 16);
}

__device__ __forceinline__ f32x4 mfma16(bf16x8 a, bf16x8 b, f32x4 c) {
  return __builtin_amdgcn_mfma_f32_16x16x32_bf16(a, b, c, 0, 0, 0);
}
__device__ __forceinline__ f32x4 mfma8(long a, long b, f32x4 c) {
  return __builtin_amdgcn_mfma_f32_16x16x32_fp8_fp8(a, b, c, 0, 0, 0);
}

__device__ __forceinline__ void gload16(const void* g, void* l) {
  __builtin_amdgcn_global_load_lds(
      (const __attribute__((address_space(1))) unsigned*)g,
      (__attribute__((address_space(3))) unsigned*)l, 16, 0, 0);
}

// ---------------- map kernels ----------------
__global__ __launch_bounds__(256) void mapA_k(int* win_rank, unsigned* bitmap) {
  int t = blockIdx.x * 256 + threadIdx.x;
  if (t < NW_) { win_rank[t] = -1; bitmap[t] = 0u; }
}

__global__ __launch_bounds__(256) void mapB_k(const int* __restrict__ iw,
                                              const int* __restrict__ blk,
                                              int* win_rank, unsigned* bitmap) {
  int t = blockIdx.x * 256 + threadIdx.x;
  if (t < WACT_) win_rank[iw[t]] = t;
  if (t < NBLK_) { int j = blk[t]; atomicOr(&bitmap[j >> 5], 1u << (j & 31)); }
}

__global__ __launch_bounds__(256) void mapC_k(const int* __restrict__ ip,
                                              const int* __restrict__ iw,
                                              const unsigned* __restrict__ bitmap,
                                              int* inv_ip, int* rowmap) {
  int i = blockIdx.x * 256 + threadIdx.x;
  if (i < NTOK_) {
    int j = ip[i];
    inv_ip[j] = i;
    int blocked = (bitmap[j >> 5] >> (j & 31)) & 1;
    rowmap[i] = blocked ? -1 : (iw[j >> 6] * 64 + (j & 63));
  }
}

// ---------------- weight conversion (qkv, proj, fc1 -> bf16) ----------------
__global__ __launch_bounds__(256) void wconv_k(const float* __restrict__ qkvw,
                                               const float* __restrict__ projw,
                                               const float* __restrict__ fc1w,
                                               short* __restrict__ dst) {
  int i = (blockIdx.x * 256 + threadIdx.x) * 4;  // total 1,179,648 elems
  f32x4 v;
  if (i < 442368) v = *(const f32x4*)&qkvw[i];
  else if (i < 589824) v = *(const f32x4*)&projw[i - 442368];
  else v = *(const f32x4*)&fc1w[i - 589824];
  s16x4 o;
#pragma unroll
  for (int e = 0; e < 4; ++e) o[e] = f2bf(v[e]);
  *(s16x4*)&dst[i] = o;
}

// fc2w -> fp8 e4m3 (HW cvt), K-PERMUTED: within each 64B group, 8B-chunk
// l -> slot ((l&3)<<1)|(l>>2). Thread handles one 8B chunk.
__global__ __launch_bounds__(256) void wconv8_k(const float* __restrict__ fc2w,
                                                unsigned char* __restrict__ dst) {
  int i = (blockIdx.x * 256 + threadIdx.x) * 8;  // 589824 / 8 -> 288 blocks
  f32x4 v0 = *(const f32x4*)&fc2w[i];
  f32x4 v1 = *(const f32x4*)&fc2w[i + 4];
  int w0 = __builtin_amdgcn_cvt_pk_fp8_f32(v0[0], v0[1], 0, false);
  w0 = __builtin_amdgcn_cvt_pk_fp8_f32(v0[2], v0[3], w0, true);
  int w1 = __builtin_amdgcn_cvt_pk_fp8_f32(v1[0], v1[1], 0, false);
  w1 = __builtin_amdgcn_cvt_pk_fp8_f32(v1[2], v1[3], w1, true);
  int kro = i % MLPD_, row = i / MLPD_;
  int g = kro >> 6, l = (kro >> 3) & 7;
  int s = ((l & 3) << 1) | (l >> 2);
  union { int u[2]; long ll; } p; p.u[0] = w0; p.u[1] = w1;
  *(long*)&dst[(size_t)row * MLPD_ + g * 64 + s * 8] = p.ll;
}

// ---------------- LN1 + gather/permute (vectorized: 32 lanes/token) --------
__global__ __launch_bounds__(256) void ln1_k(const float* __restrict__ x,
                                             const float* __restrict__ w,
                                             const float* __restrict__ b,
                                             const int* __restrict__ win_rank,
                                             const int* __restrict__ inv_ip,
                                             const unsigned* __restrict__ bitmap,
                                             float* __restrict__ out,
                                             short* __restrict__ xp) {
  const int l = threadIdx.x & 31;
  const int tok = blockIdx.x * 8 + (threadIdx.x >> 5);
  const f32x4* xr = (const f32x4*)(x + (size_t)tok * DIM_);
  f32x4 v[3]; float s = 0.f;
#pragma unroll
  for (int j = 0; j < 3; ++j) {
    v[j] = xr[l + 32 * j];
    s += v[j][0] + v[j][1] + v[j][2] + v[j][3];
  }
#pragma unroll
  for (int m = 1; m <= 16; m <<= 1) s += __shfl_xor(s, m, 64);
  float mu = s * (1.0f / DIM_);
  float q = 0.f;
#pragma unroll
  for (int j = 0; j < 3; ++j)
#pragma unroll
    for (int e = 0; e < 4; ++e) { float d = v[j][e] - mu; q += d * d; }
#pragma unroll
  for (int m = 1; m <= 16; m <<= 1) q += __shfl_xor(q, m, 64);
  float rs = rsqrtf(q * (1.0f / DIM_) + 1e-5f);
  f32x4 y[3];
#pragma unroll
  for (int j = 0; j < 3; ++j) {
    f32x4 wv = *(const f32x4*)&w[4 * l + 128 * j];
    f32x4 bv = *(const f32x4*)&b[4 * l + 128 * j];
#pragma unroll
    for (int e = 0; e < 4; ++e) y[j][e] = (v[j][e] - mu) * rs * wv[e] + bv[e];
  }
  int wdw = tok >> 6, t = tok & 63;
  int rank = win_rank[wdw];
  if (rank < 0) {
    f32x4* po = (f32x4*)(out + (size_t)tok * DIM_);
#pragma unroll
    for (int j = 0; j < 3; ++j) po[l + 32 * j] = y[j];
  } else {
    int jdx = (rank << 6) + t;
    int i = inv_ip[jdx];
#pragma unroll
    for (int j = 0; j < 3; ++j) {
      s16x4 o;
#pragma unroll
      for (int e = 0; e < 4; ++e) o[e] = f2bf(y[j][e]);
      *(s16x4*)&xp[(size_t)i * DIM_ + 4 * l + 128 * j] = o;
    }
    if ((bitmap[jdx >> 5] >> (jdx & 31)) & 1) {
      f32x4* po = (f32x4*)(out + (size_t)tok * DIM_);
#pragma unroll
      for (int j = 0; j < 3; ++j) po[l + 32 * j] = y[j];
    }
  }
}

// ---------------- LN2 (vectorized: 32 lanes/token, short4) ----------------
__global__ __launch_bounds__(256) void ln2_k(const short* __restrict__ h,
                                             const float* __restrict__ w,
                                             const float* __restrict__ b,
                                             short* __restrict__ outln) {
  const int l = threadIdx.x & 31;
  const int tok = blockIdx.x * 8 + (threadIdx.x >> 5);
  const s16x4* xr = (const s16x4*)(h + (size_t)tok * DIM_);
  float v[12]; float s = 0.f;
#pragma unroll
  for (int j = 0; j < 3; ++j) {
    s16x4 rv = xr[l + 32 * j];
#pragma unroll
    for (int e = 0; e < 4; ++e) { v[j * 4 + e] = bf2f(rv[e]); s += v[j * 4 + e]; }
  }
#pragma unroll
  for (int m = 1; m <= 16; m <<= 1) s += __shfl_xor(s, m, 64);
  float mu = s * (1.0f / DIM_);
  float q = 0.f;
#pragma unroll
  for (int e = 0; e < 12; ++e) { float d = v[e] - mu; q += d * d; }
#pragma unroll
  for (int m = 1; m <= 16; m <<= 1) q += __shfl_xor(q, m, 64);
  float rs = rsqrtf(q * (1.0f / DIM_) + 1e-5f);
  s16x4* po = (s16x4*)(outln + (size_t)tok * DIM_);
#pragma unroll
  for (int j = 0; j < 3; ++j) {
    f32x4 wv = *(const f32x4*)&w[4 * l + 128 * j];
    f32x4 bv = *(const f32x4*)&b[4 * l + 128 * j];
    s16x4 o;
#pragma unroll
    for (int e = 0; e < 4; ++e)
      o[e] = f2bf((v[j * 4 + e] - mu) * rs * wv[e] + bv[e]);
    po[l + 32 * j] = o;
  }
}

// ---------------- GEMM: C = A * B^T (256x128 tile, 8 waves) ----------------
// Proven R10 structure: single-buffer LDS (48 KB), __syncthreads pipeline,
// XCD-chunk swizzle, bias in regs. Outputs fp8 (HW cvt):
// EPI 0: +bias -> FP8 plain (ld N)                  (QKV -> qkv8)
// EPI 2: +bias, fast gelu -> FP8 K-permuted         (fc1 -> t8, ld MLPD_)
template <int EPI>
__global__ __launch_bounds__(512) void gemm_k(const short* __restrict__ A,
                                              const short* __restrict__ B,
                                              const float* __restrict__ bias,
                                              int K, int N, int nx,
                                              unsigned char* __restrict__ C8) {
  const int nwg = gridDim.x;
  const int q8 = nwg >> 3;
  const int wg = (blockIdx.x & 7) * q8 + (blockIdx.x >> 3);
  const int ntile = wg % nx, mtile = wg / nx;
  const int tid = threadIdx.x, wid = tid >> 6, lane = tid & 63;
  const int fq = lane >> 4, fr = lane & 15;
  const int wr = wid >> 1, wc = wid & 1;  // 4(M) x 2(N) waves, 64x64 each
  __shared__ __align__(16) short lA[256 * 64];
  __shared__ __align__(16) short lB[128 * 64];
  const int row0 = mtile * 256, col0 = ntile * 128;
  float bs[4];
#pragma unroll
  for (int nt = 0; nt < 4; ++nt) bs[nt] = bias[col0 + wc * 64 + nt * 16 + fr];
  f32x4 acc[4][4];
#pragma unroll
  for (int a = 0; a < 4; ++a)
#pragma unroll
    for (int c = 0; c < 4; ++c) acc[a][c] = (f32x4){0.f, 0.f, 0.f, 0.f};
  const int nkt = K >> 6;
  for (int kt = 0; kt < nkt; ++kt) {
    const int k0 = kt << 6;
#pragma unroll
    for (int i = 0; i < 4; ++i) {
      int g = i * 512 + tid;
      int r = g >> 3, c8 = g & 7;
      int s8 = c8 ^ (r & 7);
      gload16(A + (size_t)(row0 + r) * K + k0 + s8 * 8, (char*)lA + (size_t)g * 16);
    }
#pragma unroll
    for (int i = 0; i < 2; ++i) {
      int g = i * 512 + tid;
      int r = g >> 3, c8 = g & 7;
      int s8 = c8 ^ (r & 7);
      gload16(B + (size_t)(col0 + r) * K + k0 + s8 * 8, (char*)lB + (size_t)g * 16);
    }
    __syncthreads();
#pragma unroll
    for (int ks = 0; ks < 2; ++ks) {
      bf16x8 af[4], bfr[4];
#pragma unroll
      for (int mt = 0; mt < 4; ++mt) {
        int r = wr * 64 + mt * 16 + fr;
        af[mt] = *(const bf16x8*)&lA[r * 64 + ((ks * 4 + fq) ^ (r & 7)) * 8];
      }
#pragma unroll
      for (int nt = 0; nt < 4; ++nt) {
        int r = wc * 64 + nt * 16 + fr;
        bfr[nt] = *(const bf16x8*)&lB[r * 64 + ((ks * 4 + fq) ^ (r & 7)) * 8];
      }
#pragma unroll
      for (int mt = 0; mt < 4; ++mt)
#pragma unroll
        for (int nt = 0; nt < 4; ++nt)
          acc[mt][nt] = mfma16(af[mt], bfr[nt], acc[mt][nt]);
    }
    __syncthreads();
  }
#pragma unroll
  for (int mt = 0; mt < 4; ++mt) {
#pragma unroll
    for (int jj = 0; jj < 4; ++jj) {
      int r = row0 + wr * 64 + mt * 16 + fq * 4 + jj;
      if (EPI == 0) {
        float g4[4];
#pragma unroll
        for (int nt = 0; nt < 4; ++nt) g4[nt] = acc[mt][nt][jj] + bs[nt];
        int p01 = __builtin_amdgcn_cvt_pk_fp8_f32(g4[0], g4[1], 0, false);
        int p23 = __builtin_amdgcn_cvt_pk_fp8_f32(g4[2], g4[3], 0, false);
        const size_t rb = (size_t)r * N + col0 + wc * 64 + fr;
        C8[rb]      = (unsigned char)(p01 & 0xff);
        C8[rb + 16] = (unsigned char)((p01 >> 8) & 0xff);
        C8[rb + 32] = (unsigned char)(p23 & 0xff);
        C8[rb + 48] = (unsigned char)((p23 >> 8) & 0xff);
      } else {
        float g4[4];
#pragma unroll
        for (int nt = 0; nt < 4; ++nt) {
          float v = acc[mt][nt][jj] + bs[nt];
          // gelu(x) ~= x * sigmoid(2u), u = 0.79788456*(x + 0.044715 x^3)
          float u = v * (0.79788456f + 0.03567741f * v * v);
          g4[nt] = v * __builtin_amdgcn_rcpf(1.0f + __expf(-2.0f * u));
        }
        int p01 = __builtin_amdgcn_cvt_pk_fp8_f32(g4[0], g4[1], 0, false);
        int p23 = __builtin_amdgcn_cvt_pk_fp8_f32(g4[2], g4[3], 0, false);
        // K-permuted positions: col = C0 + nt*16 + fr -> chunk l = 2nt+(fr>>3),
        // slot s = ((l&3)<<1)|(l>>2); byte = C0 + s*8 + (fr&7).
        const int C0 = col0 + wc * 64;
        const size_t rb = (size_t)r * MLPD_ + C0 + (fr & 7) + ((fr >> 3) << 4);
        C8[rb]      = (unsigned char)(p01 & 0xff);          // nt=0
        C8[rb + 32] = (unsigned char)((p01 >> 8) & 0xff);   // nt=1
        C8[rb + 8]  = (unsigned char)(p23 & 0xff);          // nt=2
        C8[rb + 40] = (unsigned char)((p23 >> 8) & 0xff);   // nt=3
      }
    }
  }
}

// ---------------- GEMM 128x128 bf16 (proj) ----------------
// Proven R7 structure. +bias +add_bf -> bf16 (proj + residual -> h)
__global__ __launch_bounds__(256) void gemm128_k(const short* __restrict__ A,
                                                 const short* __restrict__ B,
                                                 const float* __restrict__ bias,
                                                 int K, int nx,
                                                 short* __restrict__ Cb,
                                                 const short* __restrict__ add_bf) {
  const int nwg = gridDim.x;
  const int q8 = nwg >> 3;
  const int wg = (blockIdx.x & 7) * q8 + (blockIdx.x >> 3);
  const int ntile = wg % nx, mtile = wg / nx;
  const int tid = threadIdx.x, wid = tid >> 6, lane = tid & 63;
  const int fq = lane >> 4, fr = lane & 15;
  const int wr = wid >> 1, wc = wid & 1;
  __shared__ __align__(16) short lA[128 * 64];
  __shared__ __align__(16) short lB[128 * 64];
  const int row0 = mtile * 128, col0 = ntile * 128;
  float bs[4];
#pragma unroll
  for (int nt = 0; nt < 4; ++nt) bs[nt] = bias[col0 + wc * 64 + nt * 16 + fr];
  f32x4 acc[4][4];
#pragma unroll
  for (int a = 0; a < 4; ++a)
#pragma unroll
    for (int c = 0; c < 4; ++c) acc[a][c] = (f32x4){0.f, 0.f, 0.f, 0.f};
  const int nkt = K >> 6;
  for (int kt = 0; kt < nkt; ++kt) {
    const int k0 = kt << 6;
#pragma unroll
    for (int i = 0; i < 4; ++i) {
      int cb = ((i * 4 + wid) << 6) + lane;
      int r = cb >> 3, c8 = cb & 7;
      int s8 = c8 ^ (r & 7);
      gload16(A + (size_t)(row0 + r) * K + k0 + s8 * 8,
              (char*)lA + (size_t)(i * 4 + wid) * 1024);
      gload16(B + (size_t)(col0 + r) * K + k0 + s8 * 8,
              (char*)lB + (size_t)(i * 4 + wid) * 1024);
    }
    __syncthreads();
#pragma unroll
    for (int ks = 0; ks < 2; ++ks) {
      bf16x8 af[4], bfr[4];
#pragma unroll
      for (int mt = 0; mt < 4; ++mt) {
        int r = wr * 64 + mt * 16 + fr;
        af[mt] = *(const bf16x8*)&lA[r * 64 + ((ks * 4 + fq) ^ (r & 7)) * 8];
      }
#pragma unroll
      for (int nt = 0; nt < 4; ++nt) {
        int r = wc * 64 + nt * 16 + fr;
        bfr[nt] = *(const bf16x8*)&lB[r * 64 + ((ks * 4 + fq) ^ (r & 7)) * 8];
      }
#pragma unroll
      for (int mt = 0; mt < 4; ++mt)
#pragma unroll
        for (int nt = 0; nt < 4; ++nt)
          acc[mt][nt] = mfma16(af[mt], bfr[nt], acc[mt][nt]);
    }
    __syncthreads();
  }
#pragma unroll
  for (int mt = 0; mt < 4; ++mt) {
#pragma unroll
    for (int jj = 0; jj < 4; ++jj) {
      int r = row0 + wr * 64 + mt * 16 + fq * 4 + jj;
#pragma unroll
      for (int nt = 0; nt < 4; ++nt) {
        int gcol = col0 + wc * 64 + nt * 16 + fr;
        float v = acc[mt][nt][jj] + bs[nt] + bf2f(add_bf[(size_t)r * DIM_ + gcol]);
        Cb[(size_t)r * DIM_ + gcol] = f2bf(v);
      }
    }
  }
}

// ---------------- FC2 GEMM fp8 (K-permuted operands) ----------------
// 128x128 tile, BK=128 fp8, ds_read_b128 conflict-free (proven R17).
__global__ __launch_bounds__(256) void gemmf8_k(const unsigned char* __restrict__ A8,
                                                const unsigned char* __restrict__ B8,
                                                const float* __restrict__ bias,
                                                int nx,
                                                const short* __restrict__ add_bf,
                                                const int* __restrict__ rowmap,
                                                float* __restrict__ outf) {
  const int K = MLPD_;
  const int nwg = gridDim.x;
  const int q8 = nwg >> 3;
  const int wg = (blockIdx.x & 7) * q8 + (blockIdx.x >> 3);
  const int ntile = wg % nx, mtile = wg / nx;
  const int tid = threadIdx.x, wid = tid >> 6, lane = tid & 63;
  const int fq = lane >> 4, fr = lane & 15;
  const int wr = wid >> 1, wc = wid & 1;
  __shared__ __align__(16) unsigned char lA[128 * 128];
  __shared__ __align__(16) unsigned char lB[128 * 128];
  const int row0 = mtile * 128, col0 = ntile * 128;
  float bs[4];
#pragma unroll
  for (int nt = 0; nt < 4; ++nt) bs[nt] = bias[col0 + wc * 64 + nt * 16 + fr];
  f32x4 acc[4][4];
#pragma unroll
  for (int a = 0; a < 4; ++a)
#pragma unroll
    for (int c = 0; c < 4; ++c) acc[a][c] = (f32x4){0.f, 0.f, 0.f, 0.f};
  const int nkt = K >> 7;  // 12
  for (int kt = 0; kt < nkt; ++kt) {
    const int k0 = kt << 7;
#pragma unroll
    for (int i = 0; i < 4; ++i) {
      int g = i * 256 + tid;
      int r = g >> 3, c8 = g & 7;
      int s8 = c8 ^ (r & 7);
      gload16(A8 + (size_t)(row0 + r) * K + k0 + s8 * 16, (char*)lA + (size_t)g * 16);
      gload16(B8 + (size_t)(col0 + r) * K + k0 + s8 * 16, (char*)lB + (size_t)g * 16);
    }
    __syncthreads();
#pragma unroll
    for (int ss = 0; ss < 2; ++ss) {
      longx2 af[4], bfr[4];
      const int pb = ss * 4 + fq;  // logical 16B block (permuted layout)
#pragma unroll
      for (int mt = 0; mt < 4; ++mt) {
        int r = wr * 64 + mt * 16 + fr;
        int d = pb ^ (r & 7);
        af[mt] = *(const longx2*)&lA[r * 128 + d * 16];
      }
#pragma unroll
      for (int nt = 0; nt < 4; ++nt) {
        int r = wc * 64 + nt * 16 + fr;
        int d = pb ^ (r & 7);
        bfr[nt] = *(const longx2*)&lB[r * 128 + d * 16];
      }
#pragma unroll
      for (int mt = 0; mt < 4; ++mt)
#pragma unroll
        for (int nt = 0; nt < 4; ++nt) {
          acc[mt][nt] = mfma8(af[mt][0], bfr[nt][0], acc[mt][nt]);
          acc[mt][nt] = mfma8(af[mt][1], bfr[nt][1], acc[mt][nt]);
        }
    }
    __syncthreads();
  }
#pragma unroll
  for (int mt = 0; mt < 4; ++mt) {
#pragma unroll
    for (int jj = 0; jj < 4; ++jj) {
      int r = row0 + wr * 64 + mt * 16 + fq * 4 + jj;
      int dmap = rowmap[r];
#pragma unroll
      for (int nt = 0; nt < 4; ++nt) {
        int gcol = col0 + wc * 64 + nt * 16 + fr;
        float v = acc[mt][nt][jj] + bs[nt] + bf2f(add_bf[(size_t)r * DIM_ + gcol]);
        if (dmap >= 0) outf[(size_t)dmap * DIM_ + gcol] = v;
      }
    }
  }
}

// ---------------- attention: one head per wave, fp8 Q/K/V/P ----------------
__global__ __launch_bounds__(256) void attn_k(const unsigned char* __restrict__ qkv8,
                                              const unsigned* __restrict__ bitmap,
                                              const int* __restrict__ ip,
                                              short* __restrict__ o) {
  // bijective XCD swizzle: 4608 = 8 * 576; same-m triplets land on one XCD
  const int flat = (blockIdx.x & 7) * 576 + (blockIdx.x >> 3);
  const int m = flat / 3;
  const int h = (flat % 3) * 4 + (threadIdx.x >> 6);
  const int wid = threadIdx.x >> 6, lane = threadIdx.x & 63;
  const int fq = lane >> 4, fr = lane & 15;
  __shared__ __align__(16) unsigned char P[4][64 * 72];
  __shared__ __align__(16) unsigned char Vt[4][32 * 72];
  __shared__ unsigned char flags[64];
  if (threadIdx.x < 64) {
    int j = ip[m * 64 + threadIdx.x];
    flags[threadIdx.x] = (unsigned char)((bitmap[j >> 5] >> (j & 31)) & 1);
  }
  __syncthreads();
  const float scale = 0.17677669529663687f;
  int msk[4];
#pragma unroll
  for (int nt = 0; nt < 4; ++nt) msk[nt] = flags[nt * 16 + fr];

  const unsigned char* base = qkv8 + (size_t)m * 64 * QKVD_ + h * 96;
  // ---- S = Q K^T (fp8) ----
  f32x4 sacc[4][4];
#pragma unroll
  for (int a = 0; a < 4; ++a)
#pragma unroll
    for (int c = 0; c < 4; ++c) sacc[a][c] = (f32x4){0.f, 0.f, 0.f, 0.f};
  long qa[4], kb[4];
#pragma unroll
  for (int mt = 0; mt < 4; ++mt)
    qa[mt] = *(const long*)(base + (size_t)(mt * 16 + fr) * QKVD_ + fq * 8);
#pragma unroll
  for (int nt = 0; nt < 4; ++nt)
    kb[nt] = *(const long*)(base + (size_t)(nt * 16 + fr) * QKVD_ + 32 + fq * 8);
#pragma unroll
  for (int mt = 0; mt < 4; ++mt)
#pragma unroll
    for (int nt = 0; nt < 4; ++nt)
      sacc[mt][nt] = mfma8(qa[mt], kb[nt], sacc[mt][nt]);
  // ---- stage V^T (fp8) ----
#pragma unroll
  for (int c = 0; c < 2; ++c) {
    u8x16 vv = *(const u8x16*)(base + (size_t)lane * QKVD_ + 64 + c * 16);
#pragma unroll
    for (int e = 0; e < 16; ++e) Vt[wid][(c * 16 + e) * 72 + lane] = vv[e];
  }
  // ---- scale + mask ----
#pragma unroll
  for (int mt = 0; mt < 4; ++mt)
#pragma unroll
    for (int nt = 0; nt < 4; ++nt) {
      f32x4 sv = sacc[mt][nt];
#pragma unroll
      for (int jj = 0; jj < 4; ++jj)
        sv[jj] = msk[nt] ? -10000.0f : sv[jj] * scale;
      sacc[mt][nt] = sv;
    }
  // ---- softmax rows + write P (fp8) ----
#pragma unroll
  for (int mt = 0; mt < 4; ++mt) {
#pragma unroll
    for (int jj = 0; jj < 4; ++jj) {
      float mx = sacc[mt][0][jj];
#pragma unroll
      for (int nt = 1; nt < 4; ++nt) mx = fmaxf(mx, sacc[mt][nt][jj]);
#pragma unroll
      for (int mm = 1; mm < 16; mm <<= 1) mx = fmaxf(mx, __shfl_xor(mx, mm, 64));
      float sm = 0.f;
      float p[4];
#pragma unroll
      for (int nt = 0; nt < 4; ++nt) {
        p[nt] = __expf(sacc[mt][nt][jj] - mx);
        sm += p[nt];
      }
#pragma unroll
      for (int mm = 1; mm < 16; mm <<= 1) sm += __shfl_xor(sm, mm, 64);
      float inv = 1.0f / sm;
      int rowb = (mt * 16 + fq * 4 + jj) * 72;
      int p01 = __builtin_amdgcn_cvt_pk_fp8_f32(p[0] * inv, p[1] * inv, 0, false);
      int p23 = __builtin_amdgcn_cvt_pk_fp8_f32(p[2] * inv, p[3] * inv, 0, false);
      P[wid][rowb + fr]      = (unsigned char)(p01 & 0xff);
      P[wid][rowb + 16 + fr] = (unsigned char)((p01 >> 8) & 0xff);
      P[wid][rowb + 32 + fr] = (unsigned char)(p23 & 0xff);
      P[wid][rowb + 48 + fr] = (unsigned char)((p23 >> 8) & 0xff);
    }
  }
  // ---- O = P V (fp8) ----
  f32x4 oacc[4][2];
#pragma unroll
  for (int a = 0; a < 4; ++a)
#pragma unroll
    for (int c = 0; c < 2; ++c) oacc[a][c] = (f32x4){0.f, 0.f, 0.f, 0.f};
#pragma unroll
  for (int ks = 0; ks < 2; ++ks) {
    long pa[4], vb[2];
#pragma unroll
    for (int mt = 0; mt < 4; ++mt)
      pa[mt] = *(const long*)&P[wid][(mt * 16 + fr) * 72 + ks * 32 + fq * 8];
#pragma unroll
    for (int nd = 0; nd < 2; ++nd)
      vb[nd] = *(const long*)&Vt[wid][(nd * 16 + fr) * 72 + ks * 32 + fq * 8];
#pragma unroll
    for (int mt = 0; mt < 4; ++mt)
#pragma unroll
      for (int nd = 0; nd < 2; ++nd)
        oacc[mt][nd] = mfma8(pa[mt], vb[nd], oacc[mt][nd]);
  }
  // ---- store O (bf16) ----
#pragma unroll
  for (int mt = 0; mt < 4; ++mt)
#pragma unroll
    for (int nd = 0; nd < 2; ++nd)
#pragma unroll
      for (int jj = 0; jj < 4; ++jj)
        o[(size_t)(m * 64 + mt * 16 + fq * 4 + jj) * DIM_ + h * 32 + nd * 16 + fr] =
            f2bf(oacc[mt][nd][jj]);
}

// ---------------- launch ----------------
extern "C" void kernel_launch(void* const* d_in, const int* in_sizes, int n_in,
                              void* d_out, int out_size, void* d_ws, size_t ws_size,
                              hipStream_t stream) {
  const float* x = (const float*)d_in[0];
  const int* iw = (const int*)d_in[1];
  const int* ip = (const int*)d_in[2];
  const int* blk = (const int*)d_in[3];
  const float* ln1w = (const float*)d_in[6];
  const float* ln1b = (const float*)d_in[7];
  const float* qkvw = (const float*)d_in[8];
  const float* qkvb = (const float*)d_in[9];
  const float* projw = (const float*)d_in[10];
  const float* projb = (const float*)d_in[11];
  const float* ln2w = (const float*)d_in[12];
  const float* ln2b = (const float*)d_in[13];
  const float* fc1w = (const float*)d_in[14];
  const float* fc1b = (const float*)d_in[15];
  const float* fc2w = (const float*)d_in[16];
  const float* fc2b = (const float*)d_in[17];
  float* out = (float*)d_out;

  char* ws = (char*)d_ws;
  short* w_all = (short*)ws;                 // 1,179,648 bf16 (qkv, proj, fc1)
  short* w_qkv = w_all;
  short* w_proj = w_all + 442368;
  short* w_fc1 = w_all + 589824;
  int* inv_ip = (int*)(ws + 3538944);
  int* rowmap = inv_ip + NTOK_;
  int* win_rank = rowmap + NTOK_;
  unsigned* bitmap = (unsigned*)(win_rank + NW_);
  short* xp = (short*)(ws + 4349952);                        // 75.5 MB (also ln2 out)
  unsigned char* qkv8 = (unsigned char*)(ws + 4349952 + 75497472);  // 113 MB fp8 qkv
  unsigned char* t8 = qkv8;                                  // fp8 gelu (FC1 out, later)
  unsigned char* w2f8 = (unsigned char*)(ws + 306339840);    // 576 KB fp8 fc2w
  short* obuf = (short*)(ws + 381837312);                    // 75.5 MB
  short* hbuf = (short*)(ws + 457334784);                    // 75.5 MB
  short* ln2buf = xp;
  (void)in_sizes; (void)n_in; (void)out_size; (void)ws_size;

  mapA_k<<<12, 256, 0, stream>>>(win_rank, bitmap);
  mapB_k<<<39, 256, 0, stream>>>(iw, blk, win_rank, bitmap);
  mapC_k<<<NTOK_ / 256, 256, 0, stream>>>(ip, iw, bitmap, inv_ip, rowmap);
  wconv_k<<<1152, 256, 0, stream>>>(qkvw, projw, fc1w, w_all);
  wconv8_k<<<288, 256, 0, stream>>>(fc2w, w2f8);
  ln1_k<<<(NW_ * 64) / 8, 256, 0, stream>>>(x, ln1w, ln1b, win_rank, inv_ip, bitmap,
                                            out, xp);
  // 256-row mtiles = 384; 128-row mtiles = 768
  gemm_k<0><<<384 * 9, 512, 0, stream>>>(xp, w_qkv, qkvb, 384, QKVD_, 9, qkv8);
  attn_k<<<WACT_ * 3, 256, 0, stream>>>(qkv8, bitmap, ip, obuf);
  gemm128_k<<<768 * 3, 256, 0, stream>>>(obuf, w_proj, projb, 384, 3, hbuf, xp);
  ln2_k<<<NTOK_ / 8, 256, 0, stream>>>(hbuf, ln2w, ln2b, ln2buf);
  gemm_k<2><<<384 * 12, 512, 0, stream>>>(ln2buf, w_fc1, fc1b, 384, MLPD_, 12, t8);
  gemmf8_k<<<768 * 3, 256, 0, stream>>>(t8, w2f8, fc2b, 3, hbuf, rowmap, out);
}

// Round 19
// 703.974 us; speedup vs baseline: 1.2247x; 1.0575x over previous
//
#include <hip/hip_runtime.h>
#include <hip/hip_bf16.h>

typedef __attribute__((ext_vector_type(8))) short bf16x8;
typedef __attribute__((ext_vector_type(4))) short s16x4;
typedef __attribute__((ext_vector_type(4))) float f32x4;
typedef __attribute__((ext_vector_type(2))) long longx2;
typedef __attribute__((ext_vector_type(16))) unsigned char u8x16;

#define NW_   3072
#define WACT_ 1536
#define NTOK_ 98304
#define NBLK_ 9830
#define DIM_  384
#define QKVD_ 1152
#define MLPD_ 1536

__device__ __forceinline__ float bf2f(short s) {
  union { unsigned u; float f; } c;
  c.u = ((unsigned)(unsigned short)s) << 16;
  return c.f;
}
__device__ __forceinline__ short f2bf(float f) {
  union { float f; unsigned u; } c; c.f = f;
  unsigned lsb = (c.u >> 16) & 1u;
  c.u += 0x7fffu + lsb;
  return (short)(c.u >> 16);
}

__device__ __forceinline__ f32x4 mfma16(bf16x8 a, bf16x8 b, f32x4 c) {
  return __builtin_amdgcn_mfma_f32_16x16x32_bf16(a, b, c, 0, 0, 0);
}
__device__ __forceinline__ f32x4 mfma8(long a, long b, f32x4 c) {
  return __builtin_amdgcn_mfma_f32_16x16x32_fp8_fp8(a, b, c, 0, 0, 0);
}

__device__ __forceinline__ void gload16(const void* g, void* l) {
  __builtin_amdgcn_global_load_lds(
      (const __attribute__((address_space(1))) unsigned*)g,
      (__attribute__((address_space(3))) unsigned*)l, 16, 0, 0);
}

// K-perm byte position within a row: col -> group*64 + slot*8 + (col&7),
// slot = ((l&3)<<1)|(l>>2), l = (col>>3)&7.  (Proven R17 convention.)
__device__ __forceinline__ int kperm(int col) {
  int l = (col >> 3) & 7;
  int s = ((l & 3) << 1) | (l >> 2);
  return (col & ~63) + s * 8 + (col & 7);
}

// ---------------- map kernels ----------------
__global__ __launch_bounds__(256) void mapA_k(int* win_rank, unsigned* bitmap) {
  int t = blockIdx.x * 256 + threadIdx.x;
  if (t < NW_) { win_rank[t] = -1; bitmap[t] = 0u; }
}

__global__ __launch_bounds__(256) void mapB_k(const int* __restrict__ iw,
                                              const int* __restrict__ blk,
                                              int* win_rank, unsigned* bitmap) {
  int t = blockIdx.x * 256 + threadIdx.x;
  if (t < WACT_) win_rank[iw[t]] = t;
  if (t < NBLK_) { int j = blk[t]; atomicOr(&bitmap[j >> 5], 1u << (j & 31)); }
}

__global__ __launch_bounds__(256) void mapC_k(const int* __restrict__ ip,
                                              const int* __restrict__ iw,
                                              const unsigned* __restrict__ bitmap,
                                              int* inv_ip, int* rowmap) {
  int i = blockIdx.x * 256 + threadIdx.x;
  if (i < NTOK_) {
    int j = ip[i];
    inv_ip[j] = i;
    int blocked = (bitmap[j >> 5] >> (j & 31)) & 1;
    rowmap[i] = blocked ? -1 : (iw[j >> 6] * 64 + (j & 63));
  }
}

// ---------------- weight conversion: qkvw -> bf16 ----------------
__global__ __launch_bounds__(256) void wconv_k(const float* __restrict__ qkvw,
                                               short* __restrict__ dst) {
  int i = (blockIdx.x * 256 + threadIdx.x) * 4;  // 442,368 elems -> 432 blocks
  f32x4 v = *(const f32x4*)&qkvw[i];
  s16x4 o;
#pragma unroll
  for (int e = 0; e < 4; ++e) o[e] = f2bf(v[e]);
  *(s16x4*)&dst[i] = o;
}

// weights -> fp8 e4m3 (HW cvt), K-permuted. Thread = one 8B chunk.
__global__ __launch_bounds__(256) void wconv8_k(const float* __restrict__ src,
                                                unsigned char* __restrict__ dst,
                                                int K) {
  int i = (blockIdx.x * 256 + threadIdx.x) * 8;
  f32x4 v0 = *(const f32x4*)&src[i];
  f32x4 v1 = *(const f32x4*)&src[i + 4];
  int w0 = __builtin_amdgcn_cvt_pk_fp8_f32(v0[0], v0[1], 0, false);
  w0 = __builtin_amdgcn_cvt_pk_fp8_f32(v0[2], v0[3], w0, true);
  int w1 = __builtin_amdgcn_cvt_pk_fp8_f32(v1[0], v1[1], 0, false);
  w1 = __builtin_amdgcn_cvt_pk_fp8_f32(v1[2], v1[3], w1, true);
  int kro = i % K, row = i / K;
  union { int u[2]; long ll; } p; p.u[0] = w0; p.u[1] = w1;
  *(long*)&dst[(size_t)row * K + kperm(kro)] = p.ll;
}

// ---------------- LN1 + gather/permute (vectorized: 32 lanes/token) --------
__global__ __launch_bounds__(256) void ln1_k(const float* __restrict__ x,
                                             const float* __restrict__ w,
                                             const float* __restrict__ b,
                                             const int* __restrict__ win_rank,
                                             const int* __restrict__ inv_ip,
                                             const unsigned* __restrict__ bitmap,
                                             float* __restrict__ out,
                                             short* __restrict__ xp) {
  const int l = threadIdx.x & 31;
  const int tok = blockIdx.x * 8 + (threadIdx.x >> 5);
  const f32x4* xr = (const f32x4*)(x + (size_t)tok * DIM_);
  f32x4 v[3]; float s = 0.f;
#pragma unroll
  for (int j = 0; j < 3; ++j) {
    v[j] = xr[l + 32 * j];
    s += v[j][0] + v[j][1] + v[j][2] + v[j][3];
  }
#pragma unroll
  for (int m = 1; m <= 16; m <<= 1) s += __shfl_xor(s, m, 64);
  float mu = s * (1.0f / DIM_);
  float q = 0.f;
#pragma unroll
  for (int j = 0; j < 3; ++j)
#pragma unroll
    for (int e = 0; e < 4; ++e) { float d = v[j][e] - mu; q += d * d; }
#pragma unroll
  for (int m = 1; m <= 16; m <<= 1) q += __shfl_xor(q, m, 64);
  float rs = rsqrtf(q * (1.0f / DIM_) + 1e-5f);
  f32x4 y[3];
#pragma unroll
  for (int j = 0; j < 3; ++j) {
    f32x4 wv = *(const f32x4*)&w[4 * l + 128 * j];
    f32x4 bv = *(const f32x4*)&b[4 * l + 128 * j];
#pragma unroll
    for (int e = 0; e < 4; ++e) y[j][e] = (v[j][e] - mu) * rs * wv[e] + bv[e];
  }
  int wdw = tok >> 6, t = tok & 63;
  int rank = win_rank[wdw];
  if (rank < 0) {
    f32x4* po = (f32x4*)(out + (size_t)tok * DIM_);
#pragma unroll
    for (int j = 0; j < 3; ++j) po[l + 32 * j] = y[j];
  } else {
    int jdx = (rank << 6) + t;
    int i = inv_ip[jdx];
#pragma unroll
    for (int j = 0; j < 3; ++j) {
      s16x4 o;
#pragma unroll
      for (int e = 0; e < 4; ++e) o[e] = f2bf(y[j][e]);
      *(s16x4*)&xp[(size_t)i * DIM_ + 4 * l + 128 * j] = o;
    }
    if ((bitmap[jdx >> 5] >> (jdx & 31)) & 1) {
      f32x4* po = (f32x4*)(out + (size_t)tok * DIM_);
#pragma unroll
      for (int j = 0; j < 3; ++j) po[l + 32 * j] = y[j];
    }
  }
}

// ---------------- LN2 -> fp8 K-permuted ----------------
__global__ __launch_bounds__(256) void ln2_k(const short* __restrict__ h,
                                             const float* __restrict__ w,
                                             const float* __restrict__ b,
                                             unsigned char* __restrict__ out8) {
  const int l = threadIdx.x & 31;
  const int tok = blockIdx.x * 8 + (threadIdx.x >> 5);
  const s16x4* xr = (const s16x4*)(h + (size_t)tok * DIM_);
  float v[12]; float s = 0.f;
#pragma unroll
  for (int j = 0; j < 3; ++j) {
    s16x4 rv = xr[l + 32 * j];
#pragma unroll
    for (int e = 0; e < 4; ++e) { v[j * 4 + e] = bf2f(rv[e]); s += v[j * 4 + e]; }
  }
#pragma unroll
  for (int m = 1; m <= 16; m <<= 1) s += __shfl_xor(s, m, 64);
  float mu = s * (1.0f / DIM_);
  float q = 0.f;
#pragma unroll
  for (int e = 0; e < 12; ++e) { float d = v[e] - mu; q += d * d; }
#pragma unroll
  for (int m = 1; m <= 16; m <<= 1) q += __shfl_xor(q, m, 64);
  float rs = rsqrtf(q * (1.0f / DIM_) + 1e-5f);
#pragma unroll
  for (int j = 0; j < 3; ++j) {
    f32x4 wv = *(const f32x4*)&w[4 * l + 128 * j];
    f32x4 bv = *(const f32x4*)&b[4 * l + 128 * j];
    float y[4];
#pragma unroll
    for (int e = 0; e < 4; ++e)
      y[e] = (v[j * 4 + e] - mu) * rs * wv[e] + bv[e];
    int wrd = __builtin_amdgcn_cvt_pk_fp8_f32(y[0], y[1], 0, false);
    wrd = __builtin_amdgcn_cvt_pk_fp8_f32(y[2], y[3], wrd, true);
    int c0 = 4 * l + 128 * j;  // 4-aligned within an 8B chunk
    *(unsigned*)&out8[(size_t)tok * DIM_ + kperm(c0)] = (unsigned)wrd;
  }
}

// ---------------- QKV GEMM bf16 (256x128, 8 waves) -> fp8 plain ------------
__global__ __launch_bounds__(512) void gemmqkv_k(const short* __restrict__ A,
                                                 const short* __restrict__ B,
                                                 const float* __restrict__ bias,
                                                 unsigned char* __restrict__ C8) {
  const int K = 384, N = QKVD_, nx = 9;
  const int nwg = gridDim.x;
  const int q8 = nwg >> 3;
  const int wg = (blockIdx.x & 7) * q8 + (blockIdx.x >> 3);
  const int ntile = wg % nx, mtile = wg / nx;
  const int tid = threadIdx.x, wid = tid >> 6, lane = tid & 63;
  const int fq = lane >> 4, fr = lane & 15;
  const int wr = wid >> 1, wc = wid & 1;
  __shared__ __align__(16) short lA[256 * 64];
  __shared__ __align__(16) short lB[128 * 64];
  const int row0 = mtile * 256, col0 = ntile * 128;
  float bs[4];
#pragma unroll
  for (int nt = 0; nt < 4; ++nt) bs[nt] = bias[col0 + wc * 64 + nt * 16 + fr];
  f32x4 acc[4][4];
#pragma unroll
  for (int a = 0; a < 4; ++a)
#pragma unroll
    for (int c = 0; c < 4; ++c) acc[a][c] = (f32x4){0.f, 0.f, 0.f, 0.f};
  const int nkt = K >> 6;
  for (int kt = 0; kt < nkt; ++kt) {
    const int k0 = kt << 6;
#pragma unroll
    for (int i = 0; i < 4; ++i) {
      int g = i * 512 + tid;
      int r = g >> 3, c8 = g & 7;
      int s8 = c8 ^ (r & 7);
      gload16(A + (size_t)(row0 + r) * K + k0 + s8 * 8, (char*)lA + (size_t)g * 16);
    }
#pragma unroll
    for (int i = 0; i < 2; ++i) {
      int g = i * 512 + tid;
      int r = g >> 3, c8 = g & 7;
      int s8 = c8 ^ (r & 7);
      gload16(B + (size_t)(col0 + r) * K + k0 + s8 * 8, (char*)lB + (size_t)g * 16);
    }
    __syncthreads();
#pragma unroll
    for (int ks = 0; ks < 2; ++ks) {
      bf16x8 af[4], bfr[4];
#pragma unroll
      for (int mt = 0; mt < 4; ++mt) {
        int r = wr * 64 + mt * 16 + fr;
        af[mt] = *(const bf16x8*)&lA[r * 64 + ((ks * 4 + fq) ^ (r & 7)) * 8];
      }
#pragma unroll
      for (int nt = 0; nt < 4; ++nt) {
        int r = wc * 64 + nt * 16 + fr;
        bfr[nt] = *(const bf16x8*)&lB[r * 64 + ((ks * 4 + fq) ^ (r & 7)) * 8];
      }
#pragma unroll
      for (int mt = 0; mt < 4; ++mt)
#pragma unroll
        for (int nt = 0; nt < 4; ++nt)
          acc[mt][nt] = mfma16(af[mt], bfr[nt], acc[mt][nt]);
    }
    __syncthreads();
  }
#pragma unroll
  for (int mt = 0; mt < 4; ++mt) {
#pragma unroll
    for (int jj = 0; jj < 4; ++jj) {
      int r = row0 + wr * 64 + mt * 16 + fq * 4 + jj;
      float g4[4];
#pragma unroll
      for (int nt = 0; nt < 4; ++nt) g4[nt] = acc[mt][nt][jj] + bs[nt];
      int p01 = __builtin_amdgcn_cvt_pk_fp8_f32(g4[0], g4[1], 0, false);
      int p23 = __builtin_amdgcn_cvt_pk_fp8_f32(g4[2], g4[3], 0, false);
      const size_t rb = (size_t)r * N + col0 + wc * 64 + fr;
      C8[rb]      = (unsigned char)(p01 & 0xff);
      C8[rb + 16] = (unsigned char)((p01 >> 8) & 0xff);
      C8[rb + 32] = (unsigned char)(p23 & 0xff);
      C8[rb + 48] = (unsigned char)((p23 >> 8) & 0xff);
    }
  }
}

// ---------------- Generic fp8 GEMM (K-permuted operands) ----------------
// 128x128 tile, BK=128 fp8, ds_read_b128 conflict-free (proven R17).
// EPI 1: +bias +add_bf -> bf16       (proj + residual -> h)
// EPI 2: +bias, gelu -> fp8 K-perm   (fc1 -> t8, ld MLPD_)
// EPI 3: +bias +add_bf, scatter fp32 (fc2 + residual -> out)
template <int EPI>
__global__ __launch_bounds__(256) void gemmf8_k(const unsigned char* __restrict__ A8,
                                                const unsigned char* __restrict__ B8,
                                                const float* __restrict__ bias,
                                                int K, int nx,
                                                short* __restrict__ Cb,
                                                unsigned char* __restrict__ C8,
                                                const short* __restrict__ add_bf,
                                                const int* __restrict__ rowmap,
                                                float* __restrict__ outf) {
  const int nwg = gridDim.x;
  const int q8 = nwg >> 3;
  const int wg = (blockIdx.x & 7) * q8 + (blockIdx.x >> 3);
  const int ntile = wg % nx, mtile = wg / nx;
  const int tid = threadIdx.x, wid = tid >> 6, lane = tid & 63;
  const int fq = lane >> 4, fr = lane & 15;
  const int wr = wid >> 1, wc = wid & 1;
  __shared__ __align__(16) unsigned char lA[128 * 128];
  __shared__ __align__(16) unsigned char lB[128 * 128];
  const int row0 = mtile * 128, col0 = ntile * 128;
  float bs[4];
#pragma unroll
  for (int nt = 0; nt < 4; ++nt) bs[nt] = bias[col0 + wc * 64 + nt * 16 + fr];
  f32x4 acc[4][4];
#pragma unroll
  for (int a = 0; a < 4; ++a)
#pragma unroll
    for (int c = 0; c < 4; ++c) acc[a][c] = (f32x4){0.f, 0.f, 0.f, 0.f};
  const int nkt = K >> 7;  // 3 or 12
  for (int kt = 0; kt < nkt; ++kt) {
    const int k0 = kt << 7;
#pragma unroll
    for (int i = 0; i < 4; ++i) {
      int g = i * 256 + tid;
      int r = g >> 3, c8 = g & 7;
      int s8 = c8 ^ (r & 7);
      gload16(A8 + (size_t)(row0 + r) * K + k0 + s8 * 16, (char*)lA + (size_t)g * 16);
      gload16(B8 + (size_t)(col0 + r) * K + k0 + s8 * 16, (char*)lB + (size_t)g * 16);
    }
    __syncthreads();
#pragma unroll
    for (int ss = 0; ss < 2; ++ss) {
      longx2 af[4], bfr[4];
      const int pb = ss * 4 + fq;
#pragma unroll
      for (int mt = 0; mt < 4; ++mt) {
        int r = wr * 64 + mt * 16 + fr;
        int d = pb ^ (r & 7);
        af[mt] = *(const longx2*)&lA[r * 128 + d * 16];
      }
#pragma unroll
      for (int nt = 0; nt < 4; ++nt) {
        int r = wc * 64 + nt * 16 + fr;
        int d = pb ^ (r & 7);
        bfr[nt] = *(const longx2*)&lB[r * 128 + d * 16];
      }
#pragma unroll
      for (int mt = 0; mt < 4; ++mt)
#pragma unroll
        for (int nt = 0; nt < 4; ++nt) {
          acc[mt][nt] = mfma8(af[mt][0], bfr[nt][0], acc[mt][nt]);
          acc[mt][nt] = mfma8(af[mt][1], bfr[nt][1], acc[mt][nt]);
        }
    }
    __syncthreads();
  }
#pragma unroll
  for (int mt = 0; mt < 4; ++mt) {
#pragma unroll
    for (int jj = 0; jj < 4; ++jj) {
      int r = row0 + wr * 64 + mt * 16 + fq * 4 + jj;
      int dmap = 0;
      if (EPI == 3) dmap = rowmap[r];
      if (EPI == 1) {
#pragma unroll
        for (int nt = 0; nt < 4; ++nt) {
          int gcol = col0 + wc * 64 + nt * 16 + fr;
          float v = acc[mt][nt][jj] + bs[nt] + bf2f(add_bf[(size_t)r * DIM_ + gcol]);
          Cb[(size_t)r * DIM_ + gcol] = f2bf(v);
        }
      } else if (EPI == 2) {
        float g4[4];
#pragma unroll
        for (int nt = 0; nt < 4; ++nt) {
          float v = acc[mt][nt][jj] + bs[nt];
          float u = v * (0.79788456f + 0.03567741f * v * v);
          g4[nt] = v * __builtin_amdgcn_rcpf(1.0f + __expf(-2.0f * u));
        }
        int p01 = __builtin_amdgcn_cvt_pk_fp8_f32(g4[0], g4[1], 0, false);
        int p23 = __builtin_amdgcn_cvt_pk_fp8_f32(g4[2], g4[3], 0, false);
        const int C0 = col0 + wc * 64;
        const size_t rb = (size_t)r * MLPD_ + C0 + (fr & 7) + ((fr >> 3) << 4);
        C8[rb]      = (unsigned char)(p01 & 0xff);
        C8[rb + 32] = (unsigned char)((p01 >> 8) & 0xff);
        C8[rb + 8]  = (unsigned char)(p23 & 0xff);
        C8[rb + 40] = (unsigned char)((p23 >> 8) & 0xff);
      } else {
#pragma unroll
        for (int nt = 0; nt < 4; ++nt) {
          int gcol = col0 + wc * 64 + nt * 16 + fr;
          float v = acc[mt][nt][jj] + bs[nt] + bf2f(add_bf[(size_t)r * DIM_ + gcol]);
          if (dmap >= 0) outf[(size_t)dmap * DIM_ + gcol] = v;
        }
      }
    }
  }
}

// ---------------- attention: one head per wave, fp8; out fp8 K-perm --------
__global__ __launch_bounds__(256) void attn_k(const unsigned char* __restrict__ qkv8,
                                              const unsigned* __restrict__ bitmap,
                                              const int* __restrict__ ip,
                                              unsigned char* __restrict__ o8) {
  const int flat = (blockIdx.x & 7) * 576 + (blockIdx.x >> 3);
  const int m = flat / 3;
  const int h = (flat % 3) * 4 + (threadIdx.x >> 6);
  const int wid = threadIdx.x >> 6, lane = threadIdx.x & 63;
  const int fq = lane >> 4, fr = lane & 15;
  __shared__ __align__(16) unsigned char P[4][64 * 72];
  __shared__ __align__(16) unsigned char Vt[4][32 * 72];
  __shared__ unsigned char flags[64];
  if (threadIdx.x < 64) {
    int j = ip[m * 64 + threadIdx.x];
    flags[threadIdx.x] = (unsigned char)((bitmap[j >> 5] >> (j & 31)) & 1);
  }
  __syncthreads();
  const float scale = 0.17677669529663687f;
  int msk[4];
#pragma unroll
  for (int nt = 0; nt < 4; ++nt) msk[nt] = flags[nt * 16 + fr];

  const unsigned char* base = qkv8 + (size_t)m * 64 * QKVD_ + h * 96;
  f32x4 sacc[4][4];
#pragma unroll
  for (int a = 0; a < 4; ++a)
#pragma unroll
    for (int c = 0; c < 4; ++c) sacc[a][c] = (f32x4){0.f, 0.f, 0.f, 0.f};
  long qa[4], kb[4];
#pragma unroll
  for (int mt = 0; mt < 4; ++mt)
    qa[mt] = *(const long*)(base + (size_t)(mt * 16 + fr) * QKVD_ + fq * 8);
#pragma unroll
  for (int nt = 0; nt < 4; ++nt)
    kb[nt] = *(const long*)(base + (size_t)(nt * 16 + fr) * QKVD_ + 32 + fq * 8);
#pragma unroll
  for (int mt = 0; mt < 4; ++mt)
#pragma unroll
    for (int nt = 0; nt < 4; ++nt)
      sacc[mt][nt] = mfma8(qa[mt], kb[nt], sacc[mt][nt]);
#pragma unroll
  for (int c = 0; c < 2; ++c) {
    u8x16 vv = *(const u8x16*)(base + (size_t)lane * QKVD_ + 64 + c * 16);
#pragma unroll
    for (int e = 0; e < 16; ++e) Vt[wid][(c * 16 + e) * 72 + lane] = vv[e];
  }
#pragma unroll
  for (int mt = 0; mt < 4; ++mt)
#pragma unroll
    for (int nt = 0; nt < 4; ++nt) {
      f32x4 sv = sacc[mt][nt];
#pragma unroll
      for (int jj = 0; jj < 4; ++jj)
        sv[jj] = msk[nt] ? -10000.0f : sv[jj] * scale;
      sacc[mt][nt] = sv;
    }
#pragma unroll
  for (int mt = 0; mt < 4; ++mt) {
#pragma unroll
    for (int jj = 0; jj < 4; ++jj) {
      float mx = sacc[mt][0][jj];
#pragma unroll
      for (int nt = 1; nt < 4; ++nt) mx = fmaxf(mx, sacc[mt][nt][jj]);
#pragma unroll
      for (int mm = 1; mm < 16; mm <<= 1) mx = fmaxf(mx, __shfl_xor(mx, mm, 64));
      float sm = 0.f;
      float p[4];
#pragma unroll
      for (int nt = 0; nt < 4; ++nt) {
        p[nt] = __expf(sacc[mt][nt][jj] - mx);
        sm += p[nt];
      }
#pragma unroll
      for (int mm = 1; mm < 16; mm <<= 1) sm += __shfl_xor(sm, mm, 64);
      float inv = 1.0f / sm;
      int rowb = (mt * 16 + fq * 4 + jj) * 72;
      int p01 = __builtin_amdgcn_cvt_pk_fp8_f32(p[0] * inv, p[1] * inv, 0, false);
      int p23 = __builtin_amdgcn_cvt_pk_fp8_f32(p[2] * inv, p[3] * inv, 0, false);
      P[wid][rowb + fr]      = (unsigned char)(p01 & 0xff);
      P[wid][rowb + 16 + fr] = (unsigned char)((p01 >> 8) & 0xff);
      P[wid][rowb + 32 + fr] = (unsigned char)(p23 & 0xff);
      P[wid][rowb + 48 + fr] = (unsigned char)((p23 >> 8) & 0xff);
    }
  }
  f32x4 oacc[4][2];
#pragma unroll
  for (int a = 0; a < 4; ++a)
#pragma unroll
    for (int c = 0; c < 2; ++c) oacc[a][c] = (f32x4){0.f, 0.f, 0.f, 0.f};
#pragma unroll
  for (int ks = 0; ks < 2; ++ks) {
    long pa[4], vb[2];
#pragma unroll
    for (int mt = 0; mt < 4; ++mt)
      pa[mt] = *(const long*)&P[wid][(mt * 16 + fr) * 72 + ks * 32 + fq * 8];
#pragma unroll
    for (int nd = 0; nd < 2; ++nd)
      vb[nd] = *(const long*)&Vt[wid][(nd * 16 + fr) * 72 + ks * 32 + fq * 8];
#pragma unroll
    for (int mt = 0; mt < 4; ++mt)
#pragma unroll
      for (int nd = 0; nd < 2; ++nd)
        oacc[mt][nd] = mfma8(pa[mt], vb[nd], oacc[mt][nd]);
  }
  // ---- store O as fp8 K-permuted (row length DIM_) ----
  const int pos0 = kperm(h * 32 + fr);
  const int pos1 = kperm(h * 32 + 16 + fr);
#pragma unroll
  for (int mt = 0; mt < 4; ++mt)
#pragma unroll
    for (int jj = 0; jj < 4; ++jj) {
      int p01 = __builtin_amdgcn_cvt_pk_fp8_f32(oacc[mt][0][jj], oacc[mt][1][jj],
                                                0, false);
      size_t rb = (size_t)(m * 64 + mt * 16 + fq * 4 + jj) * DIM_;
      o8[rb + pos0] = (unsigned char)(p01 & 0xff);
      o8[rb + pos1] = (unsigned char)((p01 >> 8) & 0xff);
    }
}

// ---------------- launch ----------------
extern "C" void kernel_launch(void* const* d_in, const int* in_sizes, int n_in,
                              void* d_out, int out_size, void* d_ws, size_t ws_size,
                              hipStream_t stream) {
  const float* x = (const float*)d_in[0];
  const int* iw = (const int*)d_in[1];
  const int* ip = (const int*)d_in[2];
  const int* blk = (const int*)d_in[3];
  const float* ln1w = (const float*)d_in[6];
  const float* ln1b = (const float*)d_in[7];
  const float* qkvw = (const float*)d_in[8];
  const float* qkvb = (const float*)d_in[9];
  const float* projw = (const float*)d_in[10];
  const float* projb = (const float*)d_in[11];
  const float* ln2w = (const float*)d_in[12];
  const float* ln2b = (const float*)d_in[13];
  const float* fc1w = (const float*)d_in[14];
  const float* fc1b = (const float*)d_in[15];
  const float* fc2w = (const float*)d_in[16];
  const float* fc2b = (const float*)d_in[17];
  float* out = (float*)d_out;

  char* ws = (char*)d_ws;
  short* w_qkv = (short*)ws;                                 // 884,736 B bf16
  unsigned char* projw8 = (unsigned char*)(ws + 884736);     // 147,456
  unsigned char* fc1w8 = (unsigned char*)(ws + 1032192);     // 589,824
  unsigned char* fc2w8 = (unsigned char*)(ws + 1622016);     // 589,824
  int* inv_ip = (int*)(ws + 2211840);
  int* rowmap = inv_ip + NTOK_;
  int* win_rank = rowmap + NTOK_;
  unsigned* bitmap = (unsigned*)(win_rank + NW_);
  short* xp = (short*)(ws + 4349952);                        // 75.5 MB bf16
  unsigned char* qkv8 = (unsigned char*)(ws + 79847424);     // 113 MB fp8
  unsigned char* t8 = qkv8;                                  // 151 MB fp8 (after attn)
  unsigned char* obuf8 = (unsigned char*)(ws + 306339840);   // 37.7 MB fp8
  unsigned char* ln2buf8 = (unsigned char*)(ws + 344088576); // 37.7 MB fp8
  short* hbuf = (short*)(ws + 457334784);                    // 75.5 MB bf16
  (void)in_sizes; (void)n_in; (void)out_size; (void)ws_size;

  mapA_k<<<12, 256, 0, stream>>>(win_rank, bitmap);
  mapB_k<<<39, 256, 0, stream>>>(iw, blk, win_rank, bitmap);
  mapC_k<<<NTOK_ / 256, 256, 0, stream>>>(ip, iw, bitmap, inv_ip, rowmap);
  wconv_k<<<432, 256, 0, stream>>>(qkvw, w_qkv);
  wconv8_k<<<72, 256, 0, stream>>>(projw, projw8, 384);
  wconv8_k<<<288, 256, 0, stream>>>(fc1w, fc1w8, 384);
  wconv8_k<<<288, 256, 0, stream>>>(fc2w, fc2w8, MLPD_);
  ln1_k<<<(NW_ * 64) / 8, 256, 0, stream>>>(x, ln1w, ln1b, win_rank, inv_ip, bitmap,
                                            out, xp);
  gemmqkv_k<<<384 * 9, 512, 0, stream>>>(xp, w_qkv, qkvb, qkv8);
  attn_k<<<WACT_ * 3, 256, 0, stream>>>(qkv8, bitmap, ip, obuf8);
  gemmf8_k<1><<<768 * 3, 256, 0, stream>>>(obuf8, projw8, projb, 384, 3, hbuf,
                                           nullptr, xp, nullptr, nullptr);
  ln2_k<<<NTOK_ / 8, 256, 0, stream>>>(hbuf, ln2w, ln2b, ln2buf8);
  gemmf8_k<2><<<768 * 12, 256, 0, stream>>>(ln2buf8, fc1w8, fc1b, 384, 12, nullptr,
                                            t8, nullptr, nullptr, nullptr);
  gemmf8_k<3><<<768 * 3, 256, 0, stream>>>(t8, fc2w8, fc2b, MLPD_, 3, nullptr,
                                           nullptr, hbuf, rowmap, out);
}

// Round 20
// 623.080 us; speedup vs baseline: 1.3837x; 1.1298x over previous
//
#include <hip/hip_runtime.h>
#include <hip/hip_bf16.h>

typedef __attribute__((ext_vector_type(8))) short bf16x8;
typedef __attribute__((ext_vector_type(4))) short s16x4;
typedef __attribute__((ext_vector_type(4))) float f32x4;
typedef __attribute__((ext_vector_type(2))) long longx2;
typedef __attribute__((ext_vector_type(16))) unsigned char u8x16;

#define NW_   3072
#define WACT_ 1536
#define NTOK_ 98304
#define NBLK_ 9830
#define DIM_  384
#define QKVD_ 1152
#define MLPD_ 1536

__device__ __forceinline__ float bf2f(short s) {
  union { unsigned u; float f; } c;
  c.u = ((unsigned)(unsigned short)s) << 16;
  return c.f;
}
__device__ __forceinline__ short f2bf(float f) {
  union { float f; unsigned u; } c; c.f = f;
  unsigned lsb = (c.u >> 16) & 1u;
  c.u += 0x7fffu + lsb;
  return (short)(c.u >> 16);
}

__device__ __forceinline__ f32x4 mfma16(bf16x8 a, bf16x8 b, f32x4 c) {
  return __builtin_amdgcn_mfma_f32_16x16x32_bf16(a, b, c, 0, 0, 0);
}
__device__ __forceinline__ f32x4 mfma8(long a, long b, f32x4 c) {
  return __builtin_amdgcn_mfma_f32_16x16x32_fp8_fp8(a, b, c, 0, 0, 0);
}

__device__ __forceinline__ void gload16(const void* g, void* l) {
  __builtin_amdgcn_global_load_lds(
      (const __attribute__((address_space(1))) unsigned*)g,
      (__attribute__((address_space(3))) unsigned*)l, 16, 0, 0);
}

// K-perm byte position within a row: col -> group*64 + slot*8 + (col&7),
// slot = ((l&3)<<1)|(l>>2), l = (col>>3)&7.  (Proven R17 convention.)
__device__ __forceinline__ int kperm(int col) {
  int l = (col >> 3) & 7;
  int s = ((l & 3) << 1) | (l >> 2);
  return (col & ~63) + s * 8 + (col & 7);
}

// ---------------- merged prologue: mapA + weight conversions ----------------
__device__ __forceinline__ void conv8_chunk(const float* __restrict__ src,
                                            unsigned char* __restrict__ dst,
                                            int K, int blk, int tid) {
  int i = (blk * 256 + tid) * 8;
  f32x4 v0 = *(const f32x4*)&src[i];
  f32x4 v1 = *(const f32x4*)&src[i + 4];
  int w0 = __builtin_amdgcn_cvt_pk_fp8_f32(v0[0], v0[1], 0, false);
  w0 = __builtin_amdgcn_cvt_pk_fp8_f32(v0[2], v0[3], w0, true);
  int w1 = __builtin_amdgcn_cvt_pk_fp8_f32(v1[0], v1[1], 0, false);
  w1 = __builtin_amdgcn_cvt_pk_fp8_f32(v1[2], v1[3], w1, true);
  int kro = i % K, row = i / K;
  union { int u[2]; long ll; } p; p.u[0] = w0; p.u[1] = w1;
  *(long*)&dst[(size_t)row * K + kperm(kro)] = p.ll;
}

__global__ __launch_bounds__(256) void pre_k(const float* __restrict__ qkvw,
                                             const float* __restrict__ projw,
                                             const float* __restrict__ fc1w,
                                             const float* __restrict__ fc2w,
                                             short* __restrict__ wq,
                                             unsigned char* __restrict__ pw8,
                                             unsigned char* __restrict__ f1w8,
                                             unsigned char* __restrict__ f2w8,
                                             int* win_rank, unsigned* bitmap) {
  const int bid = blockIdx.x, tid = threadIdx.x;
  if (bid < 12) {
    int t = bid * 256 + tid;
    if (t < NW_) { win_rank[t] = -1; bitmap[t] = 0u; }
  } else if (bid < 444) {
    int i = ((bid - 12) * 256 + tid) * 4;
    f32x4 v = *(const f32x4*)&qkvw[i];
    s16x4 o;
#pragma unroll
    for (int e = 0; e < 4; ++e) o[e] = f2bf(v[e]);
    *(s16x4*)&wq[i] = o;
  } else if (bid < 516) {
    conv8_chunk(projw, pw8, 384, bid - 444, tid);
  } else if (bid < 804) {
    conv8_chunk(fc1w, f1w8, 384, bid - 516, tid);
  } else {
    conv8_chunk(fc2w, f2w8, MLPD_, bid - 804, tid);
  }
}

// ---------------- map kernels ----------------
__global__ __launch_bounds__(256) void mapB_k(const int* __restrict__ iw,
                                              const int* __restrict__ blk,
                                              int* win_rank, unsigned* bitmap) {
  int t = blockIdx.x * 256 + threadIdx.x;
  if (t < WACT_) win_rank[iw[t]] = t;
  if (t < NBLK_) { int j = blk[t]; atomicOr(&bitmap[j >> 5], 1u << (j & 31)); }
}

__global__ __launch_bounds__(256) void mapC_k(const int* __restrict__ ip,
                                              const int* __restrict__ iw,
                                              const unsigned* __restrict__ bitmap,
                                              int* inv_ip, int* rowmap) {
  int i = blockIdx.x * 256 + threadIdx.x;
  if (i < NTOK_) {
    int j = ip[i];
    inv_ip[j] = i;
    int blocked = (bitmap[j >> 5] >> (j & 31)) & 1;
    rowmap[i] = blocked ? -1 : (iw[j >> 6] * 64 + (j & 63));
  }
}

// ---------------- LN1 + gather/permute (vectorized: 32 lanes/token) --------
__global__ __launch_bounds__(256) void ln1_k(const float* __restrict__ x,
                                             const float* __restrict__ w,
                                             const float* __restrict__ b,
                                             const int* __restrict__ win_rank,
                                             const int* __restrict__ inv_ip,
                                             const unsigned* __restrict__ bitmap,
                                             float* __restrict__ out,
                                             short* __restrict__ xp) {
  const int l = threadIdx.x & 31;
  const int tok = blockIdx.x * 8 + (threadIdx.x >> 5);
  const f32x4* xr = (const f32x4*)(x + (size_t)tok * DIM_);
  f32x4 v[3]; float s = 0.f;
#pragma unroll
  for (int j = 0; j < 3; ++j) {
    v[j] = xr[l + 32 * j];
    s += v[j][0] + v[j][1] + v[j][2] + v[j][3];
  }
#pragma unroll
  for (int m = 1; m <= 16; m <<= 1) s += __shfl_xor(s, m, 64);
  float mu = s * (1.0f / DIM_);
  float q = 0.f;
#pragma unroll
  for (int j = 0; j < 3; ++j)
#pragma unroll
    for (int e = 0; e < 4; ++e) { float d = v[j][e] - mu; q += d * d; }
#pragma unroll
  for (int m = 1; m <= 16; m <<= 1) q += __shfl_xor(q, m, 64);
  float rs = rsqrtf(q * (1.0f / DIM_) + 1e-5f);
  f32x4 y[3];
#pragma unroll
  for (int j = 0; j < 3; ++j) {
    f32x4 wv = *(const f32x4*)&w[4 * l + 128 * j];
    f32x4 bv = *(const f32x4*)&b[4 * l + 128 * j];
#pragma unroll
    for (int e = 0; e < 4; ++e) y[j][e] = (v[j][e] - mu) * rs * wv[e] + bv[e];
  }
  int wdw = tok >> 6, t = tok & 63;
  int rank = win_rank[wdw];
  if (rank < 0) {
    f32x4* po = (f32x4*)(out + (size_t)tok * DIM_);
#pragma unroll
    for (int j = 0; j < 3; ++j) po[l + 32 * j] = y[j];
  } else {
    int jdx = (rank << 6) + t;
    int i = inv_ip[jdx];
#pragma unroll
    for (int j = 0; j < 3; ++j) {
      s16x4 o;
#pragma unroll
      for (int e = 0; e < 4; ++e) o[e] = f2bf(y[j][e]);
      *(s16x4*)&xp[(size_t)i * DIM_ + 4 * l + 128 * j] = o;
    }
    if ((bitmap[jdx >> 5] >> (jdx & 31)) & 1) {
      f32x4* po = (f32x4*)(out + (size_t)tok * DIM_);
#pragma unroll
      for (int j = 0; j < 3; ++j) po[l + 32 * j] = y[j];
    }
  }
}

// ---------------- LN2 -> fp8 K-permuted ----------------
__global__ __launch_bounds__(256) void ln2_k(const short* __restrict__ h,
                                             const float* __restrict__ w,
                                             const float* __restrict__ b,
                                             unsigned char* __restrict__ out8) {
  const int l = threadIdx.x & 31;
  const int tok = blockIdx.x * 8 + (threadIdx.x >> 5);
  const s16x4* xr = (const s16x4*)(h + (size_t)tok * DIM_);
  float v[12]; float s = 0.f;
#pragma unroll
  for (int j = 0; j < 3; ++j) {
    s16x4 rv = xr[l + 32 * j];
#pragma unroll
    for (int e = 0; e < 4; ++e) { v[j * 4 + e] = bf2f(rv[e]); s += v[j * 4 + e]; }
  }
#pragma unroll
  for (int m = 1; m <= 16; m <<= 1) s += __shfl_xor(s, m, 64);
  float mu = s * (1.0f / DIM_);
  float q = 0.f;
#pragma unroll
  for (int e = 0; e < 12; ++e) { float d = v[e] - mu; q += d * d; }
#pragma unroll
  for (int m = 1; m <= 16; m <<= 1) q += __shfl_xor(q, m, 64);
  float rs = rsqrtf(q * (1.0f / DIM_) + 1e-5f);
#pragma unroll
  for (int j = 0; j < 3; ++j) {
    f32x4 wv = *(const f32x4*)&w[4 * l + 128 * j];
    f32x4 bv = *(const f32x4*)&b[4 * l + 128 * j];
    float y[4];
#pragma unroll
    for (int e = 0; e < 4; ++e)
      y[e] = (v[j * 4 + e] - mu) * rs * wv[e] + bv[e];
    int wrd = __builtin_amdgcn_cvt_pk_fp8_f32(y[0], y[1], 0, false);
    wrd = __builtin_amdgcn_cvt_pk_fp8_f32(y[2], y[3], wrd, true);
    int c0 = 4 * l + 128 * j;  // 4-aligned within an 8B chunk
    *(unsigned*)&out8[(size_t)tok * DIM_ + kperm(c0)] = (unsigned)wrd;
  }
}

// ---------------- QKV GEMM bf16 (256x128, 8 waves) -> fp8 plain ------------
__global__ __launch_bounds__(512) void gemmqkv_k(const short* __restrict__ A,
                                                 const short* __restrict__ B,
                                                 const float* __restrict__ bias,
                                                 unsigned char* __restrict__ C8) {
  const int K = 384, N = QKVD_, nx = 9;
  const int nwg = gridDim.x;
  const int q8 = nwg >> 3;
  const int wg = (blockIdx.x & 7) * q8 + (blockIdx.x >> 3);
  const int ntile = wg % nx, mtile = wg / nx;
  const int tid = threadIdx.x, wid = tid >> 6, lane = tid & 63;
  const int fq = lane >> 4, fr = lane & 15;
  const int wr = wid >> 1, wc = wid & 1;
  __shared__ __align__(16) short lA[256 * 64];
  __shared__ __align__(16) short lB[128 * 64];
  const int row0 = mtile * 256, col0 = ntile * 128;
  float bs[4];
#pragma unroll
  for (int nt = 0; nt < 4; ++nt) bs[nt] = bias[col0 + wc * 64 + nt * 16 + fr];
  f32x4 acc[4][4];
#pragma unroll
  for (int a = 0; a < 4; ++a)
#pragma unroll
    for (int c = 0; c < 4; ++c) acc[a][c] = (f32x4){0.f, 0.f, 0.f, 0.f};
  const int nkt = K >> 6;
  for (int kt = 0; kt < nkt; ++kt) {
    const int k0 = kt << 6;
#pragma unroll
    for (int i = 0; i < 4; ++i) {
      int g = i * 512 + tid;
      int r = g >> 3, c8 = g & 7;
      int s8 = c8 ^ (r & 7);
      gload16(A + (size_t)(row0 + r) * K + k0 + s8 * 8, (char*)lA + (size_t)g * 16);
    }
#pragma unroll
    for (int i = 0; i < 2; ++i) {
      int g = i * 512 + tid;
      int r = g >> 3, c8 = g & 7;
      int s8 = c8 ^ (r & 7);
      gload16(B + (size_t)(col0 + r) * K + k0 + s8 * 8, (char*)lB + (size_t)g * 16);
    }
    __syncthreads();
#pragma unroll
    for (int ks = 0; ks < 2; ++ks) {
      bf16x8 af[4], bfr[4];
#pragma unroll
      for (int mt = 0; mt < 4; ++mt) {
        int r = wr * 64 + mt * 16 + fr;
        af[mt] = *(const bf16x8*)&lA[r * 64 + ((ks * 4 + fq) ^ (r & 7)) * 8];
      }
#pragma unroll
      for (int nt = 0; nt < 4; ++nt) {
        int r = wc * 64 + nt * 16 + fr;
        bfr[nt] = *(const bf16x8*)&lB[r * 64 + ((ks * 4 + fq) ^ (r & 7)) * 8];
      }
#pragma unroll
      for (int mt = 0; mt < 4; ++mt)
#pragma unroll
        for (int nt = 0; nt < 4; ++nt)
          acc[mt][nt] = mfma16(af[mt], bfr[nt], acc[mt][nt]);
    }
    __syncthreads();
  }
#pragma unroll
  for (int mt = 0; mt < 4; ++mt) {
#pragma unroll
    for (int jj = 0; jj < 4; ++jj) {
      int r = row0 + wr * 64 + mt * 16 + fq * 4 + jj;
      float g4[4];
#pragma unroll
      for (int nt = 0; nt < 4; ++nt) g4[nt] = acc[mt][nt][jj] + bs[nt];
      int p01 = __builtin_amdgcn_cvt_pk_fp8_f32(g4[0], g4[1], 0, false);
      int p23 = __builtin_amdgcn_cvt_pk_fp8_f32(g4[2], g4[3], 0, false);
      const size_t rb = (size_t)r * N + col0 + wc * 64 + fr;
      C8[rb]      = (unsigned char)(p01 & 0xff);
      C8[rb + 16] = (unsigned char)((p01 >> 8) & 0xff);
      C8[rb + 32] = (unsigned char)(p23 & 0xff);
      C8[rb + 48] = (unsigned char)((p23 >> 8) & 0xff);
    }
  }
}

// ---------------- Generic fp8 GEMM: 256x128 tile, 8 waves (R8 geometry) ----
// BK=128 fp8, K-permuted operands, conflict-free ds_read_b128 (R17 pattern).
// EPI 1: +bias +add_bf -> bf16       (proj + residual -> h)
// EPI 2: +bias, gelu -> fp8 K-perm   (fc1 -> t8, ld MLPD_)
// EPI 3: +bias +add_bf, scatter fp32 (fc2 + residual -> out)
template <int EPI>
__global__ __launch_bounds__(512) void gemmf8_k(const unsigned char* __restrict__ A8,
                                                const unsigned char* __restrict__ B8,
                                                const float* __restrict__ bias,
                                                int K, int nx,
                                                short* __restrict__ Cb,
                                                unsigned char* __restrict__ C8,
                                                const short* __restrict__ add_bf,
                                                const int* __restrict__ rowmap,
                                                float* __restrict__ outf) {
  const int nwg = gridDim.x;
  const int q8 = nwg >> 3;
  const int wg = (blockIdx.x & 7) * q8 + (blockIdx.x >> 3);
  const int ntile = wg % nx, mtile = wg / nx;
  const int tid = threadIdx.x, wid = tid >> 6, lane = tid & 63;
  const int fq = lane >> 4, fr = lane & 15;
  const int wr = wid >> 1, wc = wid & 1;  // 4(M) x 2(N) waves, 64x64 each
  __shared__ __align__(16) unsigned char lA[256 * 128];
  __shared__ __align__(16) unsigned char lB[128 * 128];
  const int row0 = mtile * 256, col0 = ntile * 128;
  float bs[4];
#pragma unroll
  for (int nt = 0; nt < 4; ++nt) bs[nt] = bias[col0 + wc * 64 + nt * 16 + fr];
  f32x4 acc[4][4];
#pragma unroll
  for (int a = 0; a < 4; ++a)
#pragma unroll
    for (int c = 0; c < 4; ++c) acc[a][c] = (f32x4){0.f, 0.f, 0.f, 0.f};
  const int nkt = K >> 7;  // 3 or 12
  for (int kt = 0; kt < nkt; ++kt) {
    const int k0 = kt << 7;
    // A: 2048 16B-blocks (4/thread); B: 1024 (2/thread)
#pragma unroll
    for (int i = 0; i < 4; ++i) {
      int g = i * 512 + tid;
      int r = g >> 3, c8 = g & 7;
      int s8 = c8 ^ (r & 7);
      gload16(A8 + (size_t)(row0 + r) * K + k0 + s8 * 16, (char*)lA + (size_t)g * 16);
    }
#pragma unroll
    for (int i = 0; i < 2; ++i) {
      int g = i * 512 + tid;
      int r = g >> 3, c8 = g & 7;
      int s8 = c8 ^ (r & 7);
      gload16(B8 + (size_t)(col0 + r) * K + k0 + s8 * 16, (char*)lB + (size_t)g * 16);
    }
    __syncthreads();
#pragma unroll
    for (int ss = 0; ss < 2; ++ss) {
      longx2 af[4], bfr[4];
      const int pb = ss * 4 + fq;
#pragma unroll
      for (int mt = 0; mt < 4; ++mt) {
        int r = wr * 64 + mt * 16 + fr;
        int d = pb ^ (r & 7);
        af[mt] = *(const longx2*)&lA[r * 128 + d * 16];
      }
#pragma unroll
      for (int nt = 0; nt < 4; ++nt) {
        int r = wc * 64 + nt * 16 + fr;
        int d = pb ^ (r & 7);
        bfr[nt] = *(const longx2*)&lB[r * 128 + d * 16];
      }
#pragma unroll
      for (int mt = 0; mt < 4; ++mt)
#pragma unroll
        for (int nt = 0; nt < 4; ++nt) {
          acc[mt][nt] = mfma8(af[mt][0], bfr[nt][0], acc[mt][nt]);
          acc[mt][nt] = mfma8(af[mt][1], bfr[nt][1], acc[mt][nt]);
        }
    }
    __syncthreads();
  }
#pragma unroll
  for (int mt = 0; mt < 4; ++mt) {
#pragma unroll
    for (int jj = 0; jj < 4; ++jj) {
      int r = row0 + wr * 64 + mt * 16 + fq * 4 + jj;
      int dmap = 0;
      if (EPI == 3) dmap = rowmap[r];
      if (EPI == 1) {
#pragma unroll
        for (int nt = 0; nt < 4; ++nt) {
          int gcol = col0 + wc * 64 + nt * 16 + fr;
          float v = acc[mt][nt][jj] + bs[nt] + bf2f(add_bf[(size_t)r * DIM_ + gcol]);
          Cb[(size_t)r * DIM_ + gcol] = f2bf(v);
        }
      } else if (EPI == 2) {
        float g4[4];
#pragma unroll
        for (int nt = 0; nt < 4; ++nt) {
          float v = acc[mt][nt][jj] + bs[nt];
          float u = v * (0.79788456f + 0.03567741f * v * v);
          g4[nt] = v * __builtin_amdgcn_rcpf(1.0f + __expf(-2.0f * u));
        }
        int p01 = __builtin_amdgcn_cvt_pk_fp8_f32(g4[0], g4[1], 0, false);
        int p23 = __builtin_amdgcn_cvt_pk_fp8_f32(g4[2], g4[3], 0, false);
        const int C0 = col0 + wc * 64;
        const size_t rb = (size_t)r * MLPD_ + C0 + (fr & 7) + ((fr >> 3) << 4);
        C8[rb]      = (unsigned char)(p01 & 0xff);
        C8[rb + 32] = (unsigned char)((p01 >> 8) & 0xff);
        C8[rb + 8]  = (unsigned char)(p23 & 0xff);
        C8[rb + 40] = (unsigned char)((p23 >> 8) & 0xff);
      } else {
#pragma unroll
        for (int nt = 0; nt < 4; ++nt) {
          int gcol = col0 + wc * 64 + nt * 16 + fr;
          float v = acc[mt][nt][jj] + bs[nt] + bf2f(add_bf[(size_t)r * DIM_ + gcol]);
          if (dmap >= 0) outf[(size_t)dmap * DIM_ + gcol] = v;
        }
      }
    }
  }
}

// ---------------- attention: one head per wave, fp8; out fp8 K-perm --------
__global__ __launch_bounds__(256) void attn_k(const unsigned char* __restrict__ qkv8,
                                              const unsigned* __restrict__ bitmap,
                                              const int* __restrict__ ip,
                                              unsigned char* __restrict__ o8) {
  const int flat = (blockIdx.x & 7) * 576 + (blockIdx.x >> 3);
  const int m = flat / 3;
  const int h = (flat % 3) * 4 + (threadIdx.x >> 6);
  const int wid = threadIdx.x >> 6, lane = threadIdx.x & 63;
  const int fq = lane >> 4, fr = lane & 15;
  __shared__ __align__(16) unsigned char P[4][64 * 72];
  __shared__ __align__(16) unsigned char Vt[4][32 * 72];
  __shared__ unsigned char flags[64];
  if (threadIdx.x < 64) {
    int j = ip[m * 64 + threadIdx.x];
    flags[threadIdx.x] = (unsigned char)((bitmap[j >> 5] >> (j & 31)) & 1);
  }
  __syncthreads();
  const float scale = 0.17677669529663687f;
  int msk[4];
#pragma unroll
  for (int nt = 0; nt < 4; ++nt) msk[nt] = flags[nt * 16 + fr];

  const unsigned char* base = qkv8 + (size_t)m * 64 * QKVD_ + h * 96;
  f32x4 sacc[4][4];
#pragma unroll
  for (int a = 0; a < 4; ++a)
#pragma unroll
    for (int c = 0; c < 4; ++c) sacc[a][c] = (f32x4){0.f, 0.f, 0.f, 0.f};
  long qa[4], kb[4];
#pragma unroll
  for (int mt = 0; mt < 4; ++mt)
    qa[mt] = *(const long*)(base + (size_t)(mt * 16 + fr) * QKVD_ + fq * 8);
#pragma unroll
  for (int nt = 0; nt < 4; ++nt)
    kb[nt] = *(const long*)(base + (size_t)(nt * 16 + fr) * QKVD_ + 32 + fq * 8);
#pragma unroll
  for (int mt = 0; mt < 4; ++mt)
#pragma unroll
    for (int nt = 0; nt < 4; ++nt)
      sacc[mt][nt] = mfma8(qa[mt], kb[nt], sacc[mt][nt]);
#pragma unroll
  for (int c = 0; c < 2; ++c) {
    u8x16 vv = *(const u8x16*)(base + (size_t)lane * QKVD_ + 64 + c * 16);
#pragma unroll
    for (int e = 0; e < 16; ++e) Vt[wid][(c * 16 + e) * 72 + lane] = vv[e];
  }
#pragma unroll
  for (int mt = 0; mt < 4; ++mt)
#pragma unroll
    for (int nt = 0; nt < 4; ++nt) {
      f32x4 sv = sacc[mt][nt];
#pragma unroll
      for (int jj = 0; jj < 4; ++jj)
        sv[jj] = msk[nt] ? -10000.0f : sv[jj] * scale;
      sacc[mt][nt] = sv;
    }
#pragma unroll
  for (int mt = 0; mt < 4; ++mt) {
#pragma unroll
    for (int jj = 0; jj < 4; ++jj) {
      float mx = sacc[mt][0][jj];
#pragma unroll
      for (int nt = 1; nt < 4; ++nt) mx = fmaxf(mx, sacc[mt][nt][jj]);
#pragma unroll
      for (int mm = 1; mm < 16; mm <<= 1) mx = fmaxf(mx, __shfl_xor(mx, mm, 64));
      float sm = 0.f;
      float p[4];
#pragma unroll
      for (int nt = 0; nt < 4; ++nt) {
        p[nt] = __expf(sacc[mt][nt][jj] - mx);
        sm += p[nt];
      }
#pragma unroll
      for (int mm = 1; mm < 16; mm <<= 1) sm += __shfl_xor(sm, mm, 64);
      float inv = 1.0f / sm;
      int rowb = (mt * 16 + fq * 4 + jj) * 72;
      int p01 = __builtin_amdgcn_cvt_pk_fp8_f32(p[0] * inv, p[1] * inv, 0, false);
      int p23 = __builtin_amdgcn_cvt_pk_fp8_f32(p[2] * inv, p[3] * inv, 0, false);
      P[wid][rowb + fr]      = (unsigned char)(p01 & 0xff);
      P[wid][rowb + 16 + fr] = (unsigned char)((p01 >> 8) & 0xff);
      P[wid][rowb + 32 + fr] = (unsigned char)(p23 & 0xff);
      P[wid][rowb + 48 + fr] = (unsigned char)((p23 >> 8) & 0xff);
    }
  }
  f32x4 oacc[4][2];
#pragma unroll
  for (int a = 0; a < 4; ++a)
#pragma unroll
    for (int c = 0; c < 2; ++c) oacc[a][c] = (f32x4){0.f, 0.f, 0.f, 0.f};
#pragma unroll
  for (int ks = 0; ks < 2; ++ks) {
    long pa[4], vb[2];
#pragma unroll
    for (int mt = 0; mt < 4; ++mt)
      pa[mt] = *(const long*)&P[wid][(mt * 16 + fr) * 72 + ks * 32 + fq * 8];
#pragma unroll
    for (int nd = 0; nd < 2; ++nd)
      vb[nd] = *(const long*)&Vt[wid][(nd * 16 + fr) * 72 + ks * 32 + fq * 8];
#pragma unroll
    for (int mt = 0; mt < 4; ++mt)
#pragma unroll
      for (int nd = 0; nd < 2; ++nd)
        oacc[mt][nd] = mfma8(pa[mt], vb[nd], oacc[mt][nd]);
  }
  // ---- store O as fp8 K-permuted (row length DIM_) ----
  const int pos0 = kperm(h * 32 + fr);
  const int pos1 = kperm(h * 32 + 16 + fr);
#pragma unroll
  for (int mt = 0; mt < 4; ++mt)
#pragma unroll
    for (int jj = 0; jj < 4; ++jj) {
      int p01 = __builtin_amdgcn_cvt_pk_fp8_f32(oacc[mt][0][jj], oacc[mt][1][jj],
                                                0, false);
      size_t rb = (size_t)(m * 64 + mt * 16 + fq * 4 + jj) * DIM_;
      o8[rb + pos0] = (unsigned char)(p01 & 0xff);
      o8[rb + pos1] = (unsigned char)((p01 >> 8) & 0xff);
    }
}

// ---------------- launch ----------------
extern "C" void kernel_launch(void* const* d_in, const int* in_sizes, int n_in,
                              void* d_out, int out_size, void* d_ws, size_t ws_size,
                              hipStream_t stream) {
  const float* x = (const float*)d_in[0];
  const int* iw = (const int*)d_in[1];
  const int* ip = (const int*)d_in[2];
  const int* blk = (const int*)d_in[3];
  const float* ln1w = (const float*)d_in[6];
  const float* ln1b = (const float*)d_in[7];
  const float* qkvw = (const float*)d_in[8];
  const float* qkvb = (const float*)d_in[9];
  const float* projw = (const float*)d_in[10];
  const float* projb = (const float*)d_in[11];
  const float* ln2w = (const float*)d_in[12];
  const float* ln2b = (const float*)d_in[13];
  const float* fc1w = (const float*)d_in[14];
  const float* fc1b = (const float*)d_in[15];
  const float* fc2w = (const float*)d_in[16];
  const float* fc2b = (const float*)d_in[17];
  float* out = (float*)d_out;

  char* ws = (char*)d_ws;
  short* w_qkv = (short*)ws;                                 // 884,736 B bf16
  unsigned char* projw8 = (unsigned char*)(ws + 884736);     // 147,456
  unsigned char* fc1w8 = (unsigned char*)(ws + 1032192);     // 589,824
  unsigned char* fc2w8 = (unsigned char*)(ws + 1622016);     // 589,824
  int* inv_ip = (int*)(ws + 2211840);
  int* rowmap = inv_ip + NTOK_;
  int* win_rank = rowmap + NTOK_;
  unsigned* bitmap = (unsigned*)(win_rank + NW_);
  short* xp = (short*)(ws + 4349952);                        // 75.5 MB bf16
  unsigned char* qkv8 = (unsigned char*)(ws + 79847424);     // 113 MB fp8
  unsigned char* t8 = qkv8;                                  // 151 MB fp8 (after attn)
  unsigned char* obuf8 = (unsigned char*)(ws + 306339840);   // 37.7 MB fp8
  unsigned char* ln2buf8 = (unsigned char*)(ws + 344088576); // 37.7 MB fp8
  short* hbuf = (short*)(ws + 457334784);                    // 75.5 MB bf16
  (void)in_sizes; (void)n_in; (void)out_size; (void)ws_size;

  pre_k<<<1092, 256, 0, stream>>>(qkvw, projw, fc1w, fc2w, w_qkv, projw8, fc1w8,
                                  fc2w8, win_rank, bitmap);
  mapB_k<<<39, 256, 0, stream>>>(iw, blk, win_rank, bitmap);
  mapC_k<<<NTOK_ / 256, 256, 0, stream>>>(ip, iw, bitmap, inv_ip, rowmap);
  ln1_k<<<(NW_ * 64) / 8, 256, 0, stream>>>(x, ln1w, ln1b, win_rank, inv_ip, bitmap,
                                            out, xp);
  // 256-row mtiles = 384
  gemmqkv_k<<<384 * 9, 512, 0, stream>>>(xp, w_qkv, qkvb, qkv8);
  attn_k<<<WACT_ * 3, 256, 0, stream>>>(qkv8, bitmap, ip, obuf8);
  gemmf8_k<1><<<384 * 3, 512, 0, stream>>>(obuf8, projw8, projb, 384, 3, hbuf,
                                           nullptr, xp, nullptr, nullptr);
  ln2_k<<<NTOK_ / 8, 256, 0, stream>>>(hbuf, ln2w, ln2b, ln2buf8);
  gemmf8_k<2><<<384 * 12, 512, 0, stream>>>(ln2buf8, fc1w8, fc1b, 384, 12, nullptr,
                                            t8, nullptr, nullptr, nullptr);
  gemmf8_k<3><<<384 * 3, 512, 0, stream>>>(t8, fc2w8, fc2b, MLPD_, 3, nullptr,
                                           nullptr, hbuf, rowmap, out);
}

// Round 21
// 609.730 us; speedup vs baseline: 1.4140x; 1.0219x over previous
//
#include <hip/hip_runtime.h>
#include <hip/hip_bf16.h>

typedef __attribute__((ext_vector_type(8))) short bf16x8;
typedef __attribute__((ext_vector_type(4))) short s16x4;
typedef __attribute__((ext_vector_type(4))) float f32x4;
typedef __attribute__((ext_vector_type(2))) long longx2;
typedef __attribute__((ext_vector_type(16))) unsigned char u8x16;

#define NW_   3072
#define WACT_ 1536
#define NTOK_ 98304
#define NBLK_ 9830
#define DIM_  384
#define QKVD_ 1152
#define MLPD_ 1536

__device__ __forceinline__ float bf2f(short s) {
  union { unsigned u; float f; } c;
  c.u = ((unsigned)(unsigned short)s) << 16;
  return c.f;
}
__device__ __forceinline__ short f2bf(float f) {
  union { float f; unsigned u; } c; c.f = f;
  unsigned lsb = (c.u >> 16) & 1u;
  c.u += 0x7fffu + lsb;
  return (short)(c.u >> 16);
}

__device__ __forceinline__ f32x4 mfma8(long a, long b, f32x4 c) {
  return __builtin_amdgcn_mfma_f32_16x16x32_fp8_fp8(a, b, c, 0, 0, 0);
}

__device__ __forceinline__ void gload16(const void* g, void* l) {
  __builtin_amdgcn_global_load_lds(
      (const __attribute__((address_space(1))) unsigned*)g,
      (__attribute__((address_space(3))) unsigned*)l, 16, 0, 0);
}

// K-perm byte position within a row: col -> group*64 + slot*8 + (col&7),
// slot = ((l&3)<<1)|(l>>2), l = (col>>3)&7.  (Proven R17 convention.)
__device__ __forceinline__ int kperm(int col) {
  int l = (col >> 3) & 7;
  int s = ((l & 3) << 1) | (l >> 2);
  return (col & ~63) + s * 8 + (col & 7);
}

// ---------------- merged prologue: mapA + weight conversions ----------------
__device__ __forceinline__ void conv8_chunk(const float* __restrict__ src,
                                            unsigned char* __restrict__ dst,
                                            int K, int blk, int tid) {
  int i = (blk * 256 + tid) * 8;
  f32x4 v0 = *(const f32x4*)&src[i];
  f32x4 v1 = *(const f32x4*)&src[i + 4];
  int w0 = __builtin_amdgcn_cvt_pk_fp8_f32(v0[0], v0[1], 0, false);
  w0 = __builtin_amdgcn_cvt_pk_fp8_f32(v0[2], v0[3], w0, true);
  int w1 = __builtin_amdgcn_cvt_pk_fp8_f32(v1[0], v1[1], 0, false);
  w1 = __builtin_amdgcn_cvt_pk_fp8_f32(v1[2], v1[3], w1, true);
  int kro = i % K, row = i / K;
  union { int u[2]; long ll; } p; p.u[0] = w0; p.u[1] = w1;
  *(long*)&dst[(size_t)row * K + kperm(kro)] = p.ll;
}

__global__ __launch_bounds__(256) void pre_k(const float* __restrict__ qkvw,
                                             const float* __restrict__ projw,
                                             const float* __restrict__ fc1w,
                                             const float* __restrict__ fc2w,
                                             unsigned char* __restrict__ qw8,
                                             unsigned char* __restrict__ pw8,
                                             unsigned char* __restrict__ f1w8,
                                             unsigned char* __restrict__ f2w8,
                                             int* win_rank, unsigned* bitmap) {
  const int bid = blockIdx.x, tid = threadIdx.x;
  if (bid < 12) {
    int t = bid * 256 + tid;
    if (t < NW_) { win_rank[t] = -1; bitmap[t] = 0u; }
  } else if (bid < 228) {
    conv8_chunk(qkvw, qw8, 384, bid - 12, tid);
  } else if (bid < 300) {
    conv8_chunk(projw, pw8, 384, bid - 228, tid);
  } else if (bid < 588) {
    conv8_chunk(fc1w, f1w8, 384, bid - 300, tid);
  } else {
    conv8_chunk(fc2w, f2w8, MLPD_, bid - 588, tid);
  }
}

// ---------------- map kernels ----------------
__global__ __launch_bounds__(256) void mapB_k(const int* __restrict__ iw,
                                              const int* __restrict__ blk,
                                              int* win_rank, unsigned* bitmap) {
  int t = blockIdx.x * 256 + threadIdx.x;
  if (t < WACT_) win_rank[iw[t]] = t;
  if (t < NBLK_) { int j = blk[t]; atomicOr(&bitmap[j >> 5], 1u << (j & 31)); }
}

__global__ __launch_bounds__(256) void mapC_k(const int* __restrict__ ip,
                                              const int* __restrict__ iw,
                                              const unsigned* __restrict__ bitmap,
                                              int* inv_ip, int* rowmap) {
  int i = blockIdx.x * 256 + threadIdx.x;
  if (i < NTOK_) {
    int j = ip[i];
    inv_ip[j] = i;
    int blocked = (bitmap[j >> 5] >> (j & 31)) & 1;
    rowmap[i] = blocked ? -1 : (iw[j >> 6] * 64 + (j & 63));
  }
}

// ---------------- LN1 + gather/permute -> xp bf16 + xp8 fp8 K-perm ---------
__global__ __launch_bounds__(256) void ln1_k(const float* __restrict__ x,
                                             const float* __restrict__ w,
                                             const float* __restrict__ b,
                                             const int* __restrict__ win_rank,
                                             const int* __restrict__ inv_ip,
                                             const unsigned* __restrict__ bitmap,
                                             float* __restrict__ out,
                                             short* __restrict__ xp,
                                             unsigned char* __restrict__ xp8) {
  const int l = threadIdx.x & 31;
  const int tok = blockIdx.x * 8 + (threadIdx.x >> 5);
  const f32x4* xr = (const f32x4*)(x + (size_t)tok * DIM_);
  f32x4 v[3]; float s = 0.f;
#pragma unroll
  for (int j = 0; j < 3; ++j) {
    v[j] = xr[l + 32 * j];
    s += v[j][0] + v[j][1] + v[j][2] + v[j][3];
  }
#pragma unroll
  for (int m = 1; m <= 16; m <<= 1) s += __shfl_xor(s, m, 64);
  float mu = s * (1.0f / DIM_);
  float q = 0.f;
#pragma unroll
  for (int j = 0; j < 3; ++j)
#pragma unroll
    for (int e = 0; e < 4; ++e) { float d = v[j][e] - mu; q += d * d; }
#pragma unroll
  for (int m = 1; m <= 16; m <<= 1) q += __shfl_xor(q, m, 64);
  float rs = rsqrtf(q * (1.0f / DIM_) + 1e-5f);
  f32x4 y[3];
#pragma unroll
  for (int j = 0; j < 3; ++j) {
    f32x4 wv = *(const f32x4*)&w[4 * l + 128 * j];
    f32x4 bv = *(const f32x4*)&b[4 * l + 128 * j];
#pragma unroll
    for (int e = 0; e < 4; ++e) y[j][e] = (v[j][e] - mu) * rs * wv[e] + bv[e];
  }
  int wdw = tok >> 6, t = tok & 63;
  int rank = win_rank[wdw];
  if (rank < 0) {
    f32x4* po = (f32x4*)(out + (size_t)tok * DIM_);
#pragma unroll
    for (int j = 0; j < 3; ++j) po[l + 32 * j] = y[j];
  } else {
    int jdx = (rank << 6) + t;
    int i = inv_ip[jdx];
#pragma unroll
    for (int j = 0; j < 3; ++j) {
      s16x4 o;
#pragma unroll
      for (int e = 0; e < 4; ++e) o[e] = f2bf(y[j][e]);
      *(s16x4*)&xp[(size_t)i * DIM_ + 4 * l + 128 * j] = o;
      int wrd = __builtin_amdgcn_cvt_pk_fp8_f32(y[j][0], y[j][1], 0, false);
      wrd = __builtin_amdgcn_cvt_pk_fp8_f32(y[j][2], y[j][3], wrd, true);
      *(unsigned*)&xp8[(size_t)i * DIM_ + kperm(4 * l + 128 * j)] = (unsigned)wrd;
    }
    if ((bitmap[jdx >> 5] >> (jdx & 31)) & 1) {
      f32x4* po = (f32x4*)(out + (size_t)tok * DIM_);
#pragma unroll
      for (int j = 0; j < 3; ++j) po[l + 32 * j] = y[j];
    }
  }
}

// ---------------- LN2 -> fp8 K-permuted ----------------
__global__ __launch_bounds__(256) void ln2_k(const short* __restrict__ h,
                                             const float* __restrict__ w,
                                             const float* __restrict__ b,
                                             unsigned char* __restrict__ out8) {
  const int l = threadIdx.x & 31;
  const int tok = blockIdx.x * 8 + (threadIdx.x >> 5);
  const s16x4* xr = (const s16x4*)(h + (size_t)tok * DIM_);
  float v[12]; float s = 0.f;
#pragma unroll
  for (int j = 0; j < 3; ++j) {
    s16x4 rv = xr[l + 32 * j];
#pragma unroll
    for (int e = 0; e < 4; ++e) { v[j * 4 + e] = bf2f(rv[e]); s += v[j * 4 + e]; }
  }
#pragma unroll
  for (int m = 1; m <= 16; m <<= 1) s += __shfl_xor(s, m, 64);
  float mu = s * (1.0f / DIM_);
  float q = 0.f;
#pragma unroll
  for (int e = 0; e < 12; ++e) { float d = v[e] - mu; q += d * d; }
#pragma unroll
  for (int m = 1; m <= 16; m <<= 1) q += __shfl_xor(q, m, 64);
  float rs = rsqrtf(q * (1.0f / DIM_) + 1e-5f);
#pragma unroll
  for (int j = 0; j < 3; ++j) {
    f32x4 wv = *(const f32x4*)&w[4 * l + 128 * j];
    f32x4 bv = *(const f32x4*)&b[4 * l + 128 * j];
    float y[4];
#pragma unroll
    for (int e = 0; e < 4; ++e)
      y[e] = (v[j * 4 + e] - mu) * rs * wv[e] + bv[e];
    int wrd = __builtin_amdgcn_cvt_pk_fp8_f32(y[0], y[1], 0, false);
    wrd = __builtin_amdgcn_cvt_pk_fp8_f32(y[2], y[3], wrd, true);
    int c0 = 4 * l + 128 * j;  // 4-aligned within an 8B chunk
    *(unsigned*)&out8[(size_t)tok * DIM_ + kperm(c0)] = (unsigned)wrd;
  }
}

// ---------------- Generic fp8 GEMM: 256x128 tile, 8 waves (R8 geometry) ----
// BK=128 fp8, K-permuted operands, conflict-free ds_read_b128 (R17 pattern).
// EPI 0: +bias -> fp8 plain (ld QKVD_) (qkv)
// EPI 1: +bias +add_bf -> bf16         (proj + residual -> h)
// EPI 2: +bias, gelu -> fp8 K-perm     (fc1 -> t8, ld MLPD_)
// EPI 3: +bias +add_bf, scatter fp32   (fc2 + residual -> out)
template <int EPI>
__global__ __launch_bounds__(512) void gemmf8_k(const unsigned char* __restrict__ A8,
                                                const unsigned char* __restrict__ B8,
                                                const float* __restrict__ bias,
                                                int K, int nx,
                                                short* __restrict__ Cb,
                                                unsigned char* __restrict__ C8,
                                                const short* __restrict__ add_bf,
                                                const int* __restrict__ rowmap,
                                                float* __restrict__ outf) {
  const int nwg = gridDim.x;
  const int q8 = nwg >> 3;
  const int wg = (blockIdx.x & 7) * q8 + (blockIdx.x >> 3);
  const int ntile = wg % nx, mtile = wg / nx;
  const int tid = threadIdx.x, wid = tid >> 6, lane = tid & 63;
  const int fq = lane >> 4, fr = lane & 15;
  const int wr = wid >> 1, wc = wid & 1;  // 4(M) x 2(N) waves, 64x64 each
  __shared__ __align__(16) unsigned char lA[256 * 128];
  __shared__ __align__(16) unsigned char lB[128 * 128];
  const int row0 = mtile * 256, col0 = ntile * 128;
  float bs[4];
#pragma unroll
  for (int nt = 0; nt < 4; ++nt) bs[nt] = bias[col0 + wc * 64 + nt * 16 + fr];
  f32x4 acc[4][4];
#pragma unroll
  for (int a = 0; a < 4; ++a)
#pragma unroll
    for (int c = 0; c < 4; ++c) acc[a][c] = (f32x4){0.f, 0.f, 0.f, 0.f};
  const int nkt = K >> 7;  // 3 or 12
  for (int kt = 0; kt < nkt; ++kt) {
    const int k0 = kt << 7;
    // A: 2048 16B-blocks (4/thread); B: 1024 (2/thread)
#pragma unroll
    for (int i = 0; i < 4; ++i) {
      int g = i * 512 + tid;
      int r = g >> 3, c8 = g & 7;
      int s8 = c8 ^ (r & 7);
      gload16(A8 + (size_t)(row0 + r) * K + k0 + s8 * 16, (char*)lA + (size_t)g * 16);
    }
#pragma unroll
    for (int i = 0; i < 2; ++i) {
      int g = i * 512 + tid;
      int r = g >> 3, c8 = g & 7;
      int s8 = c8 ^ (r & 7);
      gload16(B8 + (size_t)(col0 + r) * K + k0 + s8 * 16, (char*)lB + (size_t)g * 16);
    }
    __syncthreads();
#pragma unroll
    for (int ss = 0; ss < 2; ++ss) {
      longx2 af[4], bfr[4];
      const int pb = ss * 4 + fq;
#pragma unroll
      for (int mt = 0; mt < 4; ++mt) {
        int r = wr * 64 + mt * 16 + fr;
        int d = pb ^ (r & 7);
        af[mt] = *(const longx2*)&lA[r * 128 + d * 16];
      }
#pragma unroll
      for (int nt = 0; nt < 4; ++nt) {
        int r = wc * 64 + nt * 16 + fr;
        int d = pb ^ (r & 7);
        bfr[nt] = *(const longx2*)&lB[r * 128 + d * 16];
      }
#pragma unroll
      for (int mt = 0; mt < 4; ++mt)
#pragma unroll
        for (int nt = 0; nt < 4; ++nt) {
          acc[mt][nt] = mfma8(af[mt][0], bfr[nt][0], acc[mt][nt]);
          acc[mt][nt] = mfma8(af[mt][1], bfr[nt][1], acc[mt][nt]);
        }
    }
    __syncthreads();
  }
#pragma unroll
  for (int mt = 0; mt < 4; ++mt) {
#pragma unroll
    for (int jj = 0; jj < 4; ++jj) {
      int r = row0 + wr * 64 + mt * 16 + fq * 4 + jj;
      int dmap = 0;
      if (EPI == 3) dmap = rowmap[r];
      if (EPI == 0) {
        float g4[4];
#pragma unroll
        for (int nt = 0; nt < 4; ++nt) g4[nt] = acc[mt][nt][jj] + bs[nt];
        int p01 = __builtin_amdgcn_cvt_pk_fp8_f32(g4[0], g4[1], 0, false);
        int p23 = __builtin_amdgcn_cvt_pk_fp8_f32(g4[2], g4[3], 0, false);
        const size_t rb = (size_t)r * QKVD_ + col0 + wc * 64 + fr;
        C8[rb]      = (unsigned char)(p01 & 0xff);
        C8[rb + 16] = (unsigned char)((p01 >> 8) & 0xff);
        C8[rb + 32] = (unsigned char)(p23 & 0xff);
        C8[rb + 48] = (unsigned char)((p23 >> 8) & 0xff);
      } else if (EPI == 1) {
#pragma unroll
        for (int nt = 0; nt < 4; ++nt) {
          int gcol = col0 + wc * 64 + nt * 16 + fr;
          float v = acc[mt][nt][jj] + bs[nt] + bf2f(add_bf[(size_t)r * DIM_ + gcol]);
          Cb[(size_t)r * DIM_ + gcol] = f2bf(v);
        }
      } else if (EPI == 2) {
        float g4[4];
#pragma unroll
        for (int nt = 0; nt < 4; ++nt) {
          float v = acc[mt][nt][jj] + bs[nt];
          float u = v * (0.79788456f + 0.03567741f * v * v);
          g4[nt] = v * __builtin_amdgcn_rcpf(1.0f + __expf(-2.0f * u));
        }
        int p01 = __builtin_amdgcn_cvt_pk_fp8_f32(g4[0], g4[1], 0, false);
        int p23 = __builtin_amdgcn_cvt_pk_fp8_f32(g4[2], g4[3], 0, false);
        const int C0 = col0 + wc * 64;
        const size_t rb = (size_t)r * MLPD_ + C0 + (fr & 7) + ((fr >> 3) << 4);
        C8[rb]      = (unsigned char)(p01 & 0xff);
        C8[rb + 32] = (unsigned char)((p01 >> 8) & 0xff);
        C8[rb + 8]  = (unsigned char)(p23 & 0xff);
        C8[rb + 40] = (unsigned char)((p23 >> 8) & 0xff);
      } else {
#pragma unroll
        for (int nt = 0; nt < 4; ++nt) {
          int gcol = col0 + wc * 64 + nt * 16 + fr;
          float v = acc[mt][nt][jj] + bs[nt] + bf2f(add_bf[(size_t)r * DIM_ + gcol]);
          if (dmap >= 0) outf[(size_t)dmap * DIM_ + gcol] = v;
        }
      }
    }
  }
}

// ---------------- attention: one head per wave, fp8; out fp8 K-perm --------
__global__ __launch_bounds__(256) void attn_k(const unsigned char* __restrict__ qkv8,
                                              const unsigned* __restrict__ bitmap,
                                              const int* __restrict__ ip,
                                              unsigned char* __restrict__ o8) {
  const int flat = (blockIdx.x & 7) * 576 + (blockIdx.x >> 3);
  const int m = flat / 3;
  const int h = (flat % 3) * 4 + (threadIdx.x >> 6);
  const int wid = threadIdx.x >> 6, lane = threadIdx.x & 63;
  const int fq = lane >> 4, fr = lane & 15;
  __shared__ __align__(16) unsigned char P[4][64 * 72];
  __shared__ __align__(16) unsigned char Vt[4][32 * 72];
  __shared__ unsigned char flags[64];
  if (threadIdx.x < 64) {
    int j = ip[m * 64 + threadIdx.x];
    flags[threadIdx.x] = (unsigned char)((bitmap[j >> 5] >> (j & 31)) & 1);
  }
  __syncthreads();
  const float scale = 0.17677669529663687f;
  int msk[4];
#pragma unroll
  for (int nt = 0; nt < 4; ++nt) msk[nt] = flags[nt * 16 + fr];

  const unsigned char* base = qkv8 + (size_t)m * 64 * QKVD_ + h * 96;
  f32x4 sacc[4][4];
#pragma unroll
  for (int a = 0; a < 4; ++a)
#pragma unroll
    for (int c = 0; c < 4; ++c) sacc[a][c] = (f32x4){0.f, 0.f, 0.f, 0.f};
  long qa[4], kb[4];
#pragma unroll
  for (int mt = 0; mt < 4; ++mt)
    qa[mt] = *(const long*)(base + (size_t)(mt * 16 + fr) * QKVD_ + fq * 8);
#pragma unroll
  for (int nt = 0; nt < 4; ++nt)
    kb[nt] = *(const long*)(base + (size_t)(nt * 16 + fr) * QKVD_ + 32 + fq * 8);
#pragma unroll
  for (int mt = 0; mt < 4; ++mt)
#pragma unroll
    for (int nt = 0; nt < 4; ++nt)
      sacc[mt][nt] = mfma8(qa[mt], kb[nt], sacc[mt][nt]);
#pragma unroll
  for (int c = 0; c < 2; ++c) {
    u8x16 vv = *(const u8x16*)(base + (size_t)lane * QKVD_ + 64 + c * 16);
#pragma unroll
    for (int e = 0; e < 16; ++e) Vt[wid][(c * 16 + e) * 72 + lane] = vv[e];
  }
#pragma unroll
  for (int mt = 0; mt < 4; ++mt)
#pragma unroll
    for (int nt = 0; nt < 4; ++nt) {
      f32x4 sv = sacc[mt][nt];
#pragma unroll
      for (int jj = 0; jj < 4; ++jj)
        sv[jj] = msk[nt] ? -10000.0f : sv[jj] * scale;
      sacc[mt][nt] = sv;
    }
#pragma unroll
  for (int mt = 0; mt < 4; ++mt) {
#pragma unroll
    for (int jj = 0; jj < 4; ++jj) {
      float mx = sacc[mt][0][jj];
#pragma unroll
      for (int nt = 1; nt < 4; ++nt) mx = fmaxf(mx, sacc[mt][nt][jj]);
#pragma unroll
      for (int mm = 1; mm < 16; mm <<= 1) mx = fmaxf(mx, __shfl_xor(mx, mm, 64));
      float sm = 0.f;
      float p[4];
#pragma unroll
      for (int nt = 0; nt < 4; ++nt) {
        p[nt] = __expf(sacc[mt][nt][jj] - mx);
        sm += p[nt];
      }
#pragma unroll
      for (int mm = 1; mm < 16; mm <<= 1) sm += __shfl_xor(sm, mm, 64);
      float inv = 1.0f / sm;
      int rowb = (mt * 16 + fq * 4 + jj) * 72;
      int p01 = __builtin_amdgcn_cvt_pk_fp8_f32(p[0] * inv, p[1] * inv, 0, false);
      int p23 = __builtin_amdgcn_cvt_pk_fp8_f32(p[2] * inv, p[3] * inv, 0, false);
      P[wid][rowb + fr]      = (unsigned char)(p01 & 0xff);
      P[wid][rowb + 16 + fr] = (unsigned char)((p01 >> 8) & 0xff);
      P[wid][rowb + 32 + fr] = (unsigned char)(p23 & 0xff);
      P[wid][rowb + 48 + fr] = (unsigned char)((p23 >> 8) & 0xff);
    }
  }
  f32x4 oacc[4][2];
#pragma unroll
  for (int a = 0; a < 4; ++a)
#pragma unroll
    for (int c = 0; c < 2; ++c) oacc[a][c] = (f32x4){0.f, 0.f, 0.f, 0.f};
#pragma unroll
  for (int ks = 0; ks < 2; ++ks) {
    long pa[4], vb[2];
#pragma unroll
    for (int mt = 0; mt < 4; ++mt)
      pa[mt] = *(const long*)&P[wid][(mt * 16 + fr) * 72 + ks * 32 + fq * 8];
#pragma unroll
    for (int nd = 0; nd < 2; ++nd)
      vb[nd] = *(const long*)&Vt[wid][(nd * 16 + fr) * 72 + ks * 32 + fq * 8];
#pragma unroll
    for (int mt = 0; mt < 4; ++mt)
#pragma unroll
      for (int nd = 0; nd < 2; ++nd)
        oacc[mt][nd] = mfma8(pa[mt], vb[nd], oacc[mt][nd]);
  }
  // ---- store O as fp8 K-permuted (row length DIM_) ----
  const int pos0 = kperm(h * 32 + fr);
  const int pos1 = kperm(h * 32 + 16 + fr);
#pragma unroll
  for (int mt = 0; mt < 4; ++mt)
#pragma unroll
    for (int jj = 0; jj < 4; ++jj) {
      int p01 = __builtin_amdgcn_cvt_pk_fp8_f32(oacc[mt][0][jj], oacc[mt][1][jj],
                                                0, false);
      size_t rb = (size_t)(m * 64 + mt * 16 + fq * 4 + jj) * DIM_;
      o8[rb + pos0] = (unsigned char)(p01 & 0xff);
      o8[rb + pos1] = (unsigned char)((p01 >> 8) & 0xff);
    }
}

// ---------------- launch ----------------
extern "C" void kernel_launch(void* const* d_in, const int* in_sizes, int n_in,
                              void* d_out, int out_size, void* d_ws, size_t ws_size,
                              hipStream_t stream) {
  const float* x = (const float*)d_in[0];
  const int* iw = (const int*)d_in[1];
  const int* ip = (const int*)d_in[2];
  const int* blk = (const int*)d_in[3];
  const float* ln1w = (const float*)d_in[6];
  const float* ln1b = (const float*)d_in[7];
  const float* qkvw = (const float*)d_in[8];
  const float* qkvb = (const float*)d_in[9];
  const float* projw = (const float*)d_in[10];
  const float* projb = (const float*)d_in[11];
  const float* ln2w = (const float*)d_in[12];
  const float* ln2b = (const float*)d_in[13];
  const float* fc1w = (const float*)d_in[14];
  const float* fc1b = (const float*)d_in[15];
  const float* fc2w = (const float*)d_in[16];
  const float* fc2b = (const float*)d_in[17];
  float* out = (float*)d_out;

  char* ws = (char*)d_ws;
  unsigned char* qkvw8 = (unsigned char*)ws;                 // 442,368
  unsigned char* projw8 = (unsigned char*)(ws + 442368);     // 147,456
  unsigned char* fc1w8 = (unsigned char*)(ws + 589824);      // 589,824
  unsigned char* fc2w8 = (unsigned char*)(ws + 1179648);     // 589,824 -> 1,769,472
  int* inv_ip = (int*)(ws + 2211840);
  int* rowmap = inv_ip + NTOK_;
  int* win_rank = rowmap + NTOK_;
  unsigned* bitmap = (unsigned*)(win_rank + NW_);
  short* xp = (short*)(ws + 4349952);                        // 75.5 MB bf16
  unsigned char* qkv8 = (unsigned char*)(ws + 79847424);     // 113 MB fp8
  unsigned char* t8 = qkv8;                                  // 151 MB fp8 (after attn)
  unsigned char* obuf8 = (unsigned char*)(ws + 306339840);   // 37.7 MB fp8
  unsigned char* ln2buf8 = (unsigned char*)(ws + 344088576); // 37.7 MB fp8
  unsigned char* xp8 = (unsigned char*)(ws + 381837312);     // 37.7 MB fp8
  short* hbuf = (short*)(ws + 457334784);                    // 75.5 MB bf16
  (void)in_sizes; (void)n_in; (void)out_size; (void)ws_size;

  pre_k<<<876, 256, 0, stream>>>(qkvw, projw, fc1w, fc2w, qkvw8, projw8, fc1w8,
                                 fc2w8, win_rank, bitmap);
  mapB_k<<<39, 256, 0, stream>>>(iw, blk, win_rank, bitmap);
  mapC_k<<<NTOK_ / 256, 256, 0, stream>>>(ip, iw, bitmap, inv_ip, rowmap);
  ln1_k<<<(NW_ * 64) / 8, 256, 0, stream>>>(x, ln1w, ln1b, win_rank, inv_ip, bitmap,
                                            out, xp, xp8);
  // 256-row mtiles = 384
  gemmf8_k<0><<<384 * 9, 512, 0, stream>>>(xp8, qkvw8, qkvb, 384, 9, nullptr,
                                           qkv8, nullptr, nullptr, nullptr);
  attn_k<<<WACT_ * 3, 256, 0, stream>>>(qkv8, bitmap, ip, obuf8);
  gemmf8_k<1><<<384 * 3, 512, 0, stream>>>(obuf8, projw8, projb, 384, 3, hbuf,
                                           nullptr, xp, nullptr, nullptr);
  ln2_k<<<NTOK_ / 8, 256, 0, stream>>>(hbuf, ln2w, ln2b, ln2buf8);
  gemmf8_k<2><<<384 * 12, 512, 0, stream>>>(ln2buf8, fc1w8, fc1b, 384, 12, nullptr,
                                            t8, nullptr, nullptr, nullptr);
  gemmf8_k<3><<<384 * 3, 512, 0, stream>>>(t8, fc2w8, fc2b, MLPD_, 3, nullptr,
                                           nullptr, hbuf, rowmap, out);
}

// Round 22
// 609.132 us; speedup vs baseline: 1.4154x; 1.0010x over previous
//
#include <hip/hip_runtime.h>
#include <hip/hip_bf16.h>

typedef __attribute__((ext_vector_type(8))) short bf16x8;
typedef __attribute__((ext_vector_type(4))) short s16x4;
typedef __attribute__((ext_vector_type(4))) float f32x4;
typedef __attribute__((ext_vector_type(2))) long longx2;

#define NW_   3072
#define WACT_ 1536
#define NTOK_ 98304
#define NBLK_ 9830
#define DIM_  384
#define QKVD_ 1152
#define MLPD_ 1536

__device__ __forceinline__ float bf2f(short s) {
  union { unsigned u; float f; } c;
  c.u = ((unsigned)(unsigned short)s) << 16;
  return c.f;
}
__device__ __forceinline__ short f2bf(float f) {
  union { float f; unsigned u; } c; c.f = f;
  unsigned lsb = (c.u >> 16) & 1u;
  c.u += 0x7fffu + lsb;
  return (short)(c.u >> 16);
}

__device__ __forceinline__ f32x4 mfma8(long a, long b, f32x4 c) {
  return __builtin_amdgcn_mfma_f32_16x16x32_fp8_fp8(a, b, c, 0, 0, 0);
}

__device__ __forceinline__ void gload16(const void* g, void* l) {
  __builtin_amdgcn_global_load_lds(
      (const __attribute__((address_space(1))) unsigned*)g,
      (__attribute__((address_space(3))) unsigned*)l, 16, 0, 0);
}

// K-perm byte position within a row: col -> group*64 + slot*8 + (col&7),
// slot = ((l&3)<<1)|(l>>2), l = (col>>3)&7.  (Proven R17 convention.)
__device__ __forceinline__ int kperm(int col) {
  int l = (col >> 3) & 7;
  int s = ((l & 3) << 1) | (l >> 2);
  return (col & ~63) + s * 8 + (col & 7);
}

// ---------------- merged prologue: mapA + weight conversions ----------------
__device__ __forceinline__ void conv8_chunk(const float* __restrict__ src,
                                            unsigned char* __restrict__ dst,
                                            int K, int blk, int tid) {
  int i = (blk * 256 + tid) * 8;
  f32x4 v0 = *(const f32x4*)&src[i];
  f32x4 v1 = *(const f32x4*)&src[i + 4];
  int w0 = __builtin_amdgcn_cvt_pk_fp8_f32(v0[0], v0[1], 0, false);
  w0 = __builtin_amdgcn_cvt_pk_fp8_f32(v0[2], v0[3], w0, true);
  int w1 = __builtin_amdgcn_cvt_pk_fp8_f32(v1[0], v1[1], 0, false);
  w1 = __builtin_amdgcn_cvt_pk_fp8_f32(v1[2], v1[3], w1, true);
  int kro = i % K, row = i / K;
  union { int u[2]; long ll; } p; p.u[0] = w0; p.u[1] = w1;
  *(long*)&dst[(size_t)row * K + kperm(kro)] = p.ll;
}

__global__ __launch_bounds__(256) void pre_k(const float* __restrict__ qkvw,
                                             const float* __restrict__ projw,
                                             const float* __restrict__ fc1w,
                                             const float* __restrict__ fc2w,
                                             unsigned char* __restrict__ qw8,
                                             unsigned char* __restrict__ pw8,
                                             unsigned char* __restrict__ f1w8,
                                             unsigned char* __restrict__ f2w8,
                                             int* win_rank, unsigned* bitmap) {
  const int bid = blockIdx.x, tid = threadIdx.x;
  if (bid < 12) {
    int t = bid * 256 + tid;
    if (t < NW_) { win_rank[t] = -1; bitmap[t] = 0u; }
  } else if (bid < 228) {
    conv8_chunk(qkvw, qw8, 384, bid - 12, tid);
  } else if (bid < 300) {
    conv8_chunk(projw, pw8, 384, bid - 228, tid);
  } else if (bid < 588) {
    conv8_chunk(fc1w, f1w8, 384, bid - 300, tid);
  } else {
    conv8_chunk(fc2w, f2w8, MLPD_, bid - 588, tid);
  }
}

// ---------------- map kernels ----------------
__global__ __launch_bounds__(256) void mapB_k(const int* __restrict__ iw,
                                              const int* __restrict__ blk,
                                              int* win_rank, unsigned* bitmap) {
  int t = blockIdx.x * 256 + threadIdx.x;
  if (t < WACT_) win_rank[iw[t]] = t;
  if (t < NBLK_) { int j = blk[t]; atomicOr(&bitmap[j >> 5], 1u << (j & 31)); }
}

__global__ __launch_bounds__(256) void mapC_k(const int* __restrict__ ip,
                                              const int* __restrict__ iw,
                                              const unsigned* __restrict__ bitmap,
                                              int* inv_ip, int* rowmap) {
  int i = blockIdx.x * 256 + threadIdx.x;
  if (i < NTOK_) {
    int j = ip[i];
    inv_ip[j] = i;
    int blocked = (bitmap[j >> 5] >> (j & 31)) & 1;
    rowmap[i] = blocked ? -1 : (iw[j >> 6] * 64 + (j & 63));
  }
}

// ---------------- LN1 + gather/permute -> xp bf16 + xp8 fp8 K-perm ---------
__global__ __launch_bounds__(256) void ln1_k(const float* __restrict__ x,
                                             const float* __restrict__ w,
                                             const float* __restrict__ b,
                                             const int* __restrict__ win_rank,
                                             const int* __restrict__ inv_ip,
                                             const unsigned* __restrict__ bitmap,
                                             float* __restrict__ out,
                                             short* __restrict__ xp,
                                             unsigned char* __restrict__ xp8) {
  const int l = threadIdx.x & 31;
  const int tok = blockIdx.x * 8 + (threadIdx.x >> 5);
  const f32x4* xr = (const f32x4*)(x + (size_t)tok * DIM_);
  f32x4 v[3]; float s = 0.f;
#pragma unroll
  for (int j = 0; j < 3; ++j) {
    v[j] = xr[l + 32 * j];
    s += v[j][0] + v[j][1] + v[j][2] + v[j][3];
  }
#pragma unroll
  for (int m = 1; m <= 16; m <<= 1) s += __shfl_xor(s, m, 64);
  float mu = s * (1.0f / DIM_);
  float q = 0.f;
#pragma unroll
  for (int j = 0; j < 3; ++j)
#pragma unroll
    for (int e = 0; e < 4; ++e) { float d = v[j][e] - mu; q += d * d; }
#pragma unroll
  for (int m = 1; m <= 16; m <<= 1) q += __shfl_xor(q, m, 64);
  float rs = rsqrtf(q * (1.0f / DIM_) + 1e-5f);
  f32x4 y[3];
#pragma unroll
  for (int j = 0; j < 3; ++j) {
    f32x4 wv = *(const f32x4*)&w[4 * l + 128 * j];
    f32x4 bv = *(const f32x4*)&b[4 * l + 128 * j];
#pragma unroll
    for (int e = 0; e < 4; ++e) y[j][e] = (v[j][e] - mu) * rs * wv[e] + bv[e];
  }
  int wdw = tok >> 6, t = tok & 63;
  int rank = win_rank[wdw];
  if (rank < 0) {
    f32x4* po = (f32x4*)(out + (size_t)tok * DIM_);
#pragma unroll
    for (int j = 0; j < 3; ++j) po[l + 32 * j] = y[j];
  } else {
    int jdx = (rank << 6) + t;
    int i = inv_ip[jdx];
#pragma unroll
    for (int j = 0; j < 3; ++j) {
      s16x4 o;
#pragma unroll
      for (int e = 0; e < 4; ++e) o[e] = f2bf(y[j][e]);
      *(s16x4*)&xp[(size_t)i * DIM_ + 4 * l + 128 * j] = o;
      int wrd = __builtin_amdgcn_cvt_pk_fp8_f32(y[j][0], y[j][1], 0, false);
      wrd = __builtin_amdgcn_cvt_pk_fp8_f32(y[j][2], y[j][3], wrd, true);
      *(unsigned*)&xp8[(size_t)i * DIM_ + kperm(4 * l + 128 * j)] = (unsigned)wrd;
    }
    if ((bitmap[jdx >> 5] >> (jdx & 31)) & 1) {
      f32x4* po = (f32x4*)(out + (size_t)tok * DIM_);
#pragma unroll
      for (int j = 0; j < 3; ++j) po[l + 32 * j] = y[j];
    }
  }
}

// ---------------- LN2 -> fp8 K-permuted ----------------
__global__ __launch_bounds__(256) void ln2_k(const short* __restrict__ h,
                                             const float* __restrict__ w,
                                             const float* __restrict__ b,
                                             unsigned char* __restrict__ out8) {
  const int l = threadIdx.x & 31;
  const int tok = blockIdx.x * 8 + (threadIdx.x >> 5);
  const s16x4* xr = (const s16x4*)(h + (size_t)tok * DIM_);
  float v[12]; float s = 0.f;
#pragma unroll
  for (int j = 0; j < 3; ++j) {
    s16x4 rv = xr[l + 32 * j];
#pragma unroll
    for (int e = 0; e < 4; ++e) { v[j * 4 + e] = bf2f(rv[e]); s += v[j * 4 + e]; }
  }
#pragma unroll
  for (int m = 1; m <= 16; m <<= 1) s += __shfl_xor(s, m, 64);
  float mu = s * (1.0f / DIM_);
  float q = 0.f;
#pragma unroll
  for (int e = 0; e < 12; ++e) { float d = v[e] - mu; q += d * d; }
#pragma unroll
  for (int m = 1; m <= 16; m <<= 1) q += __shfl_xor(q, m, 64);
  float rs = rsqrtf(q * (1.0f / DIM_) + 1e-5f);
#pragma unroll
  for (int j = 0; j < 3; ++j) {
    f32x4 wv = *(const f32x4*)&w[4 * l + 128 * j];
    f32x4 bv = *(const f32x4*)&b[4 * l + 128 * j];
    float y[4];
#pragma unroll
    for (int e = 0; e < 4; ++e)
      y[e] = (v[j * 4 + e] - mu) * rs * wv[e] + bv[e];
    int wrd = __builtin_amdgcn_cvt_pk_fp8_f32(y[0], y[1], 0, false);
    wrd = __builtin_amdgcn_cvt_pk_fp8_f32(y[2], y[3], wrd, true);
    int c0 = 4 * l + 128 * j;  // 4-aligned within an 8B chunk
    *(unsigned*)&out8[(size_t)tok * DIM_ + kperm(c0)] = (unsigned)wrd;
  }
}

// ---------------- Generic fp8 GEMM: 256x128 tile, 8 waves (R8 geometry) ----
// BK=128 fp8, K-permuted operands, conflict-free ds_read_b128 (R17 pattern).
// EPI 0: +bias -> fp8 plain (ld QKVD_) (qkv)
// EPI 1: +bias +add_bf -> bf16         (proj + residual -> h)
// EPI 2: +bias, gelu -> fp8 K-perm     (fc1 -> t8, ld MLPD_)
// EPI 3: +bias +add_bf, scatter fp32   (fc2 + residual -> out)
template <int EPI>
__global__ __launch_bounds__(512) void gemmf8_k(const unsigned char* __restrict__ A8,
                                                const unsigned char* __restrict__ B8,
                                                const float* __restrict__ bias,
                                                int K, int nx,
                                                short* __restrict__ Cb,
                                                unsigned char* __restrict__ C8,
                                                const short* __restrict__ add_bf,
                                                const int* __restrict__ rowmap,
                                                float* __restrict__ outf) {
  const int nwg = gridDim.x;
  const int q8 = nwg >> 3;
  const int wg = (blockIdx.x & 7) * q8 + (blockIdx.x >> 3);
  const int ntile = wg % nx, mtile = wg / nx;
  const int tid = threadIdx.x, wid = tid >> 6, lane = tid & 63;
  const int fq = lane >> 4, fr = lane & 15;
  const int wr = wid >> 1, wc = wid & 1;  // 4(M) x 2(N) waves, 64x64 each
  __shared__ __align__(16) unsigned char lA[256 * 128];
  __shared__ __align__(16) unsigned char lB[128 * 128];
  const int row0 = mtile * 256, col0 = ntile * 128;
  float bs[4];
#pragma unroll
  for (int nt = 0; nt < 4; ++nt) bs[nt] = bias[col0 + wc * 64 + nt * 16 + fr];
  f32x4 acc[4][4];
#pragma unroll
  for (int a = 0; a < 4; ++a)
#pragma unroll
    for (int c = 0; c < 4; ++c) acc[a][c] = (f32x4){0.f, 0.f, 0.f, 0.f};
  const int nkt = K >> 7;  // 3 or 12
  for (int kt = 0; kt < nkt; ++kt) {
    const int k0 = kt << 7;
    // A: 2048 16B-blocks (4/thread); B: 1024 (2/thread)
#pragma unroll
    for (int i = 0; i < 4; ++i) {
      int g = i * 512 + tid;
      int r = g >> 3, c8 = g & 7;
      int s8 = c8 ^ (r & 7);
      gload16(A8 + (size_t)(row0 + r) * K + k0 + s8 * 16, (char*)lA + (size_t)g * 16);
    }
#pragma unroll
    for (int i = 0; i < 2; ++i) {
      int g = i * 512 + tid;
      int r = g >> 3, c8 = g & 7;
      int s8 = c8 ^ (r & 7);
      gload16(B8 + (size_t)(col0 + r) * K + k0 + s8 * 16, (char*)lB + (size_t)g * 16);
    }
    __syncthreads();
#pragma unroll
    for (int ss = 0; ss < 2; ++ss) {
      longx2 af[4], bfr[4];
      const int pb = ss * 4 + fq;
#pragma unroll
      for (int mt = 0; mt < 4; ++mt) {
        int r = wr * 64 + mt * 16 + fr;
        int d = pb ^ (r & 7);
        af[mt] = *(const longx2*)&lA[r * 128 + d * 16];
      }
#pragma unroll
      for (int nt = 0; nt < 4; ++nt) {
        int r = wc * 64 + nt * 16 + fr;
        int d = pb ^ (r & 7);
        bfr[nt] = *(const longx2*)&lB[r * 128 + d * 16];
      }
#pragma unroll
      for (int mt = 0; mt < 4; ++mt)
#pragma unroll
        for (int nt = 0; nt < 4; ++nt) {
          acc[mt][nt] = mfma8(af[mt][0], bfr[nt][0], acc[mt][nt]);
          acc[mt][nt] = mfma8(af[mt][1], bfr[nt][1], acc[mt][nt]);
        }
    }
    __syncthreads();
  }
#pragma unroll
  for (int mt = 0; mt < 4; ++mt) {
#pragma unroll
    for (int jj = 0; jj < 4; ++jj) {
      int r = row0 + wr * 64 + mt * 16 + fq * 4 + jj;
      int dmap = 0;
      if (EPI == 3) dmap = rowmap[r];
      if (EPI == 0) {
        float g4[4];
#pragma unroll
        for (int nt = 0; nt < 4; ++nt) g4[nt] = acc[mt][nt][jj] + bs[nt];
        int p01 = __builtin_amdgcn_cvt_pk_fp8_f32(g4[0], g4[1], 0, false);
        int p23 = __builtin_amdgcn_cvt_pk_fp8_f32(g4[2], g4[3], 0, false);
        const size_t rb = (size_t)r * QKVD_ + col0 + wc * 64 + fr;
        C8[rb]      = (unsigned char)(p01 & 0xff);
        C8[rb + 16] = (unsigned char)((p01 >> 8) & 0xff);
        C8[rb + 32] = (unsigned char)(p23 & 0xff);
        C8[rb + 48] = (unsigned char)((p23 >> 8) & 0xff);
      } else if (EPI == 1) {
#pragma unroll
        for (int nt = 0; nt < 4; ++nt) {
          int gcol = col0 + wc * 64 + nt * 16 + fr;
          float v = acc[mt][nt][jj] + bs[nt] + bf2f(add_bf[(size_t)r * DIM_ + gcol]);
          Cb[(size_t)r * DIM_ + gcol] = f2bf(v);
        }
      } else if (EPI == 2) {
        float g4[4];
#pragma unroll
        for (int nt = 0; nt < 4; ++nt) {
          float v = acc[mt][nt][jj] + bs[nt];
          float u = v * (0.79788456f + 0.03567741f * v * v);
          g4[nt] = v * __builtin_amdgcn_rcpf(1.0f + __expf(-2.0f * u));
        }
        int p01 = __builtin_amdgcn_cvt_pk_fp8_f32(g4[0], g4[1], 0, false);
        int p23 = __builtin_amdgcn_cvt_pk_fp8_f32(g4[2], g4[3], 0, false);
        const int C0 = col0 + wc * 64;
        const size_t rb = (size_t)r * MLPD_ + C0 + (fr & 7) + ((fr >> 3) << 4);
        C8[rb]      = (unsigned char)(p01 & 0xff);
        C8[rb + 32] = (unsigned char)((p01 >> 8) & 0xff);
        C8[rb + 8]  = (unsigned char)(p23 & 0xff);
        C8[rb + 40] = (unsigned char)((p23 >> 8) & 0xff);
      } else {
#pragma unroll
        for (int nt = 0; nt < 4; ++nt) {
          int gcol = col0 + wc * 64 + nt * 16 + fr;
          float v = acc[mt][nt][jj] + bs[nt] + bf2f(add_bf[(size_t)r * DIM_ + gcol]);
          if (dmap >= 0) outf[(size_t)dmap * DIM_ + gcol] = v;
        }
      }
    }
  }
}

// ---------------- attention: fp8, coalesced LDS staging ----------------
// Block = (m, head-group grp of 4 heads) -> 64 rows x 384 B contiguous slice
// of qkv8. Staged via 6 coalesced gload16/thread with rule-#21 pre-swizzled
// global source (c16 ^= r&7, LDS linear). Fragment reads hit ~2-way banks.
// P (18 KB) aliases the staging buffer after a barrier.
__global__ __launch_bounds__(256) void attn_k(const unsigned char* __restrict__ qkv8,
                                              const unsigned* __restrict__ bitmap,
                                              const int* __restrict__ ip,
                                              unsigned char* __restrict__ o8) {
  const int flat = (blockIdx.x & 7) * 576 + (blockIdx.x >> 3);
  const int m = flat / 3;
  const int grp = flat % 3;
  const int wid = threadIdx.x >> 6, lane = threadIdx.x & 63;
  const int h = grp * 4 + wid;
  const int fq = lane >> 4, fr = lane & 15;
  __shared__ __align__(16) unsigned char qkvL[24576];   // 64 rows x 384 B
  __shared__ __align__(16) unsigned char Vt[4][32 * 72];
  __shared__ unsigned char flags[64];
  unsigned char (*P)[64 * 72] = (unsigned char (*)[64 * 72])qkvL;  // alias

  // coalesced staging: 1536 16B-blocks; LDS slot c16 of row r holds global
  // block c16 ^ (r & 7)  (source pre-swizzle keeps fragment reads spread).
  const unsigned char* rowbase = qkv8 + (size_t)m * 64 * QKVD_ + grp * 384;
#pragma unroll
  for (int i = 0; i < 6; ++i) {
    int g = i * 256 + threadIdx.x;
    int r = g / 24, c16 = g % 24;
    int sc = c16 ^ (r & 7);
    gload16(rowbase + (size_t)r * QKVD_ + sc * 16, (char*)qkvL + (size_t)g * 16);
  }
  if (threadIdx.x < 64) {
    int j = ip[m * 64 + threadIdx.x];
    flags[threadIdx.x] = (unsigned char)((bitmap[j >> 5] >> (j & 31)) & 1);
  }
  __syncthreads();  // drains gload16 (vmcnt) + flags

  const float scale = 0.17677669529663687f;
  int msk[4];
#pragma unroll
  for (int nt = 0; nt < 4; ++nt) msk[nt] = flags[nt * 16 + fr];

  // 8B chunk c (0..47) of row r, accounting for the staging swizzle
  auto ldsc = [&](int r, int c) -> long {
    int slot = (c >> 1) ^ (r & 7);
    return *(const long*)&qkvL[r * 384 + slot * 16 + (c & 1) * 8];
  };

  // ---- Q/K fragments from LDS; S = Q K^T ----
  f32x4 sacc[4][4];
#pragma unroll
  for (int a = 0; a < 4; ++a)
#pragma unroll
    for (int c = 0; c < 4; ++c) sacc[a][c] = (f32x4){0.f, 0.f, 0.f, 0.f};
  long qa[4], kb[4];
#pragma unroll
  for (int mt = 0; mt < 4; ++mt) qa[mt] = ldsc(mt * 16 + fr, wid * 12 + fq);
#pragma unroll
  for (int nt = 0; nt < 4; ++nt) kb[nt] = ldsc(nt * 16 + fr, wid * 12 + 4 + fq);
#pragma unroll
  for (int mt = 0; mt < 4; ++mt)
#pragma unroll
    for (int nt = 0; nt < 4; ++nt)
      sacc[mt][nt] = mfma8(qa[mt], kb[nt], sacc[mt][nt]);
  // ---- stage V^T from qkvL ----
#pragma unroll
  for (int cc = 0; cc < 4; ++cc) {
    long vv = ldsc(lane, wid * 12 + 8 + cc);
    const unsigned char* vb = (const unsigned char*)&vv;
#pragma unroll
    for (int e = 0; e < 8; ++e) Vt[wid][(cc * 8 + e) * 72 + lane] = vb[e];
  }
  __syncthreads();  // all qkvL reads done before P alias writes

  // ---- scale + mask ----
#pragma unroll
  for (int mt = 0; mt < 4; ++mt)
#pragma unroll
    for (int nt = 0; nt < 4; ++nt) {
      f32x4 sv = sacc[mt][nt];
#pragma unroll
      for (int jj = 0; jj < 4; ++jj)
        sv[jj] = msk[nt] ? -10000.0f : sv[jj] * scale;
      sacc[mt][nt] = sv;
    }
  // ---- softmax rows + write P (fp8, aliased over qkvL) ----
#pragma unroll
  for (int mt = 0; mt < 4; ++mt) {
#pragma unroll
    for (int jj = 0; jj < 4; ++jj) {
      float mx = sacc[mt][0][jj];
#pragma unroll
      for (int nt = 1; nt < 4; ++nt) mx = fmaxf(mx, sacc[mt][nt][jj]);
#pragma unroll
      for (int mm = 1; mm < 16; mm <<= 1) mx = fmaxf(mx, __shfl_xor(mx, mm, 64));
      float sm = 0.f;
      float p[4];
#pragma unroll
      for (int nt = 0; nt < 4; ++nt) {
        p[nt] = __expf(sacc[mt][nt][jj] - mx);
        sm += p[nt];
      }
#pragma unroll
      for (int mm = 1; mm < 16; mm <<= 1) sm += __shfl_xor(sm, mm, 64);
      float inv = 1.0f / sm;
      int rowb = (mt * 16 + fq * 4 + jj) * 72;
      int p01 = __builtin_amdgcn_cvt_pk_fp8_f32(p[0] * inv, p[1] * inv, 0, false);
      int p23 = __builtin_amdgcn_cvt_pk_fp8_f32(p[2] * inv, p[3] * inv, 0, false);
      P[wid][rowb + fr]      = (unsigned char)(p01 & 0xff);
      P[wid][rowb + 16 + fr] = (unsigned char)((p01 >> 8) & 0xff);
      P[wid][rowb + 32 + fr] = (unsigned char)(p23 & 0xff);
      P[wid][rowb + 48 + fr] = (unsigned char)((p23 >> 8) & 0xff);
    }
  }
  // ---- O = P V ----
  f32x4 oacc[4][2];
#pragma unroll
  for (int a = 0; a < 4; ++a)
#pragma unroll
    for (int c = 0; c < 2; ++c) oacc[a][c] = (f32x4){0.f, 0.f, 0.f, 0.f};
#pragma unroll
  for (int ks = 0; ks < 2; ++ks) {
    long pa[4], vb[2];
#pragma unroll
    for (int mt = 0; mt < 4; ++mt)
      pa[mt] = *(const long*)&P[wid][(mt * 16 + fr) * 72 + ks * 32 + fq * 8];
#pragma unroll
    for (int nd = 0; nd < 2; ++nd)
      vb[nd] = *(const long*)&Vt[wid][(nd * 16 + fr) * 72 + ks * 32 + fq * 8];
#pragma unroll
    for (int mt = 0; mt < 4; ++mt)
#pragma unroll
      for (int nd = 0; nd < 2; ++nd)
        oacc[mt][nd] = mfma8(pa[mt], vb[nd], oacc[mt][nd]);
  }
  // ---- store O as fp8 K-permuted (row length DIM_) ----
  const int pos0 = kperm(h * 32 + fr);
  const int pos1 = kperm(h * 32 + 16 + fr);
#pragma unroll
  for (int mt = 0; mt < 4; ++mt)
#pragma unroll
    for (int jj = 0; jj < 4; ++jj) {
      int p01 = __builtin_amdgcn_cvt_pk_fp8_f32(oacc[mt][0][jj], oacc[mt][1][jj],
                                                0, false);
      size_t rb = (size_t)(m * 64 + mt * 16 + fq * 4 + jj) * DIM_;
      o8[rb + pos0] = (unsigned char)(p01 & 0xff);
      o8[rb + pos1] = (unsigned char)((p01 >> 8) & 0xff);
    }
}

// ---------------- launch ----------------
extern "C" void kernel_launch(void* const* d_in, const int* in_sizes, int n_in,
                              void* d_out, int out_size, void* d_ws, size_t ws_size,
                              hipStream_t stream) {
  const float* x = (const float*)d_in[0];
  const int* iw = (const int*)d_in[1];
  const int* ip = (const int*)d_in[2];
  const int* blk = (const int*)d_in[3];
  const float* ln1w = (const float*)d_in[6];
  const float* ln1b = (const float*)d_in[7];
  const float* qkvw = (const float*)d_in[8];
  const float* qkvb = (const float*)d_in[9];
  const float* projw = (const float*)d_in[10];
  const float* projb = (const float*)d_in[11];
  const float* ln2w = (const float*)d_in[12];
  const float* ln2b = (const float*)d_in[13];
  const float* fc1w = (const float*)d_in[14];
  const float* fc1b = (const float*)d_in[15];
  const float* fc2w = (const float*)d_in[16];
  const float* fc2b = (const float*)d_in[17];
  float* out = (float*)d_out;

  char* ws = (char*)d_ws;
  unsigned char* qkvw8 = (unsigned char*)ws;                 // 442,368
  unsigned char* projw8 = (unsigned char*)(ws + 442368);     // 147,456
  unsigned char* fc1w8 = (unsigned char*)(ws + 589824);      // 589,824
  unsigned char* fc2w8 = (unsigned char*)(ws + 1179648);     // 589,824 -> 1,769,472
  int* inv_ip = (int*)(ws + 2211840);
  int* rowmap = inv_ip + NTOK_;
  int* win_rank = rowmap + NTOK_;
  unsigned* bitmap = (unsigned*)(win_rank + NW_);
  short* xp = (short*)(ws + 4349952);                        // 75.5 MB bf16
  unsigned char* qkv8 = (unsigned char*)(ws + 79847424);     // 113 MB fp8
  unsigned char* t8 = qkv8;                                  // 151 MB fp8 (after attn)
  unsigned char* obuf8 = (unsigned char*)(ws + 306339840);   // 37.7 MB fp8
  unsigned char* ln2buf8 = (unsigned char*)(ws + 344088576); // 37.7 MB fp8
  unsigned char* xp8 = (unsigned char*)(ws + 381837312);     // 37.7 MB fp8
  short* hbuf = (short*)(ws + 457334784);                    // 75.5 MB bf16
  (void)in_sizes; (void)n_in; (void)out_size; (void)ws_size;

  pre_k<<<876, 256, 0, stream>>>(qkvw, projw, fc1w, fc2w, qkvw8, projw8, fc1w8,
                                 fc2w8, win_rank, bitmap);
  mapB_k<<<39, 256, 0, stream>>>(iw, blk, win_rank, bitmap);
  mapC_k<<<NTOK_ / 256, 256, 0, stream>>>(ip, iw, bitmap, inv_ip, rowmap);
  ln1_k<<<(NW_ * 64) / 8, 256, 0, stream>>>(x, ln1w, ln1b, win_rank, inv_ip, bitmap,
                                            out, xp, xp8);
  // 256-row mtiles = 384
  gemmf8_k<0><<<384 * 9, 512, 0, stream>>>(xp8, qkvw8, qkvb, 384, 9, nullptr,
                                           qkv8, nullptr, nullptr, nullptr);
  attn_k<<<WACT_ * 3, 256, 0, stream>>>(qkv8, bitmap, ip, obuf8);
  gemmf8_k<1><<<384 * 3, 512, 0, stream>>>(obuf8, projw8, projb, 384, 3, hbuf,
                                           nullptr, xp, nullptr, nullptr);
  ln2_k<<<NTOK_ / 8, 256, 0, stream>>>(hbuf, ln2w, ln2b, ln2buf8);
  gemmf8_k<2><<<384 * 12, 512, 0, stream>>>(ln2buf8, fc1w8, fc1b, 384, 12, nullptr,
                                            t8, nullptr, nullptr, nullptr);
  gemmf8_k<3><<<384 * 3, 512, 0, stream>>>(t8, fc2w8, fc2b, MLPD_, 3, nullptr,
                                           nullptr, hbuf, rowmap, out);
}